// Round 1
// baseline (12266.530 us; speedup 1.0000x reference)
//
#include <hip/hip_runtime.h>
#include <cmath>

#define NB 16      // batch
#define SS 400     // source len
#define TT 96      // target len
#define EE 1024    // embed
#define HL 128     // LSTM per dir
#define HH 256     // decoder hidden (2*HL)
#define AA 64      // attn dim
#define VV 30611   // vocab
#define START_TOK 101
#define NCHUNK 120 // vocab chunks of 256

// ---------- helpers ----------
__device__ __forceinline__ float gload(const float* p) {
  return __hip_atomic_load(p, __ATOMIC_RELAXED, __HIP_MEMORY_SCOPE_AGENT);
}
__device__ __forceinline__ void gstore(float* p, float v) {
  __hip_atomic_store(p, v, __ATOMIC_RELAXED, __HIP_MEMORY_SCOPE_AGENT);
}
// multi-WG barrier: monotonic counter, nwg workgroups participate
__device__ __forceinline__ void wgbar(int* cnt, int nwg) {
  __syncthreads();   // compiler drains vmcnt before s_barrier -> all stores done
  if (threadIdx.x == 0) {
    __threadfence();
    int old = atomicAdd(cnt, 1);
    int target = (old / nwg + 1) * nwg;
    while (__hip_atomic_load(cnt, __ATOMIC_RELAXED, __HIP_MEMORY_SCOPE_AGENT) < target)
      __builtin_amdgcn_s_sleep(2);
  }
  __syncthreads();
  __threadfence();   // acquire
}
__device__ __forceinline__ float sigmf(float x) { return 1.0f / (1.0f + __expf(-x)); }
__device__ __forceinline__ float tanhf_(float x) {
  float xc = fminf(fmaxf(x, -15.0f), 15.0f);
  return 1.0f - 2.0f / (__expf(2.0f * xc) + 1.0f);
}

// ---------- init: zero cross-step buffers & barrier counters ----------
__global__ __launch_bounds__(256) void k_init(float* hg, float* ctxb, int* cnts) {
  for (int i = threadIdx.x; i < 2*2*NB*HL; i += 256) hg[i] = 0.0f;
  for (int i = threadIdx.x; i < 2*NB*HH; i += 256) ctxb[i] = 0.0f;
  if (threadIdx.x < 8) cnts[threadIdx.x] = 0;
}

// ---------- encoder input projection: xcomb[s*16+b][n], n = dir*512 + q*128 + j ----------
__global__ __launch_bounds__(256) void k_embproj_enc(
    const float* __restrict__ emb, const int* __restrict__ article,
    const float* __restrict__ wihf, const float* __restrict__ wihb,
    const float* __restrict__ bf, const float* __restrict__ bb,
    float* __restrict__ xcomb)
{
  const int rt = blockIdx.x;        // 200 row tiles of 32
  const int n0 = blockIdx.y * 128;  // 8 col tiles
  const int tid = threadIdx.x;
  __shared__ float Alds[32*36];
  __shared__ float Blds[32*129];    // [kk][nn]
  __shared__ int toklds[32];
  if (tid < 32) {
    int R = rt*32 + tid;            // R = s*16 + b
    int s = R >> 4, b = R & 15;
    toklds[tid] = article[b*SS + s];
  }
  __syncthreads();
  float acc[16];
  #pragma unroll
  for (int q = 0; q < 16; ++q) acc[q] = 0.0f;
  const int nn = tid & 127, rg = tid >> 7;
  for (int kc = 0; kc < 1024; kc += 32) {
    #pragma unroll
    for (int i = 0; i < 4; ++i) {
      int l = tid + i*256;
      int rr = l >> 5, kk = l & 31;
      Alds[rr*36 + kk] = emb[toklds[rr]*1024 + kc + kk];
    }
    #pragma unroll
    for (int i = 0; i < 16; ++i) {
      int l = tid + i*256;
      int bn = l >> 5, kk = l & 31;
      int n = n0 + bn;
      const float* src = (n < 512) ? (wihf + n*1024) : (wihb + (n-512)*1024);
      Blds[kk*129 + bn] = src[kc + kk];
    }
    __syncthreads();
    float bvr[32];
    #pragma unroll
    for (int kk = 0; kk < 32; ++kk) bvr[kk] = Blds[kk*129 + nn];
    #pragma unroll
    for (int q = 0; q < 16; ++q) {
      const float4* a4 = (const float4*)(Alds + (rg*16 + q)*36);
      float s0 = 0.0f;
      #pragma unroll
      for (int k4 = 0; k4 < 8; ++k4) {
        float4 a = a4[k4];
        s0 += a.x*bvr[4*k4] + a.y*bvr[4*k4+1] + a.z*bvr[4*k4+2] + a.w*bvr[4*k4+3];
      }
      acc[q] += s0;
    }
    __syncthreads();
  }
  int n = n0 + nn;
  float bias = (n < 512) ? bf[n] : bb[n-512];
  #pragma unroll
  for (int q = 0; q < 16; ++q) {
    int R = rt*32 + rg*16 + q;
    xcomb[R*1024 + n] = acc[q] + bias;
  }
}

// ---------- decoder embedding projection: decpre[t*16+b][n], n = q*256+u (dec_b folded) ----------
__global__ __launch_bounds__(256) void k_embproj_dec(
    const float* __restrict__ emb, const int* __restrict__ abstr,
    const float* __restrict__ dwih, const float* __restrict__ db,
    float* __restrict__ decpre)
{
  const int rt = blockIdx.x;        // 48 row tiles of 32
  const int n0 = blockIdx.y * 128;  // 8 col tiles
  const int tid = threadIdx.x;
  __shared__ float Alds[32*36];
  __shared__ float Blds[32*129];
  __shared__ int toklds[32];
  if (tid < 32) {
    int R = rt*32 + tid;            // R = t*16 + b
    int t = R >> 4, b = R & 15;
    toklds[tid] = (t == 0) ? START_TOK : abstr[b*TT + t - 1];
  }
  __syncthreads();
  float acc[16];
  #pragma unroll
  for (int q = 0; q < 16; ++q) acc[q] = 0.0f;
  const int nn = tid & 127, rg = tid >> 7;
  for (int kc = 0; kc < 1024; kc += 32) {
    #pragma unroll
    for (int i = 0; i < 4; ++i) {
      int l = tid + i*256;
      int rr = l >> 5, kk = l & 31;
      Alds[rr*36 + kk] = emb[toklds[rr]*1024 + kc + kk];
    }
    #pragma unroll
    for (int i = 0; i < 16; ++i) {
      int l = tid + i*256;
      int bn = l >> 5, kk = l & 31;
      int n = n0 + bn;
      Blds[kk*129 + bn] = dwih[n*1280 + kc + kk];
    }
    __syncthreads();
    float bvr[32];
    #pragma unroll
    for (int kk = 0; kk < 32; ++kk) bvr[kk] = Blds[kk*129 + nn];
    #pragma unroll
    for (int q = 0; q < 16; ++q) {
      const float4* a4 = (const float4*)(Alds + (rg*16 + q)*36);
      float s0 = 0.0f;
      #pragma unroll
      for (int k4 = 0; k4 < 8; ++k4) {
        float4 a = a4[k4];
        s0 += a.x*bvr[4*k4] + a.y*bvr[4*k4+1] + a.z*bvr[4*k4+2] + a.w*bvr[4*k4+3];
      }
      acc[q] += s0;
    }
    __syncthreads();
  }
  int n = n0 + nn;
  float bias = db[n];
  #pragma unroll
  for (int q = 0; q < 16; ++q) {
    int R = rt*32 + rg*16 + q;
    decpre[R*1024 + n] = acc[q] + bias;
  }
}

// ---------- bidirectional encoder recurrence: 16 WGs (8 per dir), 1 barrier/step ----------
__global__ __launch_bounds__(256) void k_encoder(
    const float* __restrict__ xcomb,
    const float* __restrict__ whhf, const float* __restrict__ whhb,
    float* __restrict__ encout,
    float* hg,            // [2 dir][2 par][16*128]
    float* dech0,         // parity-0 decoder h buffer: [16][256] (h0)
    float* c0buf,         // [16][256]
    int* cnts)
{
  const int wg = blockIdx.x;
  const int dir = wg >> 3, sub = wg & 7;
  const int u0 = sub * 16;
  const int tid = threadIdx.x;
  const int cb = tid & 15, cu = tid >> 4;   // cell mapping
  const int rp = tid >> 3, bp = tid & 7;    // gemm mapping

  __shared__ float Wl[64*132];
  __shared__ float hb[16*132];
  __shared__ float gl[64*17];

  const float* Whh = dir ? whhb : whhf;
  #pragma unroll
  for (int i = 0; i < 32; ++i) {
    int l = tid + i*256;
    int r = l >> 7, k = l & 127;
    int q = r >> 4, uu = r & 15;
    Wl[r*132 + k] = Whh[(q*128 + u0 + uu)*128 + k];
  }
  float c_reg = 0.0f;
  float hlast = 0.0f;
  float* hgd = hg + dir * 2 * NB * HL;
  int* cnt = cnts + dir;
  __syncthreads();

  for (int s = 0; s < SS; ++s) {
    const int sf = dir ? (SS - 1 - s) : s;
    const int rpar = s & 1, wpar = rpar ^ 1;
    // prefetch x-projection for this thread's cell (gate order i,f,g,o)
    const float* xrow = xcomb + (sf*NB + cb)*1024 + dir*512 + u0 + cu;
    float xv0 = xrow[0], xv1 = xrow[128], xv2 = xrow[256], xv3 = xrow[384];
    // stage h
    #pragma unroll
    for (int i = 0; i < 8; ++i) {
      int l = tid + i*256;
      int b = l >> 7, k = l & 127;
      hb[b*132 + k] = gload(hgd + rpar*NB*HL + l);
    }
    __syncthreads();
    // gates gemm: 2 rows x 2 b per thread
    float a00 = 0, a01 = 0, a10 = 0, a11 = 0;
    {
      const float4* wa4 = (const float4*)(Wl + (2*rp)*132);
      const float4* wb4 = (const float4*)(Wl + (2*rp + 1)*132);
      const float4* ha4 = (const float4*)(hb + (2*bp)*132);
      const float4* hb4 = (const float4*)(hb + (2*bp + 1)*132);
      #pragma unroll
      for (int kq = 0; kq < 32; ++kq) {
        float4 wa = wa4[kq], wb = wb4[kq], ha = ha4[kq], hbv = hb4[kq];
        a00 += wa.x*ha.x + wa.y*ha.y + wa.z*ha.z + wa.w*ha.w;
        a01 += wa.x*hbv.x + wa.y*hbv.y + wa.z*hbv.z + wa.w*hbv.w;
        a10 += wb.x*ha.x + wb.y*ha.y + wb.z*ha.z + wb.w*ha.w;
        a11 += wb.x*hbv.x + wb.y*hbv.y + wb.z*hbv.z + wb.w*hbv.w;
      }
    }
    gl[(2*rp)*17 + 2*bp]     = a00;
    gl[(2*rp)*17 + 2*bp + 1] = a01;
    gl[(2*rp + 1)*17 + 2*bp]     = a10;
    gl[(2*rp + 1)*17 + 2*bp + 1] = a11;
    __syncthreads();
    // cell update (thread owns cell (cb, u0+cu))
    float gi = gl[(0*16 + cu)*17 + cb] + xv0;
    float gf = gl[(1*16 + cu)*17 + cb] + xv1;
    float gg = gl[(2*16 + cu)*17 + cb] + xv2;
    float go = gl[(3*16 + cu)*17 + cb] + xv3;
    float iv = sigmf(gi), fv = sigmf(gf), gv = tanhf_(gg), ov = sigmf(go);
    c_reg = fv * c_reg + iv * gv;
    float hv = ov * tanhf_(c_reg);
    gstore(hgd + wpar*NB*HL + cb*HL + u0 + cu, hv);
    encout[(cb*SS + sf)*HH + dir*HL + u0 + cu] = hv;
    hlast = hv;
    wgbar(cnt, 8);
  }
  // final states -> decoder init
  dech0[cb*HH + dir*HL + u0 + cu] = hlast;
  c0buf[cb*HH + dir*HL + u0 + cu] = c_reg;
}

// ---------- enc_ws = enc_out @ attn_s_W.T + b, stored transposed [b][a][s] ----------
__global__ __launch_bounds__(256) void k_encws(
    const float* __restrict__ encout,
    const float* __restrict__ asW, const float* __restrict__ asb,
    float* __restrict__ encwsT)
{
  const int rt = blockIdx.x;  // 200 tiles of 32 rows (row = b*400+s)
  const int tid = threadIdx.x;
  __shared__ float Al[32*260];
  #pragma unroll
  for (int i = 0; i < 32; ++i) {
    int l = tid + i*256;
    int r = l >> 8, k = l & 255;
    Al[r*260 + k] = encout[(rt*32 + r)*256 + k];
  }
  __syncthreads();
  const int a = tid & 63, rg = tid >> 6;
  float acc[8];
  #pragma unroll
  for (int q = 0; q < 8; ++q) acc[q] = 0.0f;
  const float4* w4 = (const float4*)(asW + a*256);
  for (int k4 = 0; k4 < 64; ++k4) {
    float4 w = w4[k4];
    #pragma unroll
    for (int q = 0; q < 8; ++q) {
      const float4* a4 = (const float4*)(Al + (rg*8 + q)*260);
      float4 av = a4[k4];
      acc[q] += av.x*w.x + av.y*w.y + av.z*w.z + av.w*w.w;
    }
  }
  float bias = asb[a];
  #pragma unroll
  for (int q = 0; q < 8; ++q) {
    int row = rt*32 + rg*8 + q;
    int b = row / SS, s = row - b*SS;
    encwsT[(b*AA + a)*SS + s] = acc[q] + bias;
  }
}

// ---------- decoder: 16 WGs, 2 barriers/step ----------
__global__ __launch_bounds__(256) void k_decoder(
    const float* __restrict__ decpre,
    const float* __restrict__ dwhh,   // [1024][256]
    const float* __restrict__ dwih,   // [1024][1280]
    const float* __restrict__ ahW, const float* __restrict__ ahb,
    const float* __restrict__ afW, const float* __restrict__ afb,
    const float* __restrict__ encwsT,
    const float* __restrict__ encout,
    const int* __restrict__ alen,
    const float* __restrict__ c0buf,
    float* dech, float* ctxb, float* __restrict__ dhall, int* cnt)
{
  const int wg = blockIdx.x;      // owns units [wg*16, wg*16+16); phase2 b0 = wg
  const int u0 = wg * 16;
  const int tid = threadIdx.x;
  const int cb = tid & 15, cu = tid >> 4;
  const int rp = tid >> 3, bp = tid & 7;

  __shared__ float hc[NB*516];    // [b][h(256)|ctx(256)]
  __shared__ float Wl[64*68];
  __shared__ float gl[64*17];
  __shared__ float h2[HH];
  __shared__ float whl[AA];
  __shared__ float fwl[AA];
  __shared__ float scl[SS];
  __shared__ float red[256];
  __shared__ float sh_bmax, sh_bsum;

  if (tid < AA) fwl[tid] = afW[tid];
  const float fb0 = afb[0];
  int len = alen[wg]; len = min(max(len, 1), SS);
  float c_reg = c0buf[cb*HH + u0 + cu];

  for (int t = 0; t < TT; ++t) {
    const int rpar = t & 1, wpar = rpar ^ 1;
    const float* prow = decpre + (t*NB + cb)*1024 + u0 + cu;
    float pre0 = prow[0], pre1 = prow[256], pre2 = prow[512], pre3 = prow[768];
    // stage [h|ctx]
    const float* hsrc = dech + rpar*NB*HH;
    const float* csrc = ctxb + rpar*NB*HH;
    #pragma unroll
    for (int i = 0; i < 32; ++i) {
      int l = tid + i*256;
      int b = l >> 9, k = l & 511;
      float v = (k < HH) ? gload(hsrc + b*HH + k) : gload(csrc + b*HH + (k - HH));
      hc[b*516 + k] = v;
    }
    __syncthreads();
    // gates gemm over K=512 in chunks of 64
    float a00 = 0, a01 = 0, a10 = 0, a11 = 0;
    for (int kc = 0; kc < 8; ++kc) {
      if (kc) __syncthreads();
      #pragma unroll
      for (int i = 0; i < 16; ++i) {
        int l = tid + i*256;
        int r = l >> 6, k = l & 63;
        int grow = (r >> 4)*HH + u0 + (r & 15);
        int kk = kc*64 + k;
        Wl[r*68 + k] = (kk < HH) ? dwhh[grow*HH + kk]
                                 : dwih[grow*1280 + 1024 + (kk - HH)];
      }
      __syncthreads();
      const float4* wa4 = (const float4*)(Wl + (2*rp)*68);
      const float4* wb4 = (const float4*)(Wl + (2*rp + 1)*68);
      const float4* ha4 = (const float4*)(hc + (2*bp)*516 + kc*64);
      const float4* hb4 = (const float4*)(hc + (2*bp + 1)*516 + kc*64);
      #pragma unroll
      for (int kq = 0; kq < 16; ++kq) {
        float4 wa = wa4[kq], wb = wb4[kq], ha = ha4[kq], hbv = hb4[kq];
        a00 += wa.x*ha.x + wa.y*ha.y + wa.z*ha.z + wa.w*ha.w;
        a01 += wa.x*hbv.x + wa.y*hbv.y + wa.z*hbv.z + wa.w*hbv.w;
        a10 += wb.x*ha.x + wb.y*ha.y + wb.z*ha.z + wb.w*ha.w;
        a11 += wb.x*hbv.x + wb.y*hbv.y + wb.z*hbv.z + wb.w*hbv.w;
      }
    }
    gl[(2*rp)*17 + 2*bp]     = a00;
    gl[(2*rp)*17 + 2*bp + 1] = a01;
    gl[(2*rp + 1)*17 + 2*bp]     = a10;
    gl[(2*rp + 1)*17 + 2*bp + 1] = a11;
    __syncthreads();
    float gi = gl[(0*16 + cu)*17 + cb] + pre0;
    float gf = gl[(1*16 + cu)*17 + cb] + pre1;
    float gg = gl[(2*16 + cu)*17 + cb] + pre2;
    float go = gl[(3*16 + cu)*17 + cb] + pre3;
    float iv = sigmf(gi), fv = sigmf(gf), gv = tanhf_(gg), ov = sigmf(go);
    c_reg = fv * c_reg + iv * gv;
    float hv = ov * tanhf_(c_reg);
    gstore(dech + wpar*NB*HH + cb*HH + u0 + cu, hv);
    dhall[(t*NB + cb)*HH + u0 + cu] = hv;
    wgbar(cnt, 16);

    // ---- phase 2: attention for b0 = wg ----
    const int b0 = wg;
    h2[tid] = gload(dech + wpar*NB*HH + b0*HH + tid);
    __syncthreads();
    {
      int a = tid >> 2, kq = tid & 3;
      const float* wrow = ahW + a*HH + kq*64;
      const float* hrow = h2 + kq*64;
      float p = 0.0f;
      #pragma unroll
      for (int k = 0; k < 64; ++k) p += wrow[k]*hrow[k];
      red[tid] = p;
    }
    __syncthreads();
    if (tid < AA)
      whl[tid] = ahb[tid] + red[tid*4] + red[tid*4+1] + red[tid*4+2] + red[tid*4+3];
    __syncthreads();
    for (int s = tid; s < SS; s += 256) {
      float sc = fb0;
      #pragma unroll 8
      for (int a = 0; a < AA; ++a)
        sc += fwl[a] * tanhf_(encwsT[(b0*AA + a)*SS + s] + whl[a]);
      sc = fminf(sc, (s < len) ? 9999.0f : -9999.0f);
      scl[s] = sc;
    }
    __syncthreads();
    float mloc = -1e30f;
    for (int s = tid; s < SS; s += 256) mloc = fmaxf(mloc, scl[s]);
    red[tid] = mloc; __syncthreads();
    for (int st = 128; st; st >>= 1) {
      if (tid < st) red[tid] = fmaxf(red[tid], red[tid + st]);
      __syncthreads();
    }
    if (tid == 0) sh_bmax = red[0];
    __syncthreads();
    float bmax = sh_bmax;
    float sloc = 0.0f;
    for (int s = tid; s < SS; s += 256) {
      float p = __expf(scl[s] - bmax);
      scl[s] = p; sloc += p;
    }
    red[tid] = sloc; __syncthreads();
    for (int st = 128; st; st >>= 1) {
      if (tid < st) red[tid] += red[tid + st];
      __syncthreads();
    }
    if (tid == 0) sh_bsum = red[0];
    __syncthreads();
    float inv = 1.0f / sh_bsum;
    {
      float acc = 0.0f;
      const float* eb = encout + b0*SS*HH + tid;
      #pragma unroll 4
      for (int s = 0; s < SS; ++s) acc += scl[s] * eb[s*HH];
      gstore(ctxb + wpar*NB*HH + b0*HH + tid, acc * inv);
    }
    wgbar(cnt, 16);
  }
}

// ---------- vocab logits + per-chunk logsumexp partials ----------
__global__ __launch_bounds__(256) void k_pred(
    const float* __restrict__ dhall,
    const float* __restrict__ predW,
    const float* __restrict__ predb,
    float* __restrict__ pm, float* __restrict__ ps)
{
  const int rt = blockIdx.x;   // 48 (rows of 32)
  const int ch = blockIdx.y;   // 120 (cols of 256)
  const int tid = threadIdx.x;
  __shared__ float Al[32*260];
  __shared__ float Bl[256*17];
  #pragma unroll
  for (int i = 0; i < 32; ++i) {
    int l = tid + i*256;
    int r = l >> 8, k = l & 255;
    Al[r*260 + k] = dhall[(rt*32 + r)*256 + k];
  }
  const int v = ch*256 + tid;
  float acc[32];
  #pragma unroll
  for (int r = 0; r < 32; ++r) acc[r] = 0.0f;
  for (int kc = 0; kc < 16; ++kc) {
    __syncthreads();
    #pragma unroll
    for (int i = 0; i < 16; ++i) {
      int l = tid + i*256;
      int vv = l >> 4, kk = l & 15;
      int col = ch*256 + vv;
      Bl[vv*17 + kk] = (col < VV) ? predW[col*256 + kc*16 + kk] : 0.0f;
    }
    __syncthreads();
    float bvr[16];
    #pragma unroll
    for (int kk = 0; kk < 16; ++kk) bvr[kk] = Bl[tid*17 + kk];
    #pragma unroll
    for (int r = 0; r < 32; ++r) {
      const float4* a4 = (const float4*)(Al + r*260 + kc*16);
      float s0 = 0.0f;
      #pragma unroll
      for (int k4 = 0; k4 < 4; ++k4) {
        float4 a = a4[k4];
        s0 += a.x*bvr[4*k4] + a.y*bvr[4*k4+1] + a.z*bvr[4*k4+2] + a.w*bvr[4*k4+3];
      }
      acc[r] += s0;
    }
  }
  float bias = (v < VV) ? predb[v] : 0.0f;
  __syncthreads();
  #pragma unroll
  for (int r = 0; r < 32; ++r)
    Al[r*260 + tid] = (v < VV) ? (acc[r] + bias) : -1e30f;
  __syncthreads();
  if (tid < 32) {
    int row = rt*32 + tid;
    float m = -1e30f;
    for (int c = 0; c < 256; ++c) m = fmaxf(m, Al[tid*260 + c]);
    float ssum = 0.0f;
    for (int c = 0; c < 256; ++c) ssum += __expf(Al[tid*260 + c] - m);
    pm[row*NCHUNK + ch] = m;
    ps[row*NCHUNK + ch] = ssum;
  }
}

// ---------- final loss ----------
__global__ __launch_bounds__(256) void k_loss(
    const float* __restrict__ pm, const float* __restrict__ ps,
    const float* __restrict__ dhall,
    const float* __restrict__ predW, const float* __restrict__ predb,
    const int* __restrict__ abstr, float* __restrict__ out)
{
  const int tid = threadIdx.x;
  __shared__ float rs[256], rc[256];
  float lsum = 0.0f, lcnt = 0.0f;
  for (int row = tid; row < TT*NB; row += 256) {
    int t = row >> 4, b = row & 15;
    int tok = abstr[b*TT + t];
    float m = -1e30f;
    for (int c = 0; c < NCHUNK; ++c) m = fmaxf(m, pm[row*NCHUNK + c]);
    float ss = 0.0f;
    for (int c = 0; c < NCHUNK; ++c) ss += ps[row*NCHUNK + c] * __expf(pm[row*NCHUNK + c] - m);
    float lse = m + __logf(ss);
    float tl = predb[tok];
    const float* hrow = dhall + row*256;
    const float* wrow = predW + tok*256;
    for (int k = 0; k < 256; ++k) tl += hrow[k] * wrow[k];
    if (tok != 0) { lsum += lse - tl; lcnt += 1.0f; }
  }
  rs[tid] = lsum; rc[tid] = lcnt;
  __syncthreads();
  for (int st = 128; st; st >>= 1) {
    if (tid < st) { rs[tid] += rs[tid + st]; rc[tid] += rc[tid + st]; }
    __syncthreads();
  }
  if (tid == 0) out[0] = rs[0] / fmaxf(rc[0], 1.0f);
}

// ---------- launch ----------
extern "C" void kernel_launch(void* const* d_in, const int* in_sizes, int n_in,
                              void* d_out, int out_size, void* d_ws, size_t ws_size,
                              hipStream_t stream) {
  const float* emb   = (const float*)d_in[0];
  const int* article = (const int*)d_in[1];
  const int* alen    = (const int*)d_in[2];
  const int* abstr   = (const int*)d_in[3];
  const float* eWihF = (const float*)d_in[4];
  const float* eWhhF = (const float*)d_in[5];
  const float* ebF   = (const float*)d_in[6];
  const float* eWihB = (const float*)d_in[7];
  const float* eWhhB = (const float*)d_in[8];
  const float* ebB   = (const float*)d_in[9];
  const float* dWih  = (const float*)d_in[10];
  const float* dWhh  = (const float*)d_in[11];
  const float* db    = (const float*)d_in[12];
  const float* pW    = (const float*)d_in[13];
  const float* pb    = (const float*)d_in[14];
  const float* asW   = (const float*)d_in[15];
  const float* asb   = (const float*)d_in[16];
  const float* ahW   = (const float*)d_in[17];
  const float* ahb   = (const float*)d_in[18];
  const float* afW   = (const float*)d_in[19];
  const float* afb   = (const float*)d_in[20];
  float* out = (float*)d_out;

  float* w = (float*)d_ws;
  size_t o = 0;
  float* xcomb  = w + o; o += (size_t)SS*NB*1024;
  float* encout = w + o; o += (size_t)NB*SS*HH;
  float* encwsT = w + o; o += (size_t)NB*AA*SS;
  float* decpre = w + o; o += (size_t)TT*NB*1024;
  float* dhall  = w + o; o += (size_t)TT*NB*HH;
  float* hg     = w + o; o += 2*2*NB*HL;
  float* dech   = w + o; o += 2*NB*HH;
  float* ctxb   = w + o; o += 2*NB*HH;
  float* c0buf  = w + o; o += NB*HH;
  float* pm     = w + o; o += (size_t)TT*NB*NCHUNK;
  float* ps     = w + o; o += (size_t)TT*NB*NCHUNK;
  int* cnts = (int*)(w + o); o += 64;

  k_init<<<1, 256, 0, stream>>>(hg, ctxb, cnts);
  k_embproj_enc<<<dim3(200, 8), 256, 0, stream>>>(emb, article, eWihF, eWihB, ebF, ebB, xcomb);
  k_embproj_dec<<<dim3(48, 8), 256, 0, stream>>>(emb, abstr, dWih, db, decpre);
  k_encoder<<<16, 256, 0, stream>>>(xcomb, eWhhF, eWhhB, encout, hg, dech, c0buf, cnts);
  k_encws<<<200, 256, 0, stream>>>(encout, asW, asb, encwsT);
  k_decoder<<<16, 256, 0, stream>>>(decpre, dWhh, dWih, ahW, ahb, afW, afb,
                                    encwsT, encout, alen, c0buf, dech, ctxb, dhall, cnts + 2);
  k_pred<<<dim3(48, 120), 256, 0, stream>>>(dhall, pW, pb, pm, ps);
  k_loss<<<1, 256, 0, stream>>>(pm, ps, dhall, pW, pb, abstr, out);
}

// Round 2
// 6343.624 us; speedup vs baseline: 1.9337x; 1.9337x over previous
//
#include <hip/hip_runtime.h>
#include <cmath>

#define NB 16      // batch
#define SS 400     // source len
#define TT 96      // target len
#define HL 128     // LSTM per dir
#define HH 256     // decoder hidden (2*HL)
#define AA 64      // attn dim
#define VV 30611   // vocab
#define START_TOK 101
#define NCHUNK 120 // vocab chunks of 256

// ---------- helpers ----------
__device__ __forceinline__ float gload(const float* p) {
  return __hip_atomic_load(p, __ATOMIC_RELAXED, __HIP_MEMORY_SCOPE_AGENT);
}
__device__ __forceinline__ void gstore(float* p, float v) {
  __hip_atomic_store(p, v, __ATOMIC_RELAXED, __HIP_MEMORY_SCOPE_AGENT);
}
// multi-WG barrier: monotonic counter, nwg workgroups participate
__device__ __forceinline__ void wgbar(int* cnt, int nwg) {
  __syncthreads();
  if (threadIdx.x == 0) {
    __threadfence();
    int old = atomicAdd(cnt, 1);
    int target = (old / nwg + 1) * nwg;
    while (__hip_atomic_load(cnt, __ATOMIC_RELAXED, __HIP_MEMORY_SCOPE_AGENT) < target)
      __builtin_amdgcn_s_sleep(2);
  }
  __syncthreads();
  __threadfence();
}
__device__ __forceinline__ float sigmf(float x) { return 1.0f / (1.0f + __expf(-x)); }
__device__ __forceinline__ float tanhf_(float x) {
  float xc = fminf(fmaxf(x, -15.0f), 15.0f);
  return 1.0f - 2.0f / (__expf(2.0f * xc) + 1.0f);
}

// ---------- init: zero h publish buffers & barrier counters ----------
__global__ __launch_bounds__(256) void k_init(float* hpub, int* cnts) {
  for (int i = threadIdx.x; i < 2*NB*HH; i += 256) hpub[i] = 0.0f;
  for (int i = threadIdx.x; i < 16*16; i += 256) cnts[i] = 0;
}

// ---------- encoder input projection: xcomb[s*16+b][n], n = dir*512 + gate row ----------
__global__ __launch_bounds__(256) void k_embproj_enc(
    const float* __restrict__ emb, const int* __restrict__ article,
    const float* __restrict__ wihf, const float* __restrict__ wihb,
    const float* __restrict__ bf, const float* __restrict__ bb,
    float* __restrict__ xcomb)
{
  const int rt = blockIdx.x;        // 200 row tiles of 32
  const int n0 = blockIdx.y * 128;  // 8 col tiles
  const int tid = threadIdx.x;
  __shared__ float Alds[32*36];
  __shared__ float Blds[32*129];    // [kk][nn]
  __shared__ int toklds[32];
  if (tid < 32) {
    int R = rt*32 + tid;            // R = s*16 + b
    int s = R >> 4, b = R & 15;
    toklds[tid] = article[b*SS + s];
  }
  __syncthreads();
  float acc[16];
  #pragma unroll
  for (int q = 0; q < 16; ++q) acc[q] = 0.0f;
  const int nn = tid & 127, rg = tid >> 7;
  for (int kc = 0; kc < 1024; kc += 32) {
    #pragma unroll
    for (int i = 0; i < 4; ++i) {
      int l = tid + i*256;
      int rr = l >> 5, kk = l & 31;
      Alds[rr*36 + kk] = emb[toklds[rr]*1024 + kc + kk];
    }
    #pragma unroll
    for (int i = 0; i < 16; ++i) {
      int l = tid + i*256;
      int bn = l >> 5, kk = l & 31;
      int n = n0 + bn;
      const float* src = (n < 512) ? (wihf + n*1024) : (wihb + (n-512)*1024);
      Blds[kk*129 + bn] = src[kc + kk];
    }
    __syncthreads();
    float bvr[32];
    #pragma unroll
    for (int kk = 0; kk < 32; ++kk) bvr[kk] = Blds[kk*129 + nn];
    #pragma unroll
    for (int q = 0; q < 16; ++q) {
      const float4* a4 = (const float4*)(Alds + (rg*16 + q)*36);
      float s0 = 0.0f;
      #pragma unroll
      for (int k4 = 0; k4 < 8; ++k4) {
        float4 a = a4[k4];
        s0 += a.x*bvr[4*k4] + a.y*bvr[4*k4+1] + a.z*bvr[4*k4+2] + a.w*bvr[4*k4+3];
      }
      acc[q] += s0;
    }
    __syncthreads();
  }
  int n = n0 + nn;
  float bias = (n < 512) ? bf[n] : bb[n-512];
  #pragma unroll
  for (int q = 0; q < 16; ++q) {
    int R = rt*32 + rg*16 + q;
    xcomb[R*1024 + n] = acc[q] + bias;
  }
}

// ---------- decoder embedding projection: decpre[t*16+b][n] (dec_b folded) ----------
__global__ __launch_bounds__(256) void k_embproj_dec(
    const float* __restrict__ emb, const int* __restrict__ abstr,
    const float* __restrict__ dwih, const float* __restrict__ db,
    float* __restrict__ decpre)
{
  const int rt = blockIdx.x;        // 48 row tiles of 32
  const int n0 = blockIdx.y * 128;  // 8 col tiles
  const int tid = threadIdx.x;
  __shared__ float Alds[32*36];
  __shared__ float Blds[32*129];
  __shared__ int toklds[32];
  if (tid < 32) {
    int R = rt*32 + tid;            // R = t*16 + b
    int t = R >> 4, b = R & 15;
    toklds[tid] = (t == 0) ? START_TOK : abstr[b*TT + t - 1];
  }
  __syncthreads();
  float acc[16];
  #pragma unroll
  for (int q = 0; q < 16; ++q) acc[q] = 0.0f;
  const int nn = tid & 127, rg = tid >> 7;
  for (int kc = 0; kc < 1024; kc += 32) {
    #pragma unroll
    for (int i = 0; i < 4; ++i) {
      int l = tid + i*256;
      int rr = l >> 5, kk = l & 31;
      Alds[rr*36 + kk] = emb[toklds[rr]*1024 + kc + kk];
    }
    #pragma unroll
    for (int i = 0; i < 16; ++i) {
      int l = tid + i*256;
      int bn = l >> 5, kk = l & 31;
      int n = n0 + bn;
      Blds[kk*129 + bn] = dwih[n*1280 + kc + kk];
    }
    __syncthreads();
    float bvr[32];
    #pragma unroll
    for (int kk = 0; kk < 32; ++kk) bvr[kk] = Blds[kk*129 + nn];
    #pragma unroll
    for (int q = 0; q < 16; ++q) {
      const float4* a4 = (const float4*)(Alds + (rg*16 + q)*36);
      float s0 = 0.0f;
      #pragma unroll
      for (int k4 = 0; k4 < 8; ++k4) {
        float4 a = a4[k4];
        s0 += a.x*bvr[4*k4] + a.y*bvr[4*k4+1] + a.z*bvr[4*k4+2] + a.w*bvr[4*k4+3];
      }
      acc[q] += s0;
    }
    __syncthreads();
  }
  int n = n0 + nn;
  float bias = db[n];
  #pragma unroll
  for (int q = 0; q < 16; ++q) {
    int R = rt*32 + rg*16 + q;
    decpre[R*1024 + n] = acc[q] + bias;
  }
}

// ---------- encoder: 1 WG per (batch, dir); weights in registers; LDS-only recurrence ----------
__global__ __launch_bounds__(512) void k_encoder(
    const float* __restrict__ xcomb,
    const float* __restrict__ whhf, const float* __restrict__ whhb,
    float* __restrict__ encout,
    float* __restrict__ hpub0,     // [16][256]: decoder h0 (parity-0 publish buffer)
    float* __restrict__ c0buf)     // [16][256]
{
  const int b = blockIdx.x & 15, dir = blockIdx.x >> 4;
  const int t = threadIdx.x;      // gate row 0..511 (i|f|g|o blocks of 128)
  const float* __restrict__ Whh = dir ? whhb : whhf;
  // W row in registers: 128 floats
  float4 wr[32];
  #pragma unroll
  for (int j = 0; j < 32; ++j)
    wr[j] = *(const float4*)(Whh + t*128 + j*4);
  __shared__ float hl[128];
  __shared__ float gl[512];
  float c_reg = 0.0f;
  if (t < 128) hl[t] = 0.0f;
  __syncthreads();
  for (int s = 0; s < SS; ++s) {
    const int sf = dir ? (SS-1-s) : s;
    float xv = xcomb[(sf*NB + b)*1024 + dir*512 + t];
    float a0 = 0.f, a1 = 0.f, a2 = 0.f, a3 = 0.f;
    #pragma unroll
    for (int j = 0; j < 32; j += 4) {
      float4 h0 = *(const float4*)(hl + j*4);
      float4 h1 = *(const float4*)(hl + j*4 + 4);
      float4 h2 = *(const float4*)(hl + j*4 + 8);
      float4 h3 = *(const float4*)(hl + j*4 + 12);
      a0 += wr[j].x*h0.x + wr[j].y*h0.y + wr[j].z*h0.z + wr[j].w*h0.w;
      a1 += wr[j+1].x*h1.x + wr[j+1].y*h1.y + wr[j+1].z*h1.z + wr[j+1].w*h1.w;
      a2 += wr[j+2].x*h2.x + wr[j+2].y*h2.y + wr[j+2].z*h2.z + wr[j+2].w*h2.w;
      a3 += wr[j+3].x*h3.x + wr[j+3].y*h3.y + wr[j+3].z*h3.z + wr[j+3].w*h3.w;
    }
    gl[t] = (a0 + a1) + (a2 + a3) + xv;
    __syncthreads();
    if (t < 128) {
      float gi = gl[t], gf = gl[128+t], gg = gl[256+t], go = gl[384+t];
      float iv = sigmf(gi), fv = sigmf(gf), gv = tanhf_(gg), ov = sigmf(go);
      c_reg = fv*c_reg + iv*gv;
      float hv = ov*tanhf_(c_reg);
      hl[t] = hv;
      encout[(b*SS + sf)*HH + dir*HL + t] = hv;
    }
    __syncthreads();
  }
  if (t < 128) {
    hpub0[b*HH + dir*HL + t] = hl[t];
    c0buf[b*HH + dir*HL + t] = c_reg;
  }
}

// ---------- enc_ws = enc_out @ attn_s_W.T + b, stored transposed [b][a][s] ----------
__global__ __launch_bounds__(256) void k_encws(
    const float* __restrict__ encout,
    const float* __restrict__ asW, const float* __restrict__ asb,
    float* __restrict__ encwsT)
{
  const int rt = blockIdx.x;  // 200 tiles of 32 rows (row = b*400+s)
  const int tid = threadIdx.x;
  __shared__ float Al[32*260];
  #pragma unroll
  for (int i = 0; i < 32; ++i) {
    int l = tid + i*256;
    int r = l >> 8, k = l & 255;
    Al[r*260 + k] = encout[(rt*32 + r)*256 + k];
  }
  __syncthreads();
  const int a = tid & 63, rg = tid >> 6;
  float acc[8];
  #pragma unroll
  for (int q = 0; q < 8; ++q) acc[q] = 0.0f;
  const float4* w4 = (const float4*)(asW + a*256);
  for (int k4 = 0; k4 < 64; ++k4) {
    float4 w = w4[k4];
    #pragma unroll
    for (int q = 0; q < 8; ++q) {
      const float4* a4 = (const float4*)(Al + (rg*8 + q)*260);
      float4 av = a4[k4];
      acc[q] += av.x*w.x + av.y*w.y + av.z*w.z + av.w*w.w;
    }
  }
  float bias = asb[a];
  #pragma unroll
  for (int q = 0; q < 8; ++q) {
    int row = rt*32 + rg*8 + q;
    int b = row / SS, s = row - b*SS;
    encwsT[(b*AA + a)*SS + s] = acc[q] + bias;
  }
}

// ---------- decoder: WG (g,b) = 8 unit-groups x 16 batches; weights in regs; 1 barrier/step ----------
__global__ __launch_bounds__(512) void k_decoder(
    const float* __restrict__ decpre,
    const float* __restrict__ dwhh,   // [1024][256]
    const float* __restrict__ dwih,   // [1024][1280]
    const float* __restrict__ ahW, const float* __restrict__ ahb,
    const float* __restrict__ afW, const float* __restrict__ afb,
    const float* __restrict__ encwsT, // [b*64+a][400]
    const float* __restrict__ encout, // [b*400+s][256]
    const int* __restrict__ alen,
    const float* __restrict__ c0buf,  // [16][256]
    float* hpub,                      // [2][16][256], parity 0 pre-filled with h0
    float* __restrict__ dhall,        // [96*16][256]
    int* cnts)
{
  const int wg = blockIdx.x;
  const int g = wg >> 4, b = wg & 15;   // unit-group, batch
  const int t = threadIdx.x;            // 512
  const int r = t & 127, ks = t >> 7;   // row-in-WG, K-split (4 x 128)
  const int q = r >> 5, uu = r & 31;
  const int grow = q*256 + g*32 + uu;   // global gate row
  int* cnt = cnts + b*16;

  // weight slice in registers: W[grow][ks*128 .. ks*128+128)
  float4 wr[32];
  #pragma unroll
  for (int j = 0; j < 32; ++j) {
    int k = ks*128 + j*4;
    wr[j] = (k < 256) ? *(const float4*)(dwhh + grow*256 + k)
                      : *(const float4*)(dwih + grow*1280 + 1024 + (k - 256));
  }

  __shared__ float hc[512];        // [h(256) | ctx(256)]
  __shared__ float part[4][132];
  __shared__ float gates[128];
  __shared__ float wh[64];
  __shared__ float whp[8][68];
  __shared__ float fwl[64];
  __shared__ float scl[400];
  __shared__ float rwave[8];
  __shared__ float cpart[8][260];
  __shared__ float sh_max, sh_sum;

  if (t < 64) fwl[t] = afW[t];
  const float fb0 = afb[0];
  int len = alen[b]; len = min(max(len, 1), SS);
  float c_reg = (t < 32) ? c0buf[b*HH + g*32 + t] : 0.0f;

  // pre-stage h(0) and ctx(0)=0
  if (t < 256) { hc[t] = gload(hpub + b*HH + t); hc[256 + t] = 0.0f; }
  __syncthreads();

  for (int tt = 0; tt < TT; ++tt) {
    const int wp = (tt & 1) ^ 1;
    // ---- gates GEMM: thread = (row r, K-slice ks) ----
    float a0 = 0.f, a1 = 0.f, a2 = 0.f, a3 = 0.f;
    const float* hs = hc + ks*128;
    #pragma unroll
    for (int j = 0; j < 32; j += 4) {
      float4 h0 = *(const float4*)(hs + j*4);
      float4 h1 = *(const float4*)(hs + j*4 + 4);
      float4 h2 = *(const float4*)(hs + j*4 + 8);
      float4 h3 = *(const float4*)(hs + j*4 + 12);
      a0 += wr[j].x*h0.x + wr[j].y*h0.y + wr[j].z*h0.z + wr[j].w*h0.w;
      a1 += wr[j+1].x*h1.x + wr[j+1].y*h1.y + wr[j+1].z*h1.z + wr[j+1].w*h1.w;
      a2 += wr[j+2].x*h2.x + wr[j+2].y*h2.y + wr[j+2].z*h2.z + wr[j+2].w*h2.w;
      a3 += wr[j+3].x*h3.x + wr[j+3].y*h3.y + wr[j+3].z*h3.z + wr[j+3].w*h3.w;
    }
    part[ks][r] = (a0 + a1) + (a2 + a3);
    __syncthreads();
    if (t < 128) {
      float gv = part[0][t] + part[1][t] + part[2][t] + part[3][t]
               + decpre[(tt*NB + b)*1024 + (t >> 5)*256 + g*32 + (t & 31)];
      gates[t] = gv;
    }
    __syncthreads();
    // ---- cell update: threads 0..31 own units g*32+t ----
    if (t < 32) {
      float gi = gates[t], gf = gates[32+t], gg = gates[64+t], go = gates[96+t];
      float iv = sigmf(gi), fv = sigmf(gf), gv = tanhf_(gg), ov = sigmf(go);
      c_reg = fv*c_reg + iv*gv;
      float hv = ov*tanhf_(c_reg);
      int u = g*32 + t;
      gstore(hpub + wp*NB*HH + b*HH + u, hv);
      dhall[(tt*NB + b)*HH + u] = hv;
    }
    wgbar(cnt, 8);
    // ---- stage full h_new (redundant per WG from here on) ----
    if (t < 256) hc[t] = gload(hpub + wp*NB*HH + b*HH + t);
    __syncthreads();
    // ---- wh[a] = ahb + ahW @ h_new ----
    {
      int a = t >> 3, kq = t & 7;
      float p = 0.f;
      #pragma unroll
      for (int k = 0; k < 32; ++k) p += ahW[a*HH + kq*32 + k] * hc[kq*32 + k];
      whp[kq][a] = p;
    }
    __syncthreads();
    if (t < 64) {
      float s0 = 0.f;
      #pragma unroll
      for (int kq = 0; kq < 8; ++kq) s0 += whp[kq][t];
      wh[t] = ahb[t] + s0;
    }
    __syncthreads();
    // ---- scores ----
    float sc = -1e30f;
    if (t < SS) {
      sc = fb0;
      #pragma unroll 8
      for (int a = 0; a < AA; ++a)
        sc += fwl[a] * tanhf_(encwsT[(b*AA + a)*SS + t] + wh[a]);
      sc = fminf(sc, (t < len) ? 9999.0f : -9999.0f);
    }
    // ---- softmax: wave shuffle + cross-wave ----
    float m = sc;
    #pragma unroll
    for (int o = 32; o; o >>= 1) m = fmaxf(m, __shfl_xor(m, o));
    if ((t & 63) == 0) rwave[t >> 6] = m;
    __syncthreads();
    if (t == 0) {
      float mm = rwave[0];
      #pragma unroll
      for (int i = 1; i < 8; ++i) mm = fmaxf(mm, rwave[i]);
      sh_max = mm;
    }
    __syncthreads();
    float bmax = sh_max;
    float e = 0.f;
    if (t < SS) { e = __expf(sc - bmax); scl[t] = e; }
    float ssum = e;
    #pragma unroll
    for (int o = 32; o; o >>= 1) ssum += __shfl_xor(ssum, o);
    if ((t & 63) == 0) rwave[t >> 6] = ssum;
    __syncthreads();
    if (t == 0) {
      float s0 = 0.f;
      #pragma unroll
      for (int i = 0; i < 8; ++i) s0 += rwave[i];
      sh_sum = s0;
    }
    __syncthreads();
    const float inv = 1.0f / sh_sum;
    // ---- ctx: thread (sg = t>>6, dv = t&63): 50 s-values, float4 over d ----
    {
      const int sg = t >> 6, dv = t & 63;
      float4 acc4 = make_float4(0.f, 0.f, 0.f, 0.f);
      const float* eb = encout + (b*SS + sg*50)*HH + dv*4;
      #pragma unroll 5
      for (int i = 0; i < 50; ++i) {
        float w = scl[sg*50 + i];
        float4 e4 = *(const float4*)(eb + i*HH);
        acc4.x += w*e4.x; acc4.y += w*e4.y; acc4.z += w*e4.z; acc4.w += w*e4.w;
      }
      *(float4*)(&cpart[sg][dv*4]) = acc4;
    }
    __syncthreads();
    if (t < 256) {
      float s0 = 0.f;
      #pragma unroll
      for (int sg = 0; sg < 8; ++sg) s0 += cpart[sg][t];
      hc[256 + t] = s0 * inv;
    }
    __syncthreads();
  }
}

// ---------- vocab logits + per-chunk logsumexp partials ----------
__global__ __launch_bounds__(256) void k_pred(
    const float* __restrict__ dhall,
    const float* __restrict__ predW,
    const float* __restrict__ predb,
    float* __restrict__ pm, float* __restrict__ ps)
{
  const int rt = blockIdx.x;   // 48 (rows of 32)
  const int ch = blockIdx.y;   // 120 (cols of 256)
  const int tid = threadIdx.x;
  __shared__ float Al[32*260];
  __shared__ float Bl[256*17];
  #pragma unroll
  for (int i = 0; i < 32; ++i) {
    int l = tid + i*256;
    int r = l >> 8, k = l & 255;
    Al[r*260 + k] = dhall[(rt*32 + r)*256 + k];
  }
  const int v = ch*256 + tid;
  float acc[32];
  #pragma unroll
  for (int r = 0; r < 32; ++r) acc[r] = 0.0f;
  for (int kc = 0; kc < 16; ++kc) {
    __syncthreads();
    #pragma unroll
    for (int i = 0; i < 16; ++i) {
      int l = tid + i*256;
      int vv = l >> 4, kk = l & 15;
      int col = ch*256 + vv;
      Bl[vv*17 + kk] = (col < VV) ? predW[col*256 + kc*16 + kk] : 0.0f;
    }
    __syncthreads();
    float bvr[16];
    #pragma unroll
    for (int kk = 0; kk < 16; ++kk) bvr[kk] = Bl[tid*17 + kk];
    #pragma unroll
    for (int r = 0; r < 32; ++r) {
      const float4* a4 = (const float4*)(Al + r*260 + kc*16);
      float s0 = 0.0f;
      #pragma unroll
      for (int k4 = 0; k4 < 4; ++k4) {
        float4 a = a4[k4];
        s0 += a.x*bvr[4*k4] + a.y*bvr[4*k4+1] + a.z*bvr[4*k4+2] + a.w*bvr[4*k4+3];
      }
      acc[r] += s0;
    }
  }
  float bias = (v < VV) ? predb[v] : 0.0f;
  __syncthreads();
  #pragma unroll
  for (int r = 0; r < 32; ++r)
    Al[r*260 + tid] = (v < VV) ? (acc[r] + bias) : -1e30f;
  __syncthreads();
  if (tid < 32) {
    int row = rt*32 + tid;
    float m = -1e30f;
    for (int c = 0; c < 256; ++c) m = fmaxf(m, Al[tid*260 + c]);
    float ssum = 0.0f;
    for (int c = 0; c < 256; ++c) ssum += __expf(Al[tid*260 + c] - m);
    pm[row*NCHUNK + ch] = m;
    ps[row*NCHUNK + ch] = ssum;
  }
}

// ---------- final loss ----------
__global__ __launch_bounds__(256) void k_loss(
    const float* __restrict__ pm, const float* __restrict__ ps,
    const float* __restrict__ dhall,
    const float* __restrict__ predW, const float* __restrict__ predb,
    const int* __restrict__ abstr, float* __restrict__ out)
{
  const int tid = threadIdx.x;
  __shared__ float rs[256], rc[256];
  float lsum = 0.0f, lcnt = 0.0f;
  for (int row = tid; row < TT*NB; row += 256) {
    int t = row >> 4, b = row & 15;
    int tok = abstr[b*TT + t];
    float m = -1e30f;
    for (int c = 0; c < NCHUNK; ++c) m = fmaxf(m, pm[row*NCHUNK + c]);
    float ss = 0.0f;
    for (int c = 0; c < NCHUNK; ++c) ss += ps[row*NCHUNK + c] * __expf(pm[row*NCHUNK + c] - m);
    float lse = m + __logf(ss);
    float tl = predb[tok];
    const float* hrow = dhall + row*256;
    const float* wrow = predW + tok*256;
    for (int k = 0; k < 256; ++k) tl += hrow[k] * wrow[k];
    if (tok != 0) { lsum += lse - tl; lcnt += 1.0f; }
  }
  rs[tid] = lsum; rc[tid] = lcnt;
  __syncthreads();
  for (int st = 128; st; st >>= 1) {
    if (tid < st) { rs[tid] += rs[tid + st]; rc[tid] += rc[tid + st]; }
    __syncthreads();
  }
  if (tid == 0) out[0] = rs[0] / fmaxf(rc[0], 1.0f);
}

// ---------- launch ----------
extern "C" void kernel_launch(void* const* d_in, const int* in_sizes, int n_in,
                              void* d_out, int out_size, void* d_ws, size_t ws_size,
                              hipStream_t stream) {
  const float* emb   = (const float*)d_in[0];
  const int* article = (const int*)d_in[1];
  const int* alen    = (const int*)d_in[2];
  const int* abstr   = (const int*)d_in[3];
  const float* eWihF = (const float*)d_in[4];
  const float* eWhhF = (const float*)d_in[5];
  const float* ebF   = (const float*)d_in[6];
  const float* eWihB = (const float*)d_in[7];
  const float* eWhhB = (const float*)d_in[8];
  const float* ebB   = (const float*)d_in[9];
  const float* dWih  = (const float*)d_in[10];
  const float* dWhh  = (const float*)d_in[11];
  const float* db    = (const float*)d_in[12];
  const float* pW    = (const float*)d_in[13];
  const float* pb    = (const float*)d_in[14];
  const float* asW   = (const float*)d_in[15];
  const float* asb   = (const float*)d_in[16];
  const float* ahW   = (const float*)d_in[17];
  const float* ahb   = (const float*)d_in[18];
  const float* afW   = (const float*)d_in[19];
  const float* afb   = (const float*)d_in[20];
  float* out = (float*)d_out;

  float* w = (float*)d_ws;
  size_t o = 0;
  float* xcomb  = w + o; o += (size_t)SS*NB*1024;
  float* encout = w + o; o += (size_t)NB*SS*HH;
  float* encwsT = w + o; o += (size_t)NB*AA*SS;
  float* decpre = w + o; o += (size_t)TT*NB*1024;
  float* dhall  = w + o; o += (size_t)TT*NB*HH;
  float* hpub   = w + o; o += 2*NB*HH;
  float* c0buf  = w + o; o += NB*HH;
  float* pm     = w + o; o += (size_t)TT*NB*NCHUNK;
  float* ps     = w + o; o += (size_t)TT*NB*NCHUNK;
  int* cnts = (int*)(w + o); o += 256;

  k_init<<<1, 256, 0, stream>>>(hpub, cnts);
  k_embproj_enc<<<dim3(200, 8), 256, 0, stream>>>(emb, article, eWihF, eWihB, ebF, ebB, xcomb);
  k_embproj_dec<<<dim3(48, 8), 256, 0, stream>>>(emb, abstr, dWih, db, decpre);
  k_encoder<<<32, 512, 0, stream>>>(xcomb, eWhhF, eWhhB, encout, hpub, c0buf);
  k_encws<<<200, 256, 0, stream>>>(encout, asW, asb, encwsT);
  k_decoder<<<128, 512, 0, stream>>>(decpre, dWhh, dWih, ahW, ahb, afW, afb,
                                     encwsT, encout, alen, c0buf, hpub, dhall, cnts);
  k_pred<<<dim3(48, 120), 256, 0, stream>>>(dhall, pW, pb, pm, ps);
  k_loss<<<1, 256, 0, stream>>>(pm, ps, dhall, pW, pb, abstr, out);
}

// Round 3
// 6114.221 us; speedup vs baseline: 2.0062x; 1.0375x over previous
//
#include <hip/hip_runtime.h>
#include <cmath>

#define NB 16      // batch
#define SS 400     // source len
#define TT 96      // target len
#define HL 128     // LSTM per dir
#define HH 256     // decoder hidden (2*HL)
#define AA 64      // attn dim
#define VV 30611   // vocab
#define START_TOK 101
#define NCHUNK 120 // vocab chunks of 256

// keep a loaded float4 live in VGPRs (forbid rematerialization / load sinking)
#define PIN4(v) asm volatile("" : "+v"((v).x), "+v"((v).y), "+v"((v).z), "+v"((v).w))

// ---------- helpers ----------
__device__ __forceinline__ float gload(const float* p) {
  return __hip_atomic_load(p, __ATOMIC_RELAXED, __HIP_MEMORY_SCOPE_AGENT);
}
__device__ __forceinline__ void gstore(float* p, float v) {
  __hip_atomic_store(p, v, __ATOMIC_RELAXED, __HIP_MEMORY_SCOPE_AGENT);
}
// multi-WG barrier: monotonic counter, nwg workgroups participate
__device__ __forceinline__ void wgbar(int* cnt, int nwg) {
  __syncthreads();
  if (threadIdx.x == 0) {
    __threadfence();
    int old = atomicAdd(cnt, 1);
    int target = (old / nwg + 1) * nwg;
    while (__hip_atomic_load(cnt, __ATOMIC_RELAXED, __HIP_MEMORY_SCOPE_AGENT) < target)
      __builtin_amdgcn_s_sleep(2);
  }
  __syncthreads();
  __threadfence();
}
__device__ __forceinline__ float sigmf(float x) { return 1.0f / (1.0f + __expf(-x)); }
__device__ __forceinline__ float tanhf_(float x) {
  float xc = fminf(fmaxf(x, -15.0f), 15.0f);
  return 1.0f - 2.0f / (__expf(2.0f * xc) + 1.0f);
}

// ---------- init: zero h publish buffers, barrier counters, loss partials ----------
__global__ __launch_bounds__(256) void k_init(float* hpub, int* cnts, float* lpart) {
  for (int i = threadIdx.x; i < 2*NB*HH; i += 256) hpub[i] = 0.0f;
  for (int i = threadIdx.x; i < 16*16; i += 256) cnts[i] = 0;
  if (threadIdx.x < 16) lpart[threadIdx.x] = 0.0f;
}

// ---------- encoder input projection: xcomb[s*16+b][n], n = dir*512 + gate row ----------
__global__ __launch_bounds__(256) void k_embproj_enc(
    const float* __restrict__ emb, const int* __restrict__ article,
    const float* __restrict__ wihf, const float* __restrict__ wihb,
    const float* __restrict__ bf, const float* __restrict__ bb,
    float* __restrict__ xcomb)
{
  const int rt = blockIdx.x;        // 200 row tiles of 32
  const int n0 = blockIdx.y * 128;  // 8 col tiles
  const int tid = threadIdx.x;
  __shared__ float Alds[32*36];
  __shared__ float Blds[32*129];    // [kk][nn]
  __shared__ int toklds[32];
  if (tid < 32) {
    int R = rt*32 + tid;            // R = s*16 + b
    int s = R >> 4, b = R & 15;
    toklds[tid] = article[b*SS + s];
  }
  __syncthreads();
  float acc[16];
  #pragma unroll
  for (int q = 0; q < 16; ++q) acc[q] = 0.0f;
  const int nn = tid & 127, rg = tid >> 7;
  for (int kc = 0; kc < 1024; kc += 32) {
    #pragma unroll
    for (int i = 0; i < 4; ++i) {
      int l = tid + i*256;
      int rr = l >> 5, kk = l & 31;
      Alds[rr*36 + kk] = emb[toklds[rr]*1024 + kc + kk];
    }
    #pragma unroll
    for (int i = 0; i < 16; ++i) {
      int l = tid + i*256;
      int bn = l >> 5, kk = l & 31;
      int n = n0 + bn;
      const float* src = (n < 512) ? (wihf + n*1024) : (wihb + (n-512)*1024);
      Blds[kk*129 + bn] = src[kc + kk];
    }
    __syncthreads();
    float bvr[32];
    #pragma unroll
    for (int kk = 0; kk < 32; ++kk) bvr[kk] = Blds[kk*129 + nn];
    #pragma unroll
    for (int q = 0; q < 16; ++q) {
      const float4* a4 = (const float4*)(Alds + (rg*16 + q)*36);
      float s0 = 0.0f;
      #pragma unroll
      for (int k4 = 0; k4 < 8; ++k4) {
        float4 a = a4[k4];
        s0 += a.x*bvr[4*k4] + a.y*bvr[4*k4+1] + a.z*bvr[4*k4+2] + a.w*bvr[4*k4+3];
      }
      acc[q] += s0;
    }
    __syncthreads();
  }
  int n = n0 + nn;
  float bias = (n < 512) ? bf[n] : bb[n-512];
  #pragma unroll
  for (int q = 0; q < 16; ++q) {
    int R = rt*32 + rg*16 + q;
    xcomb[R*1024 + n] = acc[q] + bias;
  }
}

// ---------- decoder embedding projection: decpre[t*16+b][n] (dec_b folded) ----------
__global__ __launch_bounds__(256) void k_embproj_dec(
    const float* __restrict__ emb, const int* __restrict__ abstr,
    const float* __restrict__ dwih, const float* __restrict__ db,
    float* __restrict__ decpre)
{
  const int rt = blockIdx.x;        // 48 row tiles of 32
  const int n0 = blockIdx.y * 128;  // 8 col tiles
  const int tid = threadIdx.x;
  __shared__ float Alds[32*36];
  __shared__ float Blds[32*129];
  __shared__ int toklds[32];
  if (tid < 32) {
    int R = rt*32 + tid;            // R = t*16 + b
    int t = R >> 4, b = R & 15;
    toklds[tid] = (t == 0) ? START_TOK : abstr[b*TT + t - 1];
  }
  __syncthreads();
  float acc[16];
  #pragma unroll
  for (int q = 0; q < 16; ++q) acc[q] = 0.0f;
  const int nn = tid & 127, rg = tid >> 7;
  for (int kc = 0; kc < 1024; kc += 32) {
    #pragma unroll
    for (int i = 0; i < 4; ++i) {
      int l = tid + i*256;
      int rr = l >> 5, kk = l & 31;
      Alds[rr*36 + kk] = emb[toklds[rr]*1024 + kc + kk];
    }
    #pragma unroll
    for (int i = 0; i < 16; ++i) {
      int l = tid + i*256;
      int bn = l >> 5, kk = l & 31;
      int n = n0 + bn;
      Blds[kk*129 + bn] = dwih[n*1280 + kc + kk];
    }
    __syncthreads();
    float bvr[32];
    #pragma unroll
    for (int kk = 0; kk < 32; ++kk) bvr[kk] = Blds[kk*129 + nn];
    #pragma unroll
    for (int q = 0; q < 16; ++q) {
      const float4* a4 = (const float4*)(Alds + (rg*16 + q)*36);
      float s0 = 0.0f;
      #pragma unroll
      for (int k4 = 0; k4 < 8; ++k4) {
        float4 a = a4[k4];
        s0 += a.x*bvr[4*k4] + a.y*bvr[4*k4+1] + a.z*bvr[4*k4+2] + a.w*bvr[4*k4+3];
      }
      acc[q] += s0;
    }
    __syncthreads();
  }
  int n = n0 + nn;
  float bias = db[n];
  #pragma unroll
  for (int q = 0; q < 16; ++q) {
    int R = rt*32 + rg*16 + q;
    decpre[R*1024 + n] = acc[q] + bias;
  }
}

// ---------- encoder: 1 WG per (batch, dir); weights pinned in registers ----------
__global__ __launch_bounds__(512, 2) void k_encoder(
    const float* __restrict__ xcomb,
    const float* __restrict__ whhf, const float* __restrict__ whhb,
    float* __restrict__ encout,
    float* __restrict__ hpub0,     // [16][256]: decoder h0 (parity-0 publish buffer)
    float* __restrict__ c0buf)     // [16][256]
{
  const int b = blockIdx.x & 15, dir = blockIdx.x >> 4;
  const int t = threadIdx.x;      // gate row 0..511 (i|f|g|o blocks of 128)
  const float* __restrict__ Whh = dir ? whhb : whhf;
  // W row in registers: 128 floats, pinned
  float4 wr[32];
  #pragma unroll
  for (int j = 0; j < 32; ++j) {
    wr[j] = *(const float4*)(Whh + t*128 + j*4);
    PIN4(wr[j]);
  }
  __shared__ float hl[128];
  __shared__ float gl[512];
  float c_reg = 0.0f;
  if (t < 128) hl[t] = 0.0f;
  __syncthreads();
  for (int s = 0; s < SS; ++s) {
    const int sf = dir ? (SS-1-s) : s;
    float xv = xcomb[(sf*NB + b)*1024 + dir*512 + t];
    float a0 = 0.f, a1 = 0.f, a2 = 0.f, a3 = 0.f;
    #pragma unroll
    for (int j = 0; j < 32; j += 4) {
      float4 h0 = *(const float4*)(hl + j*4);
      float4 h1 = *(const float4*)(hl + j*4 + 4);
      float4 h2 = *(const float4*)(hl + j*4 + 8);
      float4 h3 = *(const float4*)(hl + j*4 + 12);
      a0 += wr[j].x*h0.x + wr[j].y*h0.y + wr[j].z*h0.z + wr[j].w*h0.w;
      a1 += wr[j+1].x*h1.x + wr[j+1].y*h1.y + wr[j+1].z*h1.z + wr[j+1].w*h1.w;
      a2 += wr[j+2].x*h2.x + wr[j+2].y*h2.y + wr[j+2].z*h2.z + wr[j+2].w*h2.w;
      a3 += wr[j+3].x*h3.x + wr[j+3].y*h3.y + wr[j+3].z*h3.z + wr[j+3].w*h3.w;
    }
    gl[t] = (a0 + a1) + (a2 + a3) + xv;
    __syncthreads();
    if (t < 128) {
      float gi = gl[t], gf = gl[128+t], gg = gl[256+t], go = gl[384+t];
      float iv = sigmf(gi), fv = sigmf(gf), gv = tanhf_(gg), ov = sigmf(go);
      c_reg = fv*c_reg + iv*gv;
      float hv = ov*tanhf_(c_reg);
      hl[t] = hv;
      encout[(b*SS + sf)*HH + dir*HL + t] = hv;
    }
    __syncthreads();
  }
  if (t < 128) {
    hpub0[b*HH + dir*HL + t] = hl[t];
    c0buf[b*HH + dir*HL + t] = c_reg;
  }
}

// ---------- enc_ws = enc_out @ attn_s_W.T + b, stored transposed [b][a][s] ----------
__global__ __launch_bounds__(256) void k_encws(
    const float* __restrict__ encout,
    const float* __restrict__ asW, const float* __restrict__ asb,
    float* __restrict__ encwsT)
{
  const int rt = blockIdx.x;  // 200 tiles of 32 rows (row = b*400+s)
  const int tid = threadIdx.x;
  __shared__ float Al[32*260];
  #pragma unroll
  for (int i = 0; i < 32; ++i) {
    int l = tid + i*256;
    int r = l >> 8, k = l & 255;
    Al[r*260 + k] = encout[(rt*32 + r)*256 + k];
  }
  __syncthreads();
  const int a = tid & 63, rg = tid >> 6;
  float acc[8];
  #pragma unroll
  for (int q = 0; q < 8; ++q) acc[q] = 0.0f;
  const float4* w4 = (const float4*)(asW + a*256);
  for (int k4 = 0; k4 < 64; ++k4) {
    float4 w = w4[k4];
    #pragma unroll
    for (int q = 0; q < 8; ++q) {
      const float4* a4 = (const float4*)(Al + (rg*8 + q)*260);
      float4 av = a4[k4];
      acc[q] += av.x*w.x + av.y*w.y + av.z*w.z + av.w*w.w;
    }
  }
  float bias = asb[a];
  #pragma unroll
  for (int q = 0; q < 8; ++q) {
    int row = rt*32 + rg*8 + q;
    int b = row / SS, s = row - b*SS;
    encwsT[(b*AA + a)*SS + s] = acc[q] + bias;
  }
}

// ---------- decoder: WG (g,b) = 8 unit-groups x 16 batches; weights pinned; 1 barrier/step ----------
__global__ __launch_bounds__(512, 2) void k_decoder(
    const float* __restrict__ decpre,
    const float* __restrict__ dwhh,   // [1024][256]
    const float* __restrict__ dwih,   // [1024][1280]
    const float* __restrict__ ahW, const float* __restrict__ ahb,
    const float* __restrict__ afW, const float* __restrict__ afb,
    const float* __restrict__ encwsT, // [b*64+a][400]
    const float* __restrict__ encout, // [b*400+s][256]
    const int* __restrict__ alen,
    const float* __restrict__ c0buf,  // [16][256]
    float* hpub,                      // [2][16][256], parity 0 pre-filled with h0
    float* __restrict__ dhall,        // [96*16][256]
    int* cnts)
{
  const int wg = blockIdx.x;
  const int g = wg >> 4, b = wg & 15;   // unit-group, batch
  const int t = threadIdx.x;            // 512
  const int r = t & 127, ks = t >> 7;   // row-in-WG, K-split (4 x 128)
  const int q = r >> 5, uu = r & 31;
  const int grow = q*256 + g*32 + uu;   // global gate row
  int* cnt = cnts + b*16;

  // weight slice in registers: W[grow][ks*128 .. ks*128+128), pinned
  float4 wr[32];
  #pragma unroll
  for (int j = 0; j < 32; ++j) {
    int k = ks*128 + j*4;
    wr[j] = (k < 256) ? *(const float4*)(dwhh + grow*256 + k)
                      : *(const float4*)(dwih + grow*1280 + 1024 + (k - 256));
    PIN4(wr[j]);
  }

  __shared__ float hc[512];        // [h(256) | ctx(256)]
  __shared__ float part[4][132];
  __shared__ float gates[128];
  __shared__ float wh[64];
  __shared__ float whp[8][68];
  __shared__ float fwl[64];
  __shared__ float scl[400];
  __shared__ float rwave[8];
  __shared__ float cpart[8][260];
  __shared__ float sh_max, sh_sum;

  if (t < 64) fwl[t] = afW[t];
  const float fb0 = afb[0];
  int len = alen[b]; len = min(max(len, 1), SS);
  float c_reg = (t < 32) ? c0buf[b*HH + g*32 + t] : 0.0f;

  // pre-stage h(0) and ctx(0)=0
  if (t < 256) { hc[t] = gload(hpub + b*HH + t); hc[256 + t] = 0.0f; }
  __syncthreads();

  for (int tt = 0; tt < TT; ++tt) {
    const int wp = (tt & 1) ^ 1;
    // ---- gates GEMM: thread = (row r, K-slice ks) ----
    float a0 = 0.f, a1 = 0.f, a2 = 0.f, a3 = 0.f;
    const float* hs = hc + ks*128;
    #pragma unroll
    for (int j = 0; j < 32; j += 4) {
      float4 h0 = *(const float4*)(hs + j*4);
      float4 h1 = *(const float4*)(hs + j*4 + 4);
      float4 h2 = *(const float4*)(hs + j*4 + 8);
      float4 h3 = *(const float4*)(hs + j*4 + 12);
      a0 += wr[j].x*h0.x + wr[j].y*h0.y + wr[j].z*h0.z + wr[j].w*h0.w;
      a1 += wr[j+1].x*h1.x + wr[j+1].y*h1.y + wr[j+1].z*h1.z + wr[j+1].w*h1.w;
      a2 += wr[j+2].x*h2.x + wr[j+2].y*h2.y + wr[j+2].z*h2.z + wr[j+2].w*h2.w;
      a3 += wr[j+3].x*h3.x + wr[j+3].y*h3.y + wr[j+3].z*h3.z + wr[j+3].w*h3.w;
    }
    part[ks][r] = (a0 + a1) + (a2 + a3);
    __syncthreads();
    if (t < 128) {
      float gv = part[0][t] + part[1][t] + part[2][t] + part[3][t]
               + decpre[(tt*NB + b)*1024 + (t >> 5)*256 + g*32 + (t & 31)];
      gates[t] = gv;
    }
    __syncthreads();
    // ---- cell update: threads 0..31 own units g*32+t ----
    if (t < 32) {
      float gi = gates[t], gf = gates[32+t], gg = gates[64+t], go = gates[96+t];
      float iv = sigmf(gi), fv = sigmf(gf), gv = tanhf_(gg), ov = sigmf(go);
      c_reg = fv*c_reg + iv*gv;
      float hv = ov*tanhf_(c_reg);
      int u = g*32 + t;
      gstore(hpub + wp*NB*HH + b*HH + u, hv);
      dhall[(tt*NB + b)*HH + u] = hv;
    }
    wgbar(cnt, 8);
    // ---- stage full h_new (redundant per WG from here on) ----
    if (t < 256) hc[t] = gload(hpub + wp*NB*HH + b*HH + t);
    __syncthreads();
    // ---- wh[a] = ahb + ahW @ h_new ----
    {
      int a = t >> 3, kq = t & 7;
      float p = 0.f;
      #pragma unroll
      for (int k = 0; k < 32; ++k) p += ahW[a*HH + kq*32 + k] * hc[kq*32 + k];
      whp[kq][a] = p;
    }
    __syncthreads();
    if (t < 64) {
      float s0 = 0.f;
      #pragma unroll
      for (int kq = 0; kq < 8; ++kq) s0 += whp[kq][t];
      wh[t] = ahb[t] + s0;
    }
    __syncthreads();
    // ---- scores ----
    float sc = -1e30f;
    if (t < SS) {
      sc = fb0;
      #pragma unroll 8
      for (int a = 0; a < AA; ++a)
        sc += fwl[a] * tanhf_(encwsT[(b*AA + a)*SS + t] + wh[a]);
      sc = fminf(sc, (t < len) ? 9999.0f : -9999.0f);
    }
    // ---- softmax: wave shuffle + cross-wave ----
    float m = sc;
    #pragma unroll
    for (int o = 32; o; o >>= 1) m = fmaxf(m, __shfl_xor(m, o));
    if ((t & 63) == 0) rwave[t >> 6] = m;
    __syncthreads();
    if (t == 0) {
      float mm = rwave[0];
      #pragma unroll
      for (int i = 1; i < 8; ++i) mm = fmaxf(mm, rwave[i]);
      sh_max = mm;
    }
    __syncthreads();
    float bmax = sh_max;
    float e = 0.f;
    if (t < SS) { e = __expf(sc - bmax); scl[t] = e; }
    float ssum = e;
    #pragma unroll
    for (int o = 32; o; o >>= 1) ssum += __shfl_xor(ssum, o);
    if ((t & 63) == 0) rwave[t >> 6] = ssum;
    __syncthreads();
    if (t == 0) {
      float s0 = 0.f;
      #pragma unroll
      for (int i = 0; i < 8; ++i) s0 += rwave[i];
      sh_sum = s0;
    }
    __syncthreads();
    const float inv = 1.0f / sh_sum;
    // ---- ctx: thread (sg = t>>6, dv = t&63): 50 s-values, float4 over d ----
    {
      const int sg = t >> 6, dv = t & 63;
      float4 acc4 = make_float4(0.f, 0.f, 0.f, 0.f);
      const float* eb = encout + (b*SS + sg*50)*HH + dv*4;
      #pragma unroll 5
      for (int i = 0; i < 50; ++i) {
        float w = scl[sg*50 + i];
        float4 e4 = *(const float4*)(eb + i*HH);
        acc4.x += w*e4.x; acc4.y += w*e4.y; acc4.z += w*e4.z; acc4.w += w*e4.w;
      }
      *(float4*)(&cpart[sg][dv*4]) = acc4;
    }
    __syncthreads();
    if (t < 256) {
      float s0 = 0.f;
      #pragma unroll
      for (int sg = 0; sg < 8; ++sg) s0 += cpart[sg][t];
      hc[256 + t] = s0 * inv;
    }
    __syncthreads();
  }
}

// ---------- vocab logits + per-chunk logsumexp partials ----------
__global__ __launch_bounds__(256) void k_pred(
    const float* __restrict__ dhall,
    const float* __restrict__ predW,
    const float* __restrict__ predb,
    float* __restrict__ pm, float* __restrict__ ps)
{
  const int rt = blockIdx.x;   // 48 (rows of 32)
  const int ch = blockIdx.y;   // 120 (cols of 256)
  const int tid = threadIdx.x;
  __shared__ float Al[32*260];
  __shared__ float Bl[256*17];
  #pragma unroll
  for (int i = 0; i < 32; ++i) {
    int l = tid + i*256;
    int r = l >> 8, k = l & 255;
    Al[r*260 + k] = dhall[(rt*32 + r)*256 + k];
  }
  const int v = ch*256 + tid;
  float acc[32];
  #pragma unroll
  for (int r = 0; r < 32; ++r) acc[r] = 0.0f;
  for (int kc = 0; kc < 16; ++kc) {
    __syncthreads();
    #pragma unroll
    for (int i = 0; i < 16; ++i) {
      int l = tid + i*256;
      int vv = l >> 4, kk = l & 15;
      int col = ch*256 + vv;
      Bl[vv*17 + kk] = (col < VV) ? predW[col*256 + kc*16 + kk] : 0.0f;
    }
    __syncthreads();
    float bvr[16];
    #pragma unroll
    for (int kk = 0; kk < 16; ++kk) bvr[kk] = Bl[tid*17 + kk];
    #pragma unroll
    for (int r = 0; r < 32; ++r) {
      const float4* a4 = (const float4*)(Al + r*260 + kc*16);
      float s0 = 0.0f;
      #pragma unroll
      for (int k4 = 0; k4 < 4; ++k4) {
        float4 a = a4[k4];
        s0 += a.x*bvr[4*k4] + a.y*bvr[4*k4+1] + a.z*bvr[4*k4+2] + a.w*bvr[4*k4+3];
      }
      acc[r] += s0;
    }
  }
  float bias = (v < VV) ? predb[v] : 0.0f;
  __syncthreads();
  #pragma unroll
  for (int r = 0; r < 32; ++r)
    Al[r*260 + tid] = (v < VV) ? (acc[r] + bias) : -1e30f;
  __syncthreads();
  if (tid < 32) {
    int row = rt*32 + tid;
    float m = -1e30f;
    for (int c = 0; c < 256; ++c) m = fmaxf(m, Al[tid*260 + c]);
    float ssum = 0.0f;
    for (int c = 0; c < 256; ++c) ssum += __expf(Al[tid*260 + c] - m);
    pm[row*NCHUNK + ch] = m;
    ps[row*NCHUNK + ch] = ssum;
  }
}

// ---------- loss partials: 6 WGs x 256 threads, one row per thread ----------
__global__ __launch_bounds__(256) void k_loss_part(
    const float* __restrict__ pm, const float* __restrict__ ps,
    const float* __restrict__ dhall,
    const float* __restrict__ predW, const float* __restrict__ predb,
    const int* __restrict__ abstr, float* __restrict__ lpart)
{
  const int tid = threadIdx.x;
  const int row = blockIdx.x*256 + tid;   // < 1536
  __shared__ float rs[256], rc[256];
  float lsum = 0.0f, lcnt = 0.0f;
  {
    int t = row >> 4, b = row & 15;
    int tok = abstr[b*TT + t];
    float m = -1e30f;
    for (int c = 0; c < NCHUNK; ++c) m = fmaxf(m, pm[row*NCHUNK + c]);
    float ss = 0.0f;
    for (int c = 0; c < NCHUNK; ++c) ss += ps[row*NCHUNK + c] * __expf(pm[row*NCHUNK + c] - m);
    float lse = m + __logf(ss);
    float tl = predb[tok];
    const float* hrow = dhall + row*256;
    const float* wrow = predW + tok*256;
    #pragma unroll 4
    for (int k = 0; k < 256; ++k) tl += hrow[k] * wrow[k];
    if (tok != 0) { lsum = lse - tl; lcnt = 1.0f; }
  }
  rs[tid] = lsum; rc[tid] = lcnt;
  __syncthreads();
  for (int st = 128; st; st >>= 1) {
    if (tid < st) { rs[tid] += rs[tid + st]; rc[tid] += rc[tid + st]; }
    __syncthreads();
  }
  if (tid == 0) { lpart[blockIdx.x*2] = rs[0]; lpart[blockIdx.x*2 + 1] = rc[0]; }
}

// ---------- final: deterministic sum of 6 partials ----------
__global__ void k_loss_final(const float* __restrict__ lpart, float* __restrict__ out) {
  if (threadIdx.x == 0) {
    float s = 0.f, c = 0.f;
    for (int i = 0; i < 6; ++i) { s += lpart[i*2]; c += lpart[i*2 + 1]; }
    out[0] = s / fmaxf(c, 1.0f);
  }
}

// ---------- launch ----------
extern "C" void kernel_launch(void* const* d_in, const int* in_sizes, int n_in,
                              void* d_out, int out_size, void* d_ws, size_t ws_size,
                              hipStream_t stream) {
  const float* emb   = (const float*)d_in[0];
  const int* article = (const int*)d_in[1];
  const int* alen    = (const int*)d_in[2];
  const int* abstr   = (const int*)d_in[3];
  const float* eWihF = (const float*)d_in[4];
  const float* eWhhF = (const float*)d_in[5];
  const float* ebF   = (const float*)d_in[6];
  const float* eWihB = (const float*)d_in[7];
  const float* eWhhB = (const float*)d_in[8];
  const float* ebB   = (const float*)d_in[9];
  const float* dWih  = (const float*)d_in[10];
  const float* dWhh  = (const float*)d_in[11];
  const float* db    = (const float*)d_in[12];
  const float* pW    = (const float*)d_in[13];
  const float* pb    = (const float*)d_in[14];
  const float* asW   = (const float*)d_in[15];
  const float* asb   = (const float*)d_in[16];
  const float* ahW   = (const float*)d_in[17];
  const float* ahb   = (const float*)d_in[18];
  const float* afW   = (const float*)d_in[19];
  const float* afb   = (const float*)d_in[20];
  float* out = (float*)d_out;

  float* w = (float*)d_ws;
  size_t o = 0;
  float* xcomb  = w + o; o += (size_t)SS*NB*1024;
  float* encout = w + o; o += (size_t)NB*SS*HH;
  float* encwsT = w + o; o += (size_t)NB*AA*SS;
  float* decpre = w + o; o += (size_t)TT*NB*1024;
  float* dhall  = w + o; o += (size_t)TT*NB*HH;
  float* hpub   = w + o; o += 2*NB*HH;
  float* c0buf  = w + o; o += NB*HH;
  float* pm     = w + o; o += (size_t)TT*NB*NCHUNK;
  float* ps     = w + o; o += (size_t)TT*NB*NCHUNK;
  float* lpart  = w + o; o += 16;
  int* cnts = (int*)(w + o); o += 256;

  k_init<<<1, 256, 0, stream>>>(hpub, cnts, lpart);
  k_embproj_enc<<<dim3(200, 8), 256, 0, stream>>>(emb, article, eWihF, eWihB, ebF, ebB, xcomb);
  k_embproj_dec<<<dim3(48, 8), 256, 0, stream>>>(emb, abstr, dWih, db, decpre);
  k_encoder<<<32, 512, 0, stream>>>(xcomb, eWhhF, eWhhB, encout, hpub, c0buf);
  k_encws<<<200, 256, 0, stream>>>(encout, asW, asb, encwsT);
  k_decoder<<<128, 512, 0, stream>>>(decpre, dWhh, dWih, ahW, ahb, afW, afb,
                                     encwsT, encout, alen, c0buf, hpub, dhall, cnts);
  k_pred<<<dim3(48, 120), 256, 0, stream>>>(dhall, pW, pb, pm, ps);
  k_loss_part<<<6, 256, 0, stream>>>(pm, ps, dhall, pW, pb, abstr, lpart);
  k_loss_final<<<1, 64, 0, stream>>>(lpart, out);
}

// Round 4
// 5629.503 us; speedup vs baseline: 2.1790x; 1.0861x over previous
//
#include <hip/hip_runtime.h>
#include <cmath>

#define NB 16      // batch
#define SS 400     // source len
#define TT 96      // target len
#define HL 128     // LSTM per dir
#define HH 256     // decoder hidden (2*HL)
#define AA 64      // attn dim
#define VV 30611   // vocab
#define START_TOK 101
#define NCHUNK 120 // vocab chunks of 256

// keep a loaded float4 live in VGPRs (forbid rematerialization / load sinking)
#define PIN4(v) asm volatile("" : "+v"((v).x), "+v"((v).y), "+v"((v).z), "+v"((v).w))

// ---------- helpers ----------
__device__ __forceinline__ float gload(const float* p) {
  return __hip_atomic_load(p, __ATOMIC_RELAXED, __HIP_MEMORY_SCOPE_AGENT);
}
__device__ __forceinline__ void gstore(float* p, float v) {
  __hip_atomic_store(p, v, __ATOMIC_RELAXED, __HIP_MEMORY_SCOPE_AGENT);
}
__device__ __forceinline__ float sigmf(float x) { return 1.0f / (1.0f + __expf(-x)); }
__device__ __forceinline__ float tanhf_(float x) {
  float xc = fminf(fmaxf(x, -15.0f), 15.0f);
  return 1.0f - 2.0f / (__expf(2.0f * xc) + 1.0f);
}
// flag barrier: 8 WGs per batch, single-writer flags (one cacheline each),
// release store + acquire poll. target must be monotonically increasing.
__device__ __forceinline__ void flagbar(int* flags, int b, int g, int target) {
  __syncthreads();
  if (threadIdx.x == 0)
    __hip_atomic_store(&flags[(b*8 + g)*16], target, __ATOMIC_RELEASE, __HIP_MEMORY_SCOPE_AGENT);
  if (threadIdx.x < 64) {
    int j = threadIdx.x & 7;
    while (__hip_atomic_load(&flags[(b*8 + j)*16], __ATOMIC_ACQUIRE, __HIP_MEMORY_SCOPE_AGENT) < target)
      __builtin_amdgcn_s_sleep(1);
  }
  __syncthreads();
}

// ---------- init: zero flags ----------
__global__ __launch_bounds__(256) void k_init(int* flags) {
  for (int i = threadIdx.x; i < 16*8*16; i += 256) flags[i] = 0;
}

// ---------- encoder input projection: xcomb[s*16+b][n], n = dir*512 + gate row ----------
__global__ __launch_bounds__(256) void k_embproj_enc(
    const float* __restrict__ emb, const int* __restrict__ article,
    const float* __restrict__ wihf, const float* __restrict__ wihb,
    const float* __restrict__ bf, const float* __restrict__ bb,
    float* __restrict__ xcomb)
{
  const int rt = blockIdx.x;        // 200 row tiles of 32
  const int n0 = blockIdx.y * 128;  // 8 col tiles
  const int tid = threadIdx.x;
  __shared__ float Alds[32*36];
  __shared__ float Blds[32*129];    // [kk][nn]
  __shared__ int toklds[32];
  if (tid < 32) {
    int R = rt*32 + tid;            // R = s*16 + b
    int s = R >> 4, b = R & 15;
    toklds[tid] = article[b*SS + s];
  }
  __syncthreads();
  float acc[16];
  #pragma unroll
  for (int q = 0; q < 16; ++q) acc[q] = 0.0f;
  const int nn = tid & 127, rg = tid >> 7;
  for (int kc = 0; kc < 1024; kc += 32) {
    #pragma unroll
    for (int i = 0; i < 4; ++i) {
      int l = tid + i*256;
      int rr = l >> 5, kk = l & 31;
      Alds[rr*36 + kk] = emb[toklds[rr]*1024 + kc + kk];
    }
    #pragma unroll
    for (int i = 0; i < 16; ++i) {
      int l = tid + i*256;
      int bn = l >> 5, kk = l & 31;
      int n = n0 + bn;
      const float* src = (n < 512) ? (wihf + n*1024) : (wihb + (n-512)*1024);
      Blds[kk*129 + bn] = src[kc + kk];
    }
    __syncthreads();
    float bvr[32];
    #pragma unroll
    for (int kk = 0; kk < 32; ++kk) bvr[kk] = Blds[kk*129 + nn];
    #pragma unroll
    for (int q = 0; q < 16; ++q) {
      const float4* a4 = (const float4*)(Alds + (rg*16 + q)*36);
      float s0 = 0.0f;
      #pragma unroll
      for (int k4 = 0; k4 < 8; ++k4) {
        float4 a = a4[k4];
        s0 += a.x*bvr[4*k4] + a.y*bvr[4*k4+1] + a.z*bvr[4*k4+2] + a.w*bvr[4*k4+3];
      }
      acc[q] += s0;
    }
    __syncthreads();
  }
  int n = n0 + nn;
  float bias = (n < 512) ? bf[n] : bb[n-512];
  #pragma unroll
  for (int q = 0; q < 16; ++q) {
    int R = rt*32 + rg*16 + q;
    xcomb[R*1024 + n] = acc[q] + bias;
  }
}

// ---------- decoder embedding projection: decpre[t*16+b][n] (dec_b folded) ----------
__global__ __launch_bounds__(256) void k_embproj_dec(
    const float* __restrict__ emb, const int* __restrict__ abstr,
    const float* __restrict__ dwih, const float* __restrict__ db,
    float* __restrict__ decpre)
{
  const int rt = blockIdx.x;        // 48 row tiles of 32
  const int n0 = blockIdx.y * 128;  // 8 col tiles
  const int tid = threadIdx.x;
  __shared__ float Alds[32*36];
  __shared__ float Blds[32*129];
  __shared__ int toklds[32];
  if (tid < 32) {
    int R = rt*32 + tid;            // R = t*16 + b
    int t = R >> 4, b = R & 15;
    toklds[tid] = (t == 0) ? START_TOK : abstr[b*TT + t - 1];
  }
  __syncthreads();
  float acc[16];
  #pragma unroll
  for (int q = 0; q < 16; ++q) acc[q] = 0.0f;
  const int nn = tid & 127, rg = tid >> 7;
  for (int kc = 0; kc < 1024; kc += 32) {
    #pragma unroll
    for (int i = 0; i < 4; ++i) {
      int l = tid + i*256;
      int rr = l >> 5, kk = l & 31;
      Alds[rr*36 + kk] = emb[toklds[rr]*1024 + kc + kk];
    }
    #pragma unroll
    for (int i = 0; i < 16; ++i) {
      int l = tid + i*256;
      int bn = l >> 5, kk = l & 31;
      int n = n0 + bn;
      Blds[kk*129 + bn] = dwih[n*1280 + kc + kk];
    }
    __syncthreads();
    float bvr[32];
    #pragma unroll
    for (int kk = 0; kk < 32; ++kk) bvr[kk] = Blds[kk*129 + nn];
    #pragma unroll
    for (int q = 0; q < 16; ++q) {
      const float4* a4 = (const float4*)(Alds + (rg*16 + q)*36);
      float s0 = 0.0f;
      #pragma unroll
      for (int k4 = 0; k4 < 8; ++k4) {
        float4 a = a4[k4];
        s0 += a.x*bvr[4*k4] + a.y*bvr[4*k4+1] + a.z*bvr[4*k4+2] + a.w*bvr[4*k4+3];
      }
      acc[q] += s0;
    }
    __syncthreads();
  }
  int n = n0 + nn;
  float bias = db[n];
  #pragma unroll
  for (int q = 0; q < 16; ++q) {
    int R = rt*32 + rg*16 + q;
    decpre[R*1024 + n] = acc[q] + bias;
  }
}

// ---------- encoder: 1 WG per (batch, dir), 1024 thr, 64 wts/thread in regs ----------
__global__ __launch_bounds__(1024, 4) void k_encoder(
    const float* __restrict__ xcomb,
    const float* __restrict__ whhf, const float* __restrict__ whhb,
    float* __restrict__ encout,
    float* __restrict__ hpub,      // [16][256]: decoder h0
    float* __restrict__ c0buf)     // [16][256]
{
  const int b = blockIdx.x & 15, dir = blockIdx.x >> 4;
  const int t = threadIdx.x;       // 1024
  const int row = t & 511;         // gate row (i|f|g|o blocks of 128)
  const int ks = t >> 9;           // K-slice: 2 x 64
  const float* __restrict__ Whh = dir ? whhb : whhf;
  // 64 weights in registers, pinned
  float4 wr[16];
  #pragma unroll
  for (int j = 0; j < 16; ++j) {
    wr[j] = *(const float4*)(Whh + row*128 + ks*64 + j*4);
    PIN4(wr[j]);
  }
  __shared__ float hl[128];
  __shared__ float part[2][512];
  float c_reg = 0.0f;
  if (t < 128) hl[t] = 0.0f;
  __syncthreads();
  for (int s = 0; s < SS; ++s) {
    const int sf = dir ? (SS-1-s) : s;
    // prefetch x-projections for cell threads
    float xv0 = 0.f, xv1 = 0.f, xv2 = 0.f, xv3 = 0.f;
    if (t < 128) {
      const float* xrow = xcomb + (sf*NB + b)*1024 + dir*512 + t;
      xv0 = xrow[0]; xv1 = xrow[128]; xv2 = xrow[256]; xv3 = xrow[384];
    }
    // GEMM: 64 MACs, weights in regs, h broadcast from LDS
    const float* hs = hl + ks*64;
    float a0 = 0.f, a1 = 0.f, a2 = 0.f, a3 = 0.f;
    #pragma unroll
    for (int j = 0; j < 16; j += 4) {
      float4 h0 = *(const float4*)(hs + j*4);
      float4 h1 = *(const float4*)(hs + j*4 + 4);
      float4 h2 = *(const float4*)(hs + j*4 + 8);
      float4 h3 = *(const float4*)(hs + j*4 + 12);
      a0 += wr[j].x*h0.x + wr[j].y*h0.y + wr[j].z*h0.z + wr[j].w*h0.w;
      a1 += wr[j+1].x*h1.x + wr[j+1].y*h1.y + wr[j+1].z*h1.z + wr[j+1].w*h1.w;
      a2 += wr[j+2].x*h2.x + wr[j+2].y*h2.y + wr[j+2].z*h2.z + wr[j+2].w*h2.w;
      a3 += wr[j+3].x*h3.x + wr[j+3].y*h3.y + wr[j+3].z*h3.z + wr[j+3].w*h3.w;
    }
    part[ks][row] = (a0 + a1) + (a2 + a3);
    __syncthreads();
    if (t < 128) {
      float gi = part[0][t]       + part[1][t]       + xv0;
      float gf = part[0][128 + t] + part[1][128 + t] + xv1;
      float gg = part[0][256 + t] + part[1][256 + t] + xv2;
      float go = part[0][384 + t] + part[1][384 + t] + xv3;
      float iv = sigmf(gi), fv = sigmf(gf), gv = tanhf_(gg), ov = sigmf(go);
      c_reg = fv*c_reg + iv*gv;
      float hv = ov*tanhf_(c_reg);
      hl[t] = hv;
      encout[(b*SS + sf)*HH + dir*HL + t] = hv;
    }
    __syncthreads();
  }
  if (t < 128) {
    hpub[b*HH + dir*HL + t] = hl[t];
    c0buf[b*HH + dir*HL + t] = c_reg;
  }
}

// ---------- enc_ws = enc_out @ attn_s_W.T + b, stored transposed [b][a][s] ----------
__global__ __launch_bounds__(256) void k_encws(
    const float* __restrict__ encout,
    const float* __restrict__ asW, const float* __restrict__ asb,
    float* __restrict__ encwsT)
{
  const int rt = blockIdx.x;  // 200 tiles of 32 rows (row = b*400+s)
  const int tid = threadIdx.x;
  __shared__ float Al[32*260];
  #pragma unroll
  for (int i = 0; i < 32; ++i) {
    int l = tid + i*256;
    int r = l >> 8, k = l & 255;
    Al[r*260 + k] = encout[(rt*32 + r)*256 + k];
  }
  __syncthreads();
  const int a = tid & 63, rg = tid >> 6;
  float acc[8];
  #pragma unroll
  for (int q = 0; q < 8; ++q) acc[q] = 0.0f;
  const float4* w4 = (const float4*)(asW + a*256);
  for (int k4 = 0; k4 < 64; ++k4) {
    float4 w = w4[k4];
    #pragma unroll
    for (int q = 0; q < 8; ++q) {
      const float4* a4 = (const float4*)(Al + (rg*8 + q)*260);
      float4 av = a4[k4];
      acc[q] += av.x*w.x + av.y*w.y + av.z*w.z + av.w*w.w;
    }
  }
  float bias = asb[a];
  #pragma unroll
  for (int q = 0; q < 8; ++q) {
    int row = rt*32 + rg*8 + q;
    int b = row / SS, s = row - b*SS;
    encwsT[(b*AA + a)*SS + s] = acc[q] + bias;
  }
}

// ---------- decoder: 8 WGs x 16 batches, 1024 thr, 64 wts/thread; 2 flag barriers/step ----------
__global__ __launch_bounds__(1024, 4) void k_decoder(
    const float* __restrict__ decpre,
    const float* __restrict__ dwhh,   // [1024][256]
    const float* __restrict__ dwih,   // [1024][1280]
    const float* __restrict__ ahW, const float* __restrict__ ahb,
    const float* __restrict__ afW, const float* __restrict__ afb,
    const float* __restrict__ encwsT, // [b*64+a][400]
    const float* __restrict__ encout, // [b*400+s][256]
    const int* __restrict__ alen,
    const float* __restrict__ c0buf,  // [16][256]
    float* hpub,                      // [16][256], pre-filled with h0 by encoder
    float* cpub,                      // [16][8][256] ctx partials
    float* __restrict__ dhall,        // [96*16][256]
    int* flags)
{
  const int wg = blockIdx.x;
  const int g = wg >> 4, b = wg & 15;   // unit-group, batch
  const int t = threadIdx.x;            // 1024
  const int r = t & 127, ks = t >> 7;   // row-in-WG (128), K-slice (8 x 64)
  const int q = r >> 5, uu = r & 31;
  const int grow = q*256 + g*32 + uu;   // global gate row

  // 64-float weight slice in registers, pinned
  float4 wr[16];
  #pragma unroll
  for (int j = 0; j < 16; ++j) {
    int k = ks*64 + j*4;
    wr[j] = (k < 256) ? *(const float4*)(dwhh + grow*256 + k)
                      : *(const float4*)(dwih + grow*1280 + 1024 + (k - 256));
    PIN4(wr[j]);
  }

  __shared__ float hc[512];        // [h(256) | ctx(256)]
  __shared__ float part[8][132];
  __shared__ float gates[128];
  __shared__ float wh[64];
  __shared__ float whp[16][68];
  __shared__ float fwl[64];
  __shared__ float scl[400];
  __shared__ float red[16];
  __shared__ float sh_max, sh_sum;

  if (t < 64) fwl[t] = afW[t];
  const float fb0 = afb[0];
  int len = alen[b]; len = min(max(len, 1), SS);
  float c_reg = (t < 32) ? c0buf[b*HH + g*32 + t] : 0.0f;

  // pre-stage h(0) and ctx(0)=0
  if (t < 256) { hc[t] = gload(hpub + b*HH + t); hc[256 + t] = 0.0f; }
  __syncthreads();

  for (int tt = 0; tt < TT; ++tt) {
    // prefetch decpre for reduce threads
    float pre = 0.f;
    if (t < 128)
      pre = decpre[(tt*NB + b)*1024 + (t >> 5)*256 + g*32 + (t & 31)];
    // ---- gates GEMM: 64 MACs/thread, weights in regs, hc broadcast ----
    const float* hs = hc + ks*64;
    float a0 = 0.f, a1 = 0.f, a2 = 0.f, a3 = 0.f;
    #pragma unroll
    for (int j = 0; j < 16; j += 4) {
      float4 h0 = *(const float4*)(hs + j*4);
      float4 h1 = *(const float4*)(hs + j*4 + 4);
      float4 h2 = *(const float4*)(hs + j*4 + 8);
      float4 h3 = *(const float4*)(hs + j*4 + 12);
      a0 += wr[j].x*h0.x + wr[j].y*h0.y + wr[j].z*h0.z + wr[j].w*h0.w;
      a1 += wr[j+1].x*h1.x + wr[j+1].y*h1.y + wr[j+1].z*h1.z + wr[j+1].w*h1.w;
      a2 += wr[j+2].x*h2.x + wr[j+2].y*h2.y + wr[j+2].z*h2.z + wr[j+2].w*h2.w;
      a3 += wr[j+3].x*h3.x + wr[j+3].y*h3.y + wr[j+3].z*h3.z + wr[j+3].w*h3.w;
    }
    part[ks][r] = (a0 + a1) + (a2 + a3);
    __syncthreads();
    if (t < 128) {
      float gv = pre;
      #pragma unroll
      for (int j = 0; j < 8; ++j) gv += part[j][t];
      gates[t] = gv;
    }
    __syncthreads();
    // ---- cell update: threads 0..31 own units g*32+t ----
    if (t < 32) {
      float gi = gates[t], gf = gates[32+t], gg = gates[64+t], go = gates[96+t];
      float iv = sigmf(gi), fv = sigmf(gf), gv = tanhf_(gg), ov = sigmf(go);
      c_reg = fv*c_reg + iv*gv;
      float hv = ov*tanhf_(c_reg);
      int u = g*32 + t;
      gstore(hpub + b*HH + u, hv);
      dhall[(tt*NB + b)*HH + u] = hv;
    }
    flagbar(flags, b, g, 2*tt + 1);
    // ---- stage h_new ----
    if (t < 256) hc[t] = gload(hpub + b*HH + t);
    __syncthreads();
    // ---- wh[a] = ahb + ahW @ h_new (16k MACs over 1024 thr) ----
    {
      int a = t >> 4, kq = t & 15;
      const float* wrow = ahW + a*HH + kq*16;
      const float* hrow = hc + kq*16;
      float p = 0.f;
      #pragma unroll
      for (int k = 0; k < 16; ++k) p += wrow[k]*hrow[k];
      whp[kq][a] = p;
    }
    __syncthreads();
    if (t < 64) {
      float s0 = 0.f;
      #pragma unroll
      for (int kq = 0; kq < 16; ++kq) s0 += whp[kq][t];
      wh[t] = ahb[t] + s0;
    }
    __syncthreads();
    // ---- scores (redundant per WG) ----
    float sc = -1e30f;
    if (t < SS) {
      sc = fb0;
      #pragma unroll 8
      for (int a = 0; a < AA; ++a)
        sc += fwl[a] * tanhf_(encwsT[(b*AA + a)*SS + t] + wh[a]);
      sc = fminf(sc, (t < len) ? 9999.0f : -9999.0f);
    }
    // ---- softmax over 400 (16 waves) ----
    float m = sc;
    #pragma unroll
    for (int o = 32; o; o >>= 1) m = fmaxf(m, __shfl_xor(m, o));
    if ((t & 63) == 0) red[t >> 6] = m;
    __syncthreads();
    if (t == 0) {
      float mm = red[0];
      #pragma unroll
      for (int i = 1; i < 16; ++i) mm = fmaxf(mm, red[i]);
      sh_max = mm;
    }
    __syncthreads();
    float bmax = sh_max;
    float e = 0.f;
    if (t < SS) { e = __expf(sc - bmax); scl[t] = e; }
    float ssum = e;
    #pragma unroll
    for (int o = 32; o; o >>= 1) ssum += __shfl_xor(ssum, o);
    if ((t & 63) == 0) red[t >> 6] = ssum;
    __syncthreads();
    if (t == 0) {
      float s0 = 0.f;
      #pragma unroll
      for (int i = 0; i < 16; ++i) s0 += red[i];
      sh_sum = s0;
    }
    __syncthreads();
    const float inv = 1.0f / sh_sum;
    // ---- ctx partial: this WG covers s in [g*50, g*50+50); t<256 over d ----
    if (t < 256) {
      float acc = 0.0f;
      const float* eb = encout + (b*SS + g*50)*HH + t;
      #pragma unroll 5
      for (int i = 0; i < 50; ++i) acc += scl[g*50 + i] * eb[i*HH];
      gstore(cpub + (b*8 + g)*HH + t, acc * inv);
    }
    flagbar(flags, b, g, 2*tt + 2);
    // ---- stage full ctx = sum of 8 partials ----
    if (t < 256) {
      float s0 = 0.f;
      #pragma unroll
      for (int j = 0; j < 8; ++j) s0 += gload(cpub + (b*8 + j)*HH + t);
      hc[256 + t] = s0;
    }
    __syncthreads();
  }
}

// ---------- vocab logits + per-chunk logsumexp partials ----------
__global__ __launch_bounds__(256) void k_pred(
    const float* __restrict__ dhall,
    const float* __restrict__ predW,
    const float* __restrict__ predb,
    float* __restrict__ pm, float* __restrict__ ps)
{
  const int rt = blockIdx.x;   // 48 (rows of 32)
  const int ch = blockIdx.y;   // 120 (cols of 256)
  const int tid = threadIdx.x;
  __shared__ float Al[32*260];
  __shared__ float Bl[256*17];
  #pragma unroll
  for (int i = 0; i < 32; ++i) {
    int l = tid + i*256;
    int r = l >> 8, k = l & 255;
    Al[r*260 + k] = dhall[(rt*32 + r)*256 + k];
  }
  const int v = ch*256 + tid;
  float acc[32];
  #pragma unroll
  for (int r = 0; r < 32; ++r) acc[r] = 0.0f;
  for (int kc = 0; kc < 16; ++kc) {
    __syncthreads();
    #pragma unroll
    for (int i = 0; i < 16; ++i) {
      int l = tid + i*256;
      int vv = l >> 4, kk = l & 15;
      int col = ch*256 + vv;
      Bl[vv*17 + kk] = (col < VV) ? predW[col*256 + kc*16 + kk] : 0.0f;
    }
    __syncthreads();
    float bvr[16];
    #pragma unroll
    for (int kk = 0; kk < 16; ++kk) bvr[kk] = Bl[tid*17 + kk];
    #pragma unroll
    for (int r = 0; r < 32; ++r) {
      const float4* a4 = (const float4*)(Al + r*260 + kc*16);
      float s0 = 0.0f;
      #pragma unroll
      for (int k4 = 0; k4 < 4; ++k4) {
        float4 a = a4[k4];
        s0 += a.x*bvr[4*k4] + a.y*bvr[4*k4+1] + a.z*bvr[4*k4+2] + a.w*bvr[4*k4+3];
      }
      acc[r] += s0;
    }
  }
  float bias = (v < VV) ? predb[v] : 0.0f;
  __syncthreads();
  #pragma unroll
  for (int r = 0; r < 32; ++r)
    Al[r*260 + tid] = (v < VV) ? (acc[r] + bias) : -1e30f;
  __syncthreads();
  if (tid < 32) {
    int row = rt*32 + tid;
    float m = -1e30f;
    for (int c = 0; c < 256; ++c) m = fmaxf(m, Al[tid*260 + c]);
    float ssum = 0.0f;
    for (int c = 0; c < 256; ++c) ssum += __expf(Al[tid*260 + c] - m);
    pm[row*NCHUNK + ch] = m;
    ps[row*NCHUNK + ch] = ssum;
  }
}

// ---------- loss partials: 6 WGs x 256 threads, one row per thread ----------
__global__ __launch_bounds__(256) void k_loss_part(
    const float* __restrict__ pm, const float* __restrict__ ps,
    const float* __restrict__ dhall,
    const float* __restrict__ predW, const float* __restrict__ predb,
    const int* __restrict__ abstr, float* __restrict__ lpart)
{
  const int tid = threadIdx.x;
  const int row = blockIdx.x*256 + tid;   // < 1536
  __shared__ float rs[256], rc[256];
  float lsum = 0.0f, lcnt = 0.0f;
  {
    int t = row >> 4, b = row & 15;
    int tok = abstr[b*TT + t];
    float m = -1e30f;
    for (int c = 0; c < NCHUNK; ++c) m = fmaxf(m, pm[row*NCHUNK + c]);
    float ss = 0.0f;
    for (int c = 0; c < NCHUNK; ++c) ss += ps[row*NCHUNK + c] * __expf(pm[row*NCHUNK + c] - m);
    float lse = m + __logf(ss);
    float tl = predb[tok];
    const float* hrow = dhall + row*256;
    const float* wrow = predW + tok*256;
    #pragma unroll 4
    for (int k = 0; k < 256; ++k) tl += hrow[k] * wrow[k];
    if (tok != 0) { lsum = lse - tl; lcnt = 1.0f; }
  }
  rs[tid] = lsum; rc[tid] = lcnt;
  __syncthreads();
  for (int st = 128; st; st >>= 1) {
    if (tid < st) { rs[tid] += rs[tid + st]; rc[tid] += rc[tid + st]; }
    __syncthreads();
  }
  if (tid == 0) { lpart[blockIdx.x*2] = rs[0]; lpart[blockIdx.x*2 + 1] = rc[0]; }
}

// ---------- final: deterministic sum of 6 partials ----------
__global__ void k_loss_final(const float* __restrict__ lpart, float* __restrict__ out) {
  if (threadIdx.x == 0) {
    float s = 0.f, c = 0.f;
    for (int i = 0; i < 6; ++i) { s += lpart[i*2]; c += lpart[i*2 + 1]; }
    out[0] = s / fmaxf(c, 1.0f);
  }
}

// ---------- launch ----------
extern "C" void kernel_launch(void* const* d_in, const int* in_sizes, int n_in,
                              void* d_out, int out_size, void* d_ws, size_t ws_size,
                              hipStream_t stream) {
  const float* emb   = (const float*)d_in[0];
  const int* article = (const int*)d_in[1];
  const int* alen    = (const int*)d_in[2];
  const int* abstr   = (const int*)d_in[3];
  const float* eWihF = (const float*)d_in[4];
  const float* eWhhF = (const float*)d_in[5];
  const float* ebF   = (const float*)d_in[6];
  const float* eWihB = (const float*)d_in[7];
  const float* eWhhB = (const float*)d_in[8];
  const float* ebB   = (const float*)d_in[9];
  const float* dWih  = (const float*)d_in[10];
  const float* dWhh  = (const float*)d_in[11];
  const float* db    = (const float*)d_in[12];
  const float* pW    = (const float*)d_in[13];
  const float* pb    = (const float*)d_in[14];
  const float* asW   = (const float*)d_in[15];
  const float* asb   = (const float*)d_in[16];
  const float* ahW   = (const float*)d_in[17];
  const float* ahb   = (const float*)d_in[18];
  const float* afW   = (const float*)d_in[19];
  const float* afb   = (const float*)d_in[20];
  float* out = (float*)d_out;

  float* w = (float*)d_ws;
  size_t o = 0;
  float* xcomb  = w + o; o += (size_t)SS*NB*1024;
  float* encout = w + o; o += (size_t)NB*SS*HH;
  float* encwsT = w + o; o += (size_t)NB*AA*SS;
  float* decpre = w + o; o += (size_t)TT*NB*1024;
  float* dhall  = w + o; o += (size_t)TT*NB*HH;
  float* hpub   = w + o; o += NB*HH;
  float* cpub   = w + o; o += NB*8*HH;
  float* c0buf  = w + o; o += NB*HH;
  float* pm     = w + o; o += (size_t)TT*NB*NCHUNK;
  float* ps     = w + o; o += (size_t)TT*NB*NCHUNK;
  float* lpart  = w + o; o += 16;
  int* flags = (int*)(w + o); o += 16*8*16;

  k_init<<<1, 256, 0, stream>>>(flags);
  k_embproj_enc<<<dim3(200, 8), 256, 0, stream>>>(emb, article, eWihF, eWihB, ebF, ebB, xcomb);
  k_embproj_dec<<<dim3(48, 8), 256, 0, stream>>>(emb, abstr, dWih, db, decpre);
  k_encoder<<<32, 1024, 0, stream>>>(xcomb, eWhhF, eWhhB, encout, hpub, c0buf);
  k_encws<<<200, 256, 0, stream>>>(encout, asW, asb, encwsT);
  k_decoder<<<128, 1024, 0, stream>>>(decpre, dWhh, dWih, ahW, ahb, afW, afb,
                                      encwsT, encout, alen, c0buf, hpub, cpub, dhall, flags);
  k_pred<<<dim3(48, 120), 256, 0, stream>>>(dhall, pW, pb, pm, ps);
  k_loss_part<<<6, 256, 0, stream>>>(pm, ps, dhall, pW, pb, abstr, lpart);
  k_loss_final<<<1, 64, 0, stream>>>(lpart, out);
}

// Round 5
// 4178.364 us; speedup vs baseline: 2.9357x; 1.3473x over previous
//
#include <hip/hip_runtime.h>
#include <cmath>

#define NB 16      // batch
#define SS 400     // source len
#define TT 96      // target len
#define HL 128     // LSTM per dir
#define HH 256     // decoder hidden (2*HL)
#define AA 64      // attn dim
#define VV 30611   // vocab
#define START_TOK 101
#define NCHUNK 120 // vocab chunks of 256

// keep a loaded float4 live in VGPRs (forbid rematerialization / load sinking)
#define PIN4(v) asm volatile("" : "+v"((v).x), "+v"((v).y), "+v"((v).z), "+v"((v).w))

// ---------- helpers ----------
__device__ __forceinline__ float gload(const float* p) {
  return __hip_atomic_load(p, __ATOMIC_RELAXED, __HIP_MEMORY_SCOPE_AGENT);
}
__device__ __forceinline__ void gstore(float* p, float v) {
  __hip_atomic_store(p, v, __ATOMIC_RELAXED, __HIP_MEMORY_SCOPE_AGENT);
}
__device__ __forceinline__ float sigmf(float x) { return 1.0f / (1.0f + __expf(-x)); }
__device__ __forceinline__ float tanhf_(float x) {
  float xc = fminf(fmaxf(x, -15.0f), 15.0f);
  return 1.0f - 2.0f / (__expf(2.0f * xc) + 1.0f);
}
// flag barrier: 8 WGs per batch, single-writer flags (one cacheline each),
// release store + acquire poll. target must be monotonically increasing.
__device__ __forceinline__ void flagbar(int* flags, int b, int g, int target) {
  __syncthreads();
  if (threadIdx.x == 0)
    __hip_atomic_store(&flags[(b*8 + g)*16], target, __ATOMIC_RELEASE, __HIP_MEMORY_SCOPE_AGENT);
  if (threadIdx.x < 64) {
    int j = threadIdx.x & 7;
    while (__hip_atomic_load(&flags[(b*8 + j)*16], __ATOMIC_ACQUIRE, __HIP_MEMORY_SCOPE_AGENT) < target)
      __builtin_amdgcn_s_sleep(1);
  }
  __syncthreads();
}

// ---------- init: zero flags ----------
__global__ __launch_bounds__(256) void k_init(int* flags) {
  for (int i = threadIdx.x; i < 16*8*16; i += 256) flags[i] = 0;
}

// ---------- encoder input projection: xcomb[s*16+b][n], n = dir*512 + gate row ----------
__global__ __launch_bounds__(256) void k_embproj_enc(
    const float* __restrict__ emb, const int* __restrict__ article,
    const float* __restrict__ wihf, const float* __restrict__ wihb,
    const float* __restrict__ bf, const float* __restrict__ bb,
    float* __restrict__ xcomb)
{
  const int rt = blockIdx.x;        // 200 row tiles of 32
  const int n0 = blockIdx.y * 128;  // 8 col tiles
  const int tid = threadIdx.x;
  __shared__ float Alds[32*36];
  __shared__ float Blds[32*129];    // [kk][nn]
  __shared__ int toklds[32];
  if (tid < 32) {
    int R = rt*32 + tid;            // R = s*16 + b
    int s = R >> 4, b = R & 15;
    toklds[tid] = article[b*SS + s];
  }
  __syncthreads();
  float acc[16];
  #pragma unroll
  for (int q = 0; q < 16; ++q) acc[q] = 0.0f;
  const int nn = tid & 127, rg = tid >> 7;
  for (int kc = 0; kc < 1024; kc += 32) {
    #pragma unroll
    for (int i = 0; i < 4; ++i) {
      int l = tid + i*256;
      int rr = l >> 5, kk = l & 31;
      Alds[rr*36 + kk] = emb[toklds[rr]*1024 + kc + kk];
    }
    #pragma unroll
    for (int i = 0; i < 16; ++i) {
      int l = tid + i*256;
      int bn = l >> 5, kk = l & 31;
      int n = n0 + bn;
      const float* src = (n < 512) ? (wihf + n*1024) : (wihb + (n-512)*1024);
      Blds[kk*129 + bn] = src[kc + kk];
    }
    __syncthreads();
    float bvr[32];
    #pragma unroll
    for (int kk = 0; kk < 32; ++kk) bvr[kk] = Blds[kk*129 + nn];
    #pragma unroll
    for (int q = 0; q < 16; ++q) {
      const float4* a4 = (const float4*)(Alds + (rg*16 + q)*36);
      float s0 = 0.0f;
      #pragma unroll
      for (int k4 = 0; k4 < 8; ++k4) {
        float4 a = a4[k4];
        s0 += a.x*bvr[4*k4] + a.y*bvr[4*k4+1] + a.z*bvr[4*k4+2] + a.w*bvr[4*k4+3];
      }
      acc[q] += s0;
    }
    __syncthreads();
  }
  int n = n0 + nn;
  float bias = (n < 512) ? bf[n] : bb[n-512];
  #pragma unroll
  for (int q = 0; q < 16; ++q) {
    int R = rt*32 + rg*16 + q;
    xcomb[R*1024 + n] = acc[q] + bias;
  }
}

// ---------- decoder embedding projection: decpre[t*16+b][n] (dec_b folded) ----------
__global__ __launch_bounds__(256) void k_embproj_dec(
    const float* __restrict__ emb, const int* __restrict__ abstr,
    const float* __restrict__ dwih, const float* __restrict__ db,
    float* __restrict__ decpre)
{
  const int rt = blockIdx.x;        // 48 row tiles of 32
  const int n0 = blockIdx.y * 128;  // 8 col tiles
  const int tid = threadIdx.x;
  __shared__ float Alds[32*36];
  __shared__ float Blds[32*129];
  __shared__ int toklds[32];
  if (tid < 32) {
    int R = rt*32 + tid;            // R = t*16 + b
    int t = R >> 4, b = R & 15;
    toklds[tid] = (t == 0) ? START_TOK : abstr[b*TT + t - 1];
  }
  __syncthreads();
  float acc[16];
  #pragma unroll
  for (int q = 0; q < 16; ++q) acc[q] = 0.0f;
  const int nn = tid & 127, rg = tid >> 7;
  for (int kc = 0; kc < 1024; kc += 32) {
    #pragma unroll
    for (int i = 0; i < 4; ++i) {
      int l = tid + i*256;
      int rr = l >> 5, kk = l & 31;
      Alds[rr*36 + kk] = emb[toklds[rr]*1024 + kc + kk];
    }
    #pragma unroll
    for (int i = 0; i < 16; ++i) {
      int l = tid + i*256;
      int bn = l >> 5, kk = l & 31;
      int n = n0 + bn;
      Blds[kk*129 + bn] = dwih[n*1280 + kc + kk];
    }
    __syncthreads();
    float bvr[32];
    #pragma unroll
    for (int kk = 0; kk < 32; ++kk) bvr[kk] = Blds[kk*129 + nn];
    #pragma unroll
    for (int q = 0; q < 16; ++q) {
      const float4* a4 = (const float4*)(Alds + (rg*16 + q)*36);
      float s0 = 0.0f;
      #pragma unroll
      for (int k4 = 0; k4 < 8; ++k4) {
        float4 a = a4[k4];
        s0 += a.x*bvr[4*k4] + a.y*bvr[4*k4+1] + a.z*bvr[4*k4+2] + a.w*bvr[4*k4+3];
      }
      acc[q] += s0;
    }
    __syncthreads();
  }
  int n = n0 + nn;
  float bias = db[n];
  #pragma unroll
  for (int q = 0; q < 16; ++q) {
    int R = rt*32 + rg*16 + q;
    decpre[R*1024 + n] = acc[q] + bias;
  }
}

// ---------- encoder: 1 WG per (batch, dir), 1024 thr, 64 wts/thread in regs ----------
__global__ __launch_bounds__(1024, 4) void k_encoder(
    const float* __restrict__ xcomb,
    const float* __restrict__ whhf, const float* __restrict__ whhb,
    float* __restrict__ encout,
    float* __restrict__ hpub,      // [16][256]: decoder h0
    float* __restrict__ c0buf)     // [16][256]
{
  const int b = blockIdx.x & 15, dir = blockIdx.x >> 4;
  const int t = threadIdx.x;       // 1024
  const int row = t & 511;         // gate row (i|f|g|o blocks of 128)
  const int ks = t >> 9;           // K-slice: 2 x 64
  const float* __restrict__ Whh = dir ? whhb : whhf;
  // 64 weights in registers, pinned
  float4 wr[16];
  #pragma unroll
  for (int j = 0; j < 16; ++j) {
    wr[j] = *(const float4*)(Whh + row*128 + ks*64 + j*4);
    PIN4(wr[j]);
  }
  __shared__ float hl[128];
  __shared__ float part[2][512];
  float c_reg = 0.0f;
  if (t < 128) hl[t] = 0.0f;
  __syncthreads();
  for (int s = 0; s < SS; ++s) {
    const int sf = dir ? (SS-1-s) : s;
    // prefetch x-projections for cell threads
    float xv0 = 0.f, xv1 = 0.f, xv2 = 0.f, xv3 = 0.f;
    if (t < 128) {
      const float* xrow = xcomb + (sf*NB + b)*1024 + dir*512 + t;
      xv0 = xrow[0]; xv1 = xrow[128]; xv2 = xrow[256]; xv3 = xrow[384];
    }
    // GEMM: 64 MACs, weights in regs, h broadcast from LDS
    const float* hs = hl + ks*64;
    float a0 = 0.f, a1 = 0.f, a2 = 0.f, a3 = 0.f;
    #pragma unroll
    for (int j = 0; j < 16; j += 4) {
      float4 h0 = *(const float4*)(hs + j*4);
      float4 h1 = *(const float4*)(hs + j*4 + 4);
      float4 h2 = *(const float4*)(hs + j*4 + 8);
      float4 h3 = *(const float4*)(hs + j*4 + 12);
      a0 += wr[j].x*h0.x + wr[j].y*h0.y + wr[j].z*h0.z + wr[j].w*h0.w;
      a1 += wr[j+1].x*h1.x + wr[j+1].y*h1.y + wr[j+1].z*h1.z + wr[j+1].w*h1.w;
      a2 += wr[j+2].x*h2.x + wr[j+2].y*h2.y + wr[j+2].z*h2.z + wr[j+2].w*h2.w;
      a3 += wr[j+3].x*h3.x + wr[j+3].y*h3.y + wr[j+3].z*h3.z + wr[j+3].w*h3.w;
    }
    part[ks][row] = (a0 + a1) + (a2 + a3);
    __syncthreads();
    if (t < 128) {
      float gi = part[0][t]       + part[1][t]       + xv0;
      float gf = part[0][128 + t] + part[1][128 + t] + xv1;
      float gg = part[0][256 + t] + part[1][256 + t] + xv2;
      float go = part[0][384 + t] + part[1][384 + t] + xv3;
      float iv = sigmf(gi), fv = sigmf(gf), gv = tanhf_(gg), ov = sigmf(go);
      c_reg = fv*c_reg + iv*gv;
      float hv = ov*tanhf_(c_reg);
      hl[t] = hv;
      encout[(b*SS + sf)*HH + dir*HL + t] = hv;
    }
    __syncthreads();
  }
  if (t < 128) {
    hpub[b*HH + dir*HL + t] = hl[t];
    c0buf[b*HH + dir*HL + t] = c_reg;
  }
}

// ---------- enc_ws = enc_out @ attn_s_W.T + b, row-major [b][s][a] ----------
__global__ __launch_bounds__(256) void k_encws(
    const float* __restrict__ encout,
    const float* __restrict__ asW, const float* __restrict__ asb,
    float* __restrict__ encwsR)
{
  const int rt = blockIdx.x;  // 200 tiles of 32 rows (row = b*400+s)
  const int tid = threadIdx.x;
  __shared__ float Al[32*260];
  #pragma unroll
  for (int i = 0; i < 32; ++i) {
    int l = tid + i*256;
    int r = l >> 8, k = l & 255;
    Al[r*260 + k] = encout[(rt*32 + r)*256 + k];
  }
  __syncthreads();
  const int a = tid & 63, rg = tid >> 6;
  float acc[8];
  #pragma unroll
  for (int q = 0; q < 8; ++q) acc[q] = 0.0f;
  const float4* w4 = (const float4*)(asW + a*256);
  for (int k4 = 0; k4 < 64; ++k4) {
    float4 w = w4[k4];
    #pragma unroll
    for (int q = 0; q < 8; ++q) {
      const float4* a4 = (const float4*)(Al + (rg*8 + q)*260);
      float4 av = a4[k4];
      acc[q] += av.x*w.x + av.y*w.y + av.z*w.z + av.w*w.w;
    }
  }
  float bias = asb[a];
  #pragma unroll
  for (int q = 0; q < 8; ++q) {
    int row = rt*32 + rg*8 + q;
    encwsR[row*64 + a] = acc[q] + bias;
  }
}

// ---------- decoder: 8 WGs x 16 batches; all per-step state in LDS; online-softmax partials ----------
__global__ __launch_bounds__(1024, 4) void k_decoder(
    const float* __restrict__ decpre,
    const float* __restrict__ dwhh,   // [1024][256]
    const float* __restrict__ dwih,   // [1024][1280]
    const float* __restrict__ ahW, const float* __restrict__ ahb,
    const float* __restrict__ afW, const float* __restrict__ afb,
    const float* __restrict__ encwsR, // [b*400+s][64]
    const float* __restrict__ encout, // [b*400+s][256]
    const int* __restrict__ alen,
    const float* __restrict__ c0buf,  // [16][256]
    float* hpub,                      // [16][256], pre-filled with h0 by encoder
    float* cpub,                      // [16][8][272]: ctxu[256] | m | s
    float* __restrict__ dhall,        // [96*16][256]
    int* flags)
{
  const int wg = blockIdx.x;
  const int g = wg >> 4, b = wg & 15;   // unit-group / s-slice, batch
  const int t = threadIdx.x;            // 1024
  const int r = t & 127, ks = t >> 7;   // row-in-WG (128), K-slice (8 x 64)
  const int q = r >> 5, uu = r & 31;
  const int grow = q*256 + g*32 + uu;   // global gate row
  const int s0 = g*50;                  // this WG's source-slice start

  // 64-float weight slice in registers, pinned
  float4 wr[16];
  #pragma unroll
  for (int j = 0; j < 16; ++j) {
    int k = ks*64 + j*4;
    wr[j] = (k < 256) ? *(const float4*)(dwhh + grow*256 + k)
                      : *(const float4*)(dwih + grow*1280 + 1024 + (k - 256));
    PIN4(wr[j]);
  }

  __shared__ float encl[50*256];   // encout slice       (51200 B)
  __shared__ float wsl[50*68];     // enc_ws slice, pad  (13600 B)
  __shared__ float ahWt[256*68];   // ahW transposed,pad (69632 B)
  __shared__ float hc[512];        // [h(256) | ctx(256)]
  __shared__ float part[8][132];
  __shared__ float gates[128];
  __shared__ float wh[64];
  __shared__ float whp[16][68];
  __shared__ float fwl[64];
  __shared__ float scl[64];        // p values for own slice
  __shared__ float scp[50][17];    // score partials
  __shared__ float cpart[2][256];
  __shared__ float mg[8], sg[8];
  __shared__ float sh_m, sh_s;

  // ---- one-time stage-in ----
  for (int i = t; i < 50*256; i += 1024) {
    int si = i >> 8, d = i & 255;
    encl[i] = encout[(b*SS + s0 + si)*HH + d];
  }
  for (int i = t; i < 50*64; i += 1024) {
    int si = i >> 6, a = i & 63;
    wsl[si*68 + a] = encwsR[(b*SS + s0 + si)*64 + a];
  }
  for (int i = t; i < 64*256; i += 1024) {
    int a = i >> 8, k = i & 255;
    ahWt[k*68 + a] = ahW[i];
  }
  if (t < 64) fwl[t] = afW[t];
  const float fb0 = afb[0];
  int len = alen[b]; len = min(max(len, 1), SS);
  float c_reg = (t < 32) ? c0buf[b*HH + g*32 + t] : 0.0f;
  if (t < 256) { hc[t] = gload(hpub + b*HH + t); hc[256 + t] = 0.0f; }
  __syncthreads();

  for (int tt = 0; tt < TT; ++tt) {
    // prefetch decpre for reduce threads
    float pre = 0.f;
    if (t < 128)
      pre = decpre[(tt*NB + b)*1024 + (t >> 5)*256 + g*32 + (t & 31)];
    // ---- gates GEMM: 64 MACs/thread, weights in regs, hc broadcast ----
    const float* hs = hc + ks*64;
    float a0 = 0.f, a1 = 0.f, a2 = 0.f, a3 = 0.f;
    #pragma unroll
    for (int j = 0; j < 16; j += 4) {
      float4 h0 = *(const float4*)(hs + j*4);
      float4 h1 = *(const float4*)(hs + j*4 + 4);
      float4 h2 = *(const float4*)(hs + j*4 + 8);
      float4 h3 = *(const float4*)(hs + j*4 + 12);
      a0 += wr[j].x*h0.x + wr[j].y*h0.y + wr[j].z*h0.z + wr[j].w*h0.w;
      a1 += wr[j+1].x*h1.x + wr[j+1].y*h1.y + wr[j+1].z*h1.z + wr[j+1].w*h1.w;
      a2 += wr[j+2].x*h2.x + wr[j+2].y*h2.y + wr[j+2].z*h2.z + wr[j+2].w*h2.w;
      a3 += wr[j+3].x*h3.x + wr[j+3].y*h3.y + wr[j+3].z*h3.z + wr[j+3].w*h3.w;
    }
    part[ks][r] = (a0 + a1) + (a2 + a3);
    __syncthreads();
    if (t < 128) {
      float gv = pre;
      #pragma unroll
      for (int j = 0; j < 8; ++j) gv += part[j][t];
      gates[t] = gv;
    }
    __syncthreads();
    // ---- cell update: threads 0..31 own units g*32+t ----
    if (t < 32) {
      float gi = gates[t], gf = gates[32+t], gg = gates[64+t], go = gates[96+t];
      float iv = sigmf(gi), fv = sigmf(gf), gv = tanhf_(gg), ov = sigmf(go);
      c_reg = fv*c_reg + iv*gv;
      float hv = ov*tanhf_(c_reg);
      int u = g*32 + t;
      gstore(hpub + b*HH + u, hv);
      dhall[(tt*NB + b)*HH + u] = hv;
    }
    flagbar(flags, b, g, 2*tt + 1);
    // ---- stage h_new ----
    if (t < 256) hc[t] = gload(hpub + b*HH + t);
    __syncthreads();
    // ---- wh[a] = ahb + ahW @ h_new, from LDS (conflict-free) ----
    {
      int kq = t >> 6, a = t & 63;   // 16 k-slices x 64 a
      float p = 0.f;
      #pragma unroll
      for (int k = 0; k < 16; ++k) p += ahWt[(kq*16 + k)*68 + a] * hc[kq*16 + k];
      whp[kq][a] = p;
    }
    __syncthreads();
    if (t < 64) {
      float s0v = 0.f;
      #pragma unroll
      for (int kq = 0; kq < 16; ++kq) s0v += whp[kq][t];
      wh[t] = ahb[t] + s0v;
    }
    __syncthreads();
    // ---- scores for own 50-source slice, from LDS ----
    if (t < 800) {
      int s = t >> 4, j = t & 15;
      const float* wrow = wsl + s*68 + j*4;
      float p = fwl[j*4]   * tanhf_(wrow[0] + wh[j*4])
              + fwl[j*4+1] * tanhf_(wrow[1] + wh[j*4+1])
              + fwl[j*4+2] * tanhf_(wrow[2] + wh[j*4+2])
              + fwl[j*4+3] * tanhf_(wrow[3] + wh[j*4+3]);
      scp[s][j] = p;
    }
    __syncthreads();
    // ---- slice softmax partials in one wave ----
    if (t < 64) {
      float sc = -1e30f;
      if (t < 50) {
        sc = fb0;
        #pragma unroll
        for (int j = 0; j < 16; ++j) sc += scp[t][j];
        sc = fminf(sc, (s0 + t < len) ? 9999.0f : -9999.0f);
      }
      float m = sc;
      #pragma unroll
      for (int o = 32; o; o >>= 1) m = fmaxf(m, __shfl_xor(m, o));
      float p = (t < 50) ? __expf(sc - m) : 0.0f;
      scl[t] = p;
      float ssum = p;
      #pragma unroll
      for (int o = 32; o; o >>= 1) ssum += __shfl_xor(ssum, o);
      if (t == 0) { sh_m = m; sh_s = ssum; }
    }
    __syncthreads();
    // ---- unnormalized ctx partial over own slice, from LDS ----
    if (t < 512) {
      int d = t & 255, half = t >> 8;
      float acc = 0.f;
      const float* eb = encl + (half*25)*256 + d;
      #pragma unroll 5
      for (int i = 0; i < 25; ++i) acc += scl[half*25 + i] * eb[i*256];
      cpart[half][d] = acc;
    }
    __syncthreads();
    if (t < 256) gstore(cpub + (b*8 + g)*272 + t, cpart[0][t] + cpart[1][t]);
    else if (t == 256) gstore(cpub + (b*8 + g)*272 + 256, sh_m);
    else if (t == 257) gstore(cpub + (b*8 + g)*272 + 257, sh_s);
    flagbar(flags, b, g, 2*tt + 2);
    // ---- combine 8 online-softmax partials (deterministic order) ----
    if (t < 8)  mg[t] = gload(cpub + (b*8 + t)*272 + 256);
    else if (t < 16) sg[t-8] = gload(cpub + (b*8 + (t-8))*272 + 257);
    __syncthreads();
    if (t < 256) {
      float M = mg[0];
      #pragma unroll
      for (int j = 1; j < 8; ++j) M = fmaxf(M, mg[j]);
      float denom = 0.f;
      #pragma unroll
      for (int j = 0; j < 8; ++j) denom += sg[j] * __expf(mg[j] - M);
      float inv = 1.0f / denom;
      float ctx = 0.f;
      #pragma unroll
      for (int j = 0; j < 8; ++j)
        ctx += gload(cpub + (b*8 + j)*272 + t) * __expf(mg[j] - M);
      hc[256 + t] = ctx * inv;
    }
    __syncthreads();
  }
}

// ---------- vocab logits + per-chunk logsumexp partials ----------
__global__ __launch_bounds__(256) void k_pred(
    const float* __restrict__ dhall,
    const float* __restrict__ predW,
    const float* __restrict__ predb,
    float* __restrict__ pm, float* __restrict__ ps)
{
  const int rt = blockIdx.x;   // 48 (rows of 32)
  const int ch = blockIdx.y;   // 120 (cols of 256)
  const int tid = threadIdx.x;
  __shared__ float Al[32*260];
  __shared__ float Bl[256*17];
  #pragma unroll
  for (int i = 0; i < 32; ++i) {
    int l = tid + i*256;
    int r = l >> 8, k = l & 255;
    Al[r*260 + k] = dhall[(rt*32 + r)*256 + k];
  }
  const int v = ch*256 + tid;
  float acc[32];
  #pragma unroll
  for (int r = 0; r < 32; ++r) acc[r] = 0.0f;
  for (int kc = 0; kc < 16; ++kc) {
    __syncthreads();
    #pragma unroll
    for (int i = 0; i < 16; ++i) {
      int l = tid + i*256;
      int vv = l >> 4, kk = l & 15;
      int col = ch*256 + vv;
      Bl[vv*17 + kk] = (col < VV) ? predW[col*256 + kc*16 + kk] : 0.0f;
    }
    __syncthreads();
    float bvr[16];
    #pragma unroll
    for (int kk = 0; kk < 16; ++kk) bvr[kk] = Bl[tid*17 + kk];
    #pragma unroll
    for (int r = 0; r < 32; ++r) {
      const float4* a4 = (const float4*)(Al + r*260 + kc*16);
      float s0 = 0.0f;
      #pragma unroll
      for (int k4 = 0; k4 < 4; ++k4) {
        float4 a = a4[k4];
        s0 += a.x*bvr[4*k4] + a.y*bvr[4*k4+1] + a.z*bvr[4*k4+2] + a.w*bvr[4*k4+3];
      }
      acc[r] += s0;
    }
  }
  float bias = (v < VV) ? predb[v] : 0.0f;
  __syncthreads();
  #pragma unroll
  for (int r = 0; r < 32; ++r)
    Al[r*260 + tid] = (v < VV) ? (acc[r] + bias) : -1e30f;
  __syncthreads();
  if (tid < 32) {
    int row = rt*32 + tid;
    float m = -1e30f;
    for (int c = 0; c < 256; ++c) m = fmaxf(m, Al[tid*260 + c]);
    float ssum = 0.0f;
    for (int c = 0; c < 256; ++c) ssum += __expf(Al[tid*260 + c] - m);
    pm[row*NCHUNK + ch] = m;
    ps[row*NCHUNK + ch] = ssum;
  }
}

// ---------- loss partials: 6 WGs x 256 threads, one row per thread ----------
__global__ __launch_bounds__(256) void k_loss_part(
    const float* __restrict__ pm, const float* __restrict__ ps,
    const float* __restrict__ dhall,
    const float* __restrict__ predW, const float* __restrict__ predb,
    const int* __restrict__ abstr, float* __restrict__ lpart)
{
  const int tid = threadIdx.x;
  const int row = blockIdx.x*256 + tid;   // < 1536
  __shared__ float rs[256], rc[256];
  float lsum = 0.0f, lcnt = 0.0f;
  {
    int t = row >> 4, b = row & 15;
    int tok = abstr[b*TT + t];
    float m = -1e30f;
    for (int c = 0; c < NCHUNK; ++c) m = fmaxf(m, pm[row*NCHUNK + c]);
    float ss = 0.0f;
    for (int c = 0; c < NCHUNK; ++c) ss += ps[row*NCHUNK + c] * __expf(pm[row*NCHUNK + c] - m);
    float lse = m + __logf(ss);
    float tl = predb[tok];
    const float* hrow = dhall + row*256;
    const float* wrow = predW + tok*256;
    #pragma unroll 4
    for (int k = 0; k < 256; ++k) tl += hrow[k] * wrow[k];
    if (tok != 0) { lsum = lse - tl; lcnt = 1.0f; }
  }
  rs[tid] = lsum; rc[tid] = lcnt;
  __syncthreads();
  for (int st = 128; st; st >>= 1) {
    if (tid < st) { rs[tid] += rs[tid + st]; rc[tid] += rc[tid + st]; }
    __syncthreads();
  }
  if (tid == 0) { lpart[blockIdx.x*2] = rs[0]; lpart[blockIdx.x*2 + 1] = rc[0]; }
}

// ---------- final: deterministic sum of 6 partials ----------
__global__ void k_loss_final(const float* __restrict__ lpart, float* __restrict__ out) {
  if (threadIdx.x == 0) {
    float s = 0.f, c = 0.f;
    for (int i = 0; i < 6; ++i) { s += lpart[i*2]; c += lpart[i*2 + 1]; }
    out[0] = s / fmaxf(c, 1.0f);
  }
}

// ---------- launch ----------
extern "C" void kernel_launch(void* const* d_in, const int* in_sizes, int n_in,
                              void* d_out, int out_size, void* d_ws, size_t ws_size,
                              hipStream_t stream) {
  const float* emb   = (const float*)d_in[0];
  const int* article = (const int*)d_in[1];
  const int* alen    = (const int*)d_in[2];
  const int* abstr   = (const int*)d_in[3];
  const float* eWihF = (const float*)d_in[4];
  const float* eWhhF = (const float*)d_in[5];
  const float* ebF   = (const float*)d_in[6];
  const float* eWihB = (const float*)d_in[7];
  const float* eWhhB = (const float*)d_in[8];
  const float* ebB   = (const float*)d_in[9];
  const float* dWih  = (const float*)d_in[10];
  const float* dWhh  = (const float*)d_in[11];
  const float* db    = (const float*)d_in[12];
  const float* pW    = (const float*)d_in[13];
  const float* pb    = (const float*)d_in[14];
  const float* asW   = (const float*)d_in[15];
  const float* asb   = (const float*)d_in[16];
  const float* ahW   = (const float*)d_in[17];
  const float* ahb   = (const float*)d_in[18];
  const float* afW   = (const float*)d_in[19];
  const float* afb   = (const float*)d_in[20];
  float* out = (float*)d_out;

  float* w = (float*)d_ws;
  size_t o = 0;
  float* xcomb  = w + o; o += (size_t)SS*NB*1024;
  float* encout = w + o; o += (size_t)NB*SS*HH;
  float* encwsR = w + o; o += (size_t)NB*SS*AA;
  float* decpre = w + o; o += (size_t)TT*NB*1024;
  float* dhall  = w + o; o += (size_t)TT*NB*HH;
  float* hpub   = w + o; o += NB*HH;
  float* cpub   = w + o; o += NB*8*272;
  float* c0buf  = w + o; o += NB*HH;
  float* pm     = w + o; o += (size_t)TT*NB*NCHUNK;
  float* ps     = w + o; o += (size_t)TT*NB*NCHUNK;
  float* lpart  = w + o; o += 16;
  int* flags = (int*)(w + o); o += 16*8*16;

  k_init<<<1, 256, 0, stream>>>(flags);
  k_embproj_enc<<<dim3(200, 8), 256, 0, stream>>>(emb, article, eWihF, eWihB, ebF, ebB, xcomb);
  k_embproj_dec<<<dim3(48, 8), 256, 0, stream>>>(emb, abstr, dWih, db, decpre);
  k_encoder<<<32, 1024, 0, stream>>>(xcomb, eWhhF, eWhhB, encout, hpub, c0buf);
  k_encws<<<200, 256, 0, stream>>>(encout, asW, asb, encwsR);
  k_decoder<<<128, 1024, 0, stream>>>(decpre, dWhh, dWih, ahW, ahb, afW, afb,
                                      encwsR, encout, alen, c0buf, hpub, cpub, dhall, flags);
  k_pred<<<dim3(48, 120), 256, 0, stream>>>(dhall, pW, pb, pm, ps);
  k_loss_part<<<6, 256, 0, stream>>>(pm, ps, dhall, pW, pb, abstr, lpart);
  k_loss_final<<<1, 64, 0, stream>>>(lpart, out);
}

// Round 6
// 2007.058 us; speedup vs baseline: 6.1117x; 2.0818x over previous
//
#include <hip/hip_runtime.h>
#include <cmath>

#define NB 16      // batch
#define SS 400     // source len
#define TT 96      // target len
#define HL 128     // LSTM per dir
#define HH 256     // decoder hidden (2*HL)
#define AA 64      // attn dim
#define VV 30611   // vocab
#define VVP 30720  // vocab padded to 256
#define START_TOK 101
#define NCHUNK 120 // vocab chunks of 256

typedef __attribute__((ext_vector_type(8))) short bf16x8;
typedef __attribute__((ext_vector_type(4))) float f32x4;

// keep a loaded float4 live in VGPRs (forbid rematerialization / load sinking)
#define PIN4(v) asm volatile("" : "+v"((v).x), "+v"((v).y), "+v"((v).z), "+v"((v).w))
// LDS-only barrier: no vmcnt drain (global stores stay in flight)
#define LBAR() asm volatile("s_waitcnt lgkmcnt(0)\n\ts_barrier" ::: "memory")

// ---------- helpers ----------
__device__ __forceinline__ float gload(const float* p) {
  return __hip_atomic_load(p, __ATOMIC_RELAXED, __HIP_MEMORY_SCOPE_AGENT);
}
__device__ __forceinline__ void gstore(float* p, float v) {
  __hip_atomic_store(p, v, __ATOMIC_RELAXED, __HIP_MEMORY_SCOPE_AGENT);
}
__device__ __forceinline__ float sigmf(float x) { return 1.0f / (1.0f + __expf(-x)); }
__device__ __forceinline__ float tanhf_(float x) {
  float xc = fminf(fmaxf(x, -15.0f), 15.0f);
  return 1.0f - 2.0f / (__expf(2.0f * xc) + 1.0f);
}
__device__ __forceinline__ short f2bf(float f) {
  unsigned u = __float_as_uint(f);
  unsigned r = (u + 0x7FFFu + ((u >> 16) & 1u)) >> 16;
  return (short)r;
}
// flag barrier: 8 WGs per batch, single-writer flags, release store + acquire poll
__device__ __forceinline__ void flagbar(int* flags, int b, int g, int target) {
  __syncthreads();
  if (threadIdx.x == 0)
    __hip_atomic_store(&flags[(b*8 + g)*16], target, __ATOMIC_RELEASE, __HIP_MEMORY_SCOPE_AGENT);
  if (threadIdx.x < 64) {
    int j = threadIdx.x & 7;
    while (__hip_atomic_load(&flags[(b*8 + j)*16], __ATOMIC_ACQUIRE, __HIP_MEMORY_SCOPE_AGENT) < target)
      __builtin_amdgcn_s_sleep(1);
  }
  __syncthreads();
}

// ---------- init: zero flags ----------
__global__ __launch_bounds__(256) void k_init(int* flags) {
  for (int i = threadIdx.x; i < 16*8*16; i += 256) flags[i] = 0;
}

// ---------- cast weights to bf16 ----------
__global__ __launch_bounds__(256) void k_casts(
    const float* __restrict__ predW, const float* __restrict__ wf,
    const float* __restrict__ wb, const float* __restrict__ dwih,
    short* __restrict__ predWb, short* __restrict__ wfB,
    short* __restrict__ wbB, short* __restrict__ dwB)
{
  const int stride = gridDim.x * 256;
  const int t0 = blockIdx.x * 256 + threadIdx.x;
  for (int i = t0; i < VVP*256; i += stride)
    predWb[i] = (i < VV*256) ? f2bf(predW[i]) : (short)0;
  for (int i = t0; i < 512*1024; i += stride) wfB[i] = f2bf(wf[i]);
  for (int i = t0; i < 512*1024; i += stride) wbB[i] = f2bf(wb[i]);
  for (int i = t0; i < 1024*1024; i += stride) {
    int r = i >> 10, k = i & 1023;
    dwB[i] = f2bf(dwih[r*1280 + k]);
  }
}

// ---------- encoder input projection via MFMA: xcomb[R][n] = emb[tok(R)] @ W^T + b ----------
__global__ __launch_bounds__(256) void k_embproj_enc_mfma(
    const float* __restrict__ emb, const int* __restrict__ article,
    const short* __restrict__ wfB, const short* __restrict__ wbB,
    const float* __restrict__ bf, const float* __restrict__ bb,
    float* __restrict__ xcomb)
{
  const int m0 = blockIdx.x * 64;    // 100 row tiles
  const int n0 = blockIdx.y * 256;   // 4 col tiles
  const int t = threadIdx.x;
  const int w = t >> 6, l = t & 63;
  __shared__ short Abuf[64*136];
  __shared__ int tok[64];
  if (t < 64) {
    int R = m0 + t, s = R >> 4, b = R & 15;
    tok[t] = article[b*SS + s];
  }
  const short* __restrict__ Wb = (n0 < 512) ? wfB : wbB;
  const int nb0 = (n0 < 512) ? n0 : (n0 - 512);
  f32x4 acc[4][4];
  #pragma unroll
  for (int i = 0; i < 4; ++i)
    #pragma unroll
    for (int j = 0; j < 4; ++j) acc[i][j] = (f32x4){0.f,0.f,0.f,0.f};
  __syncthreads();
  const int ar = t >> 2, ak0 = (t & 3) * 32;
  for (int kc = 0; kc < 8; ++kc) {
    // stage gathered A chunk (fp32 -> bf16)
    const float* src = emb + (size_t)tok[ar]*1024 + kc*128 + ak0;
    #pragma unroll
    for (int j = 0; j < 8; ++j) {
      float4 v = *(const float4*)(src + 4*j);
      short4 s4; s4.x = f2bf(v.x); s4.y = f2bf(v.y); s4.z = f2bf(v.z); s4.w = f2bf(v.w);
      *(short4*)(&Abuf[ar*136 + ak0 + 4*j]) = s4;
    }
    LBAR();
    #pragma unroll
    for (int ks = 0; ks < 4; ++ks) {
      bf16x8 af[4];
      #pragma unroll
      for (int mr = 0; mr < 4; ++mr)
        af[mr] = *(const bf16x8*)(&Abuf[(mr*16 + (l & 15))*136 + ks*32 + (l >> 4)*8]);
      #pragma unroll
      for (int ct = 0; ct < 4; ++ct) {
        int n = nb0 + w*64 + ct*16 + (l & 15);
        bf16x8 bfr = *(const bf16x8*)(Wb + (size_t)n*1024 + kc*128 + ks*32 + (l >> 4)*8);
        #pragma unroll
        for (int mr = 0; mr < 4; ++mr)
          acc[mr][ct] = __builtin_amdgcn_mfma_f32_16x16x32_bf16(af[mr], bfr, acc[mr][ct], 0, 0, 0);
      }
    }
    LBAR();
  }
  // epilogue
  #pragma unroll
  for (int ct = 0; ct < 4; ++ct) {
    int n = n0 + w*64 + ct*16 + (l & 15);
    float bias = (n < 512) ? bf[n] : bb[n - 512];
    #pragma unroll
    for (int mr = 0; mr < 4; ++mr) {
      #pragma unroll
      for (int r = 0; r < 4; ++r) {
        int R = m0 + mr*16 + (l >> 4)*4 + r;
        xcomb[(size_t)R*1024 + n] = acc[mr][ct][r] + bias;
      }
    }
  }
}

// ---------- decoder embedding projection via MFMA (dec_b folded) ----------
__global__ __launch_bounds__(256) void k_embproj_dec_mfma(
    const float* __restrict__ emb, const int* __restrict__ abstr,
    const short* __restrict__ dwB, const float* __restrict__ db,
    float* __restrict__ decpre)
{
  const int m0 = blockIdx.x * 64;    // 24 row tiles
  const int n0 = blockIdx.y * 256;   // 4 col tiles
  const int t = threadIdx.x;
  const int w = t >> 6, l = t & 63;
  __shared__ short Abuf[64*136];
  __shared__ int tok[64];
  if (t < 64) {
    int R = m0 + t, tt = R >> 4, b = R & 15;
    tok[t] = (tt == 0) ? START_TOK : abstr[b*TT + tt - 1];
  }
  f32x4 acc[4][4];
  #pragma unroll
  for (int i = 0; i < 4; ++i)
    #pragma unroll
    for (int j = 0; j < 4; ++j) acc[i][j] = (f32x4){0.f,0.f,0.f,0.f};
  __syncthreads();
  const int ar = t >> 2, ak0 = (t & 3) * 32;
  for (int kc = 0; kc < 8; ++kc) {
    const float* src = emb + (size_t)tok[ar]*1024 + kc*128 + ak0;
    #pragma unroll
    for (int j = 0; j < 8; ++j) {
      float4 v = *(const float4*)(src + 4*j);
      short4 s4; s4.x = f2bf(v.x); s4.y = f2bf(v.y); s4.z = f2bf(v.z); s4.w = f2bf(v.w);
      *(short4*)(&Abuf[ar*136 + ak0 + 4*j]) = s4;
    }
    LBAR();
    #pragma unroll
    for (int ks = 0; ks < 4; ++ks) {
      bf16x8 af[4];
      #pragma unroll
      for (int mr = 0; mr < 4; ++mr)
        af[mr] = *(const bf16x8*)(&Abuf[(mr*16 + (l & 15))*136 + ks*32 + (l >> 4)*8]);
      #pragma unroll
      for (int ct = 0; ct < 4; ++ct) {
        int n = n0 + w*64 + ct*16 + (l & 15);
        bf16x8 bfr = *(const bf16x8*)(dwB + (size_t)n*1024 + kc*128 + ks*32 + (l >> 4)*8);
        #pragma unroll
        for (int mr = 0; mr < 4; ++mr)
          acc[mr][ct] = __builtin_amdgcn_mfma_f32_16x16x32_bf16(af[mr], bfr, acc[mr][ct], 0, 0, 0);
      }
    }
    LBAR();
  }
  #pragma unroll
  for (int ct = 0; ct < 4; ++ct) {
    int n = n0 + w*64 + ct*16 + (l & 15);
    float bias = db[n];
    #pragma unroll
    for (int mr = 0; mr < 4; ++mr) {
      #pragma unroll
      for (int r = 0; r < 4; ++r) {
        int R = m0 + mr*16 + (l >> 4)*4 + r;
        decpre[(size_t)R*1024 + n] = acc[mr][ct][r] + bias;
      }
    }
  }
}

// ---------- encoder: 1 WG per (batch, dir), 1024 thr, 64 wts/thread in regs ----------
__global__ __launch_bounds__(1024, 4) void k_encoder(
    const float* __restrict__ xcomb,
    const float* __restrict__ whhf, const float* __restrict__ whhb,
    float* __restrict__ encout,
    float* __restrict__ hpub,      // [16][256]: decoder h0
    float* __restrict__ c0buf)     // [16][256]
{
  const int b = blockIdx.x & 15, dir = blockIdx.x >> 4;
  const int t = threadIdx.x;       // 1024
  const int row = t & 511;         // gate row (i|f|g|o blocks of 128)
  const int ks = t >> 9;           // K-slice: 2 x 64
  const float* __restrict__ Whh = dir ? whhb : whhf;
  float4 wr[16];
  #pragma unroll
  for (int j = 0; j < 16; ++j) {
    wr[j] = *(const float4*)(Whh + row*128 + ks*64 + j*4);
    PIN4(wr[j]);
  }
  __shared__ float hl[128];
  __shared__ float part[2][512];
  float c_reg = 0.0f;
  if (t < 128) hl[t] = 0.0f;
  __syncthreads();
  for (int s = 0; s < SS; ++s) {
    const int sf = dir ? (SS-1-s) : s;
    float xv0 = 0.f, xv1 = 0.f, xv2 = 0.f, xv3 = 0.f;
    if (t < 128) {
      const float* xrow = xcomb + (sf*NB + b)*1024 + dir*512 + t;
      xv0 = xrow[0]; xv1 = xrow[128]; xv2 = xrow[256]; xv3 = xrow[384];
    }
    const float* hs = hl + ks*64;
    float a0 = 0.f, a1 = 0.f, a2 = 0.f, a3 = 0.f;
    #pragma unroll
    for (int j = 0; j < 16; j += 4) {
      float4 h0 = *(const float4*)(hs + j*4);
      float4 h1 = *(const float4*)(hs + j*4 + 4);
      float4 h2 = *(const float4*)(hs + j*4 + 8);
      float4 h3 = *(const float4*)(hs + j*4 + 12);
      a0 += wr[j].x*h0.x + wr[j].y*h0.y + wr[j].z*h0.z + wr[j].w*h0.w;
      a1 += wr[j+1].x*h1.x + wr[j+1].y*h1.y + wr[j+1].z*h1.z + wr[j+1].w*h1.w;
      a2 += wr[j+2].x*h2.x + wr[j+2].y*h2.y + wr[j+2].z*h2.z + wr[j+2].w*h2.w;
      a3 += wr[j+3].x*h3.x + wr[j+3].y*h3.y + wr[j+3].z*h3.z + wr[j+3].w*h3.w;
    }
    part[ks][row] = (a0 + a1) + (a2 + a3);
    LBAR();
    if (t < 128) {
      float gi = part[0][t]       + part[1][t]       + xv0;
      float gf = part[0][128 + t] + part[1][128 + t] + xv1;
      float gg = part[0][256 + t] + part[1][256 + t] + xv2;
      float go = part[0][384 + t] + part[1][384 + t] + xv3;
      float iv = sigmf(gi), fv = sigmf(gf), gv = tanhf_(gg), ov = sigmf(go);
      c_reg = fv*c_reg + iv*gv;
      float hv = ov*tanhf_(c_reg);
      hl[t] = hv;
      encout[(b*SS + sf)*HH + dir*HL + t] = hv;
    }
    LBAR();
  }
  if (t < 128) {
    hpub[b*HH + dir*HL + t] = hl[t];
    c0buf[b*HH + dir*HL + t] = c_reg;
  }
}

// ---------- enc_ws = enc_out @ attn_s_W.T + b, row-major [b][s][a] ----------
__global__ __launch_bounds__(256) void k_encws(
    const float* __restrict__ encout,
    const float* __restrict__ asW, const float* __restrict__ asb,
    float* __restrict__ encwsR)
{
  const int rt = blockIdx.x;  // 200 tiles of 32 rows (row = b*400+s)
  const int tid = threadIdx.x;
  __shared__ float Al[32*260];
  #pragma unroll
  for (int i = 0; i < 32; ++i) {
    int l = tid + i*256;
    int r = l >> 8, k = l & 255;
    Al[r*260 + k] = encout[(rt*32 + r)*256 + k];
  }
  __syncthreads();
  const int a = tid & 63, rg = tid >> 6;
  float acc[8];
  #pragma unroll
  for (int q = 0; q < 8; ++q) acc[q] = 0.0f;
  const float4* w4 = (const float4*)(asW + a*256);
  for (int k4 = 0; k4 < 64; ++k4) {
    float4 w = w4[k4];
    #pragma unroll
    for (int q = 0; q < 8; ++q) {
      const float4* a4 = (const float4*)(Al + (rg*8 + q)*260);
      float4 av = a4[k4];
      acc[q] += av.x*w.x + av.y*w.y + av.z*w.z + av.w*w.w;
    }
  }
  float bias = asb[a];
  #pragma unroll
  for (int q = 0; q < 8; ++q) {
    int row = rt*32 + rg*8 + q;
    encwsR[row*64 + a] = acc[q] + bias;
  }
}

// ---------- decoder: 8 WGs x 16 batches; all per-step state in LDS; online-softmax partials ----------
__global__ __launch_bounds__(1024, 4) void k_decoder(
    const float* __restrict__ decpre,
    const float* __restrict__ dwhh,   // [1024][256]
    const float* __restrict__ dwih,   // [1024][1280]
    const float* __restrict__ ahW, const float* __restrict__ ahb,
    const float* __restrict__ afW, const float* __restrict__ afb,
    const float* __restrict__ encwsR, // [b*400+s][64]
    const float* __restrict__ encout, // [b*400+s][256]
    const int* __restrict__ alen,
    const float* __restrict__ c0buf,  // [16][256]
    float* hpub,                      // [16][256], pre-filled with h0 by encoder
    float* cpub,                      // [16][8][272]: ctxu[256] | m | s
    float* __restrict__ dhall,        // [96*16][256]
    int* flags)
{
  const int wg = blockIdx.x;
  const int g = wg >> 4, b = wg & 15;   // unit-group / s-slice, batch
  const int t = threadIdx.x;            // 1024
  const int r = t & 127, ks = t >> 7;   // row-in-WG (128), K-slice (8 x 64)
  const int q = r >> 5, uu = r & 31;
  const int grow = q*256 + g*32 + uu;   // global gate row
  const int s0 = g*50;                  // this WG's source-slice start

  float4 wr[16];
  #pragma unroll
  for (int j = 0; j < 16; ++j) {
    int k = ks*64 + j*4;
    wr[j] = (k < 256) ? *(const float4*)(dwhh + grow*256 + k)
                      : *(const float4*)(dwih + grow*1280 + 1024 + (k - 256));
    PIN4(wr[j]);
  }

  __shared__ float encl[50*256];
  __shared__ float wsl[50*68];
  __shared__ float ahWt[256*68];
  __shared__ float hc[512];        // [h(256) | ctx(256)]
  __shared__ float part[8][132];
  __shared__ float gates[128];
  __shared__ float wh[64];
  __shared__ float whp[16][68];
  __shared__ float fwl[64];
  __shared__ float scl[64];
  __shared__ float scp[50][17];
  __shared__ float cpart[2][256];
  __shared__ float mg[8], sg[8];
  __shared__ float sh_m, sh_s;

  for (int i = t; i < 50*256; i += 1024) {
    int si = i >> 8, d = i & 255;
    encl[i] = encout[(b*SS + s0 + si)*HH + d];
  }
  for (int i = t; i < 50*64; i += 1024) {
    int si = i >> 6, a = i & 63;
    wsl[si*68 + a] = encwsR[(b*SS + s0 + si)*64 + a];
  }
  for (int i = t; i < 64*256; i += 1024) {
    int a = i >> 8, k = i & 255;
    ahWt[k*68 + a] = ahW[i];
  }
  if (t < 64) fwl[t] = afW[t];
  const float fb0 = afb[0];
  int len = alen[b]; len = min(max(len, 1), SS);
  float c_reg = (t < 32) ? c0buf[b*HH + g*32 + t] : 0.0f;
  if (t < 256) { hc[t] = gload(hpub + b*HH + t); hc[256 + t] = 0.0f; }
  __syncthreads();

  for (int tt = 0; tt < TT; ++tt) {
    float pre = 0.f;
    if (t < 128)
      pre = decpre[(tt*NB + b)*1024 + (t >> 5)*256 + g*32 + (t & 31)];
    // ---- gates GEMM ----
    const float* hs = hc + ks*64;
    float a0 = 0.f, a1 = 0.f, a2 = 0.f, a3 = 0.f;
    #pragma unroll
    for (int j = 0; j < 16; j += 4) {
      float4 h0 = *(const float4*)(hs + j*4);
      float4 h1 = *(const float4*)(hs + j*4 + 4);
      float4 h2 = *(const float4*)(hs + j*4 + 8);
      float4 h3 = *(const float4*)(hs + j*4 + 12);
      a0 += wr[j].x*h0.x + wr[j].y*h0.y + wr[j].z*h0.z + wr[j].w*h0.w;
      a1 += wr[j+1].x*h1.x + wr[j+1].y*h1.y + wr[j+1].z*h1.z + wr[j+1].w*h1.w;
      a2 += wr[j+2].x*h2.x + wr[j+2].y*h2.y + wr[j+2].z*h2.z + wr[j+2].w*h2.w;
      a3 += wr[j+3].x*h3.x + wr[j+3].y*h3.y + wr[j+3].z*h3.z + wr[j+3].w*h3.w;
    }
    part[ks][r] = (a0 + a1) + (a2 + a3);
    LBAR();
    if (t < 128) {
      float gv = pre;
      #pragma unroll
      for (int j = 0; j < 8; ++j) gv += part[j][t];
      gates[t] = gv;
    }
    LBAR();
    if (t < 32) {
      float gi = gates[t], gf = gates[32+t], gg = gates[64+t], go = gates[96+t];
      float iv = sigmf(gi), fv = sigmf(gf), gv = tanhf_(gg), ov = sigmf(go);
      c_reg = fv*c_reg + iv*gv;
      float hv = ov*tanhf_(c_reg);
      int u = g*32 + t;
      gstore(hpub + b*HH + u, hv);
      dhall[(tt*NB + b)*HH + u] = hv;
    }
    flagbar(flags, b, g, 2*tt + 1);
    if (t < 256) hc[t] = gload(hpub + b*HH + t);
    LBAR();
    // ---- wh[a] = ahb + ahW @ h_new ----
    {
      int kq = t >> 6, a = t & 63;
      float p = 0.f;
      #pragma unroll
      for (int k = 0; k < 16; ++k) p += ahWt[(kq*16 + k)*68 + a] * hc[kq*16 + k];
      whp[kq][a] = p;
    }
    LBAR();
    if (t < 64) {
      float s0v = 0.f;
      #pragma unroll
      for (int kq = 0; kq < 16; ++kq) s0v += whp[kq][t];
      wh[t] = ahb[t] + s0v;
    }
    LBAR();
    // ---- scores for own 50-source slice ----
    if (t < 800) {
      int s = t >> 4, j = t & 15;
      const float* wrow = wsl + s*68 + j*4;
      float p = fwl[j*4]   * tanhf_(wrow[0] + wh[j*4])
              + fwl[j*4+1] * tanhf_(wrow[1] + wh[j*4+1])
              + fwl[j*4+2] * tanhf_(wrow[2] + wh[j*4+2])
              + fwl[j*4+3] * tanhf_(wrow[3] + wh[j*4+3]);
      scp[s][j] = p;
    }
    LBAR();
    if (t < 64) {
      float sc = -1e30f;
      if (t < 50) {
        sc = fb0;
        #pragma unroll
        for (int j = 0; j < 16; ++j) sc += scp[t][j];
        sc = fminf(sc, (s0 + t < len) ? 9999.0f : -9999.0f);
      }
      float m = sc;
      #pragma unroll
      for (int o = 32; o; o >>= 1) m = fmaxf(m, __shfl_xor(m, o));
      float p = (t < 50) ? __expf(sc - m) : 0.0f;
      scl[t] = p;
      float ssum = p;
      #pragma unroll
      for (int o = 32; o; o >>= 1) ssum += __shfl_xor(ssum, o);
      if (t == 0) { sh_m = m; sh_s = ssum; }
    }
    LBAR();
    if (t < 512) {
      int d = t & 255, half = t >> 8;
      float acc = 0.f;
      const float* eb = encl + (half*25)*256 + d;
      #pragma unroll 5
      for (int i = 0; i < 25; ++i) acc += scl[half*25 + i] * eb[i*256];
      cpart[half][d] = acc;
    }
    LBAR();
    if (t < 256) gstore(cpub + (b*8 + g)*272 + t, cpart[0][t] + cpart[1][t]);
    else if (t == 256) gstore(cpub + (b*8 + g)*272 + 256, sh_m);
    else if (t == 257) gstore(cpub + (b*8 + g)*272 + 257, sh_s);
    flagbar(flags, b, g, 2*tt + 2);
    if (t < 8)  mg[t] = gload(cpub + (b*8 + t)*272 + 256);
    else if (t < 16) sg[t-8] = gload(cpub + (b*8 + (t-8))*272 + 257);
    LBAR();
    if (t < 256) {
      float M = mg[0];
      #pragma unroll
      for (int j = 1; j < 8; ++j) M = fmaxf(M, mg[j]);
      float denom = 0.f;
      #pragma unroll
      for (int j = 0; j < 8; ++j) denom += sg[j] * __expf(mg[j] - M);
      float inv = 1.0f / denom;
      float ctx = 0.f;
      #pragma unroll
      for (int j = 0; j < 8; ++j)
        ctx += gload(cpub + (b*8 + j)*272 + t) * __expf(mg[j] - M);
      hc[256 + t] = ctx * inv;
    }
    LBAR();
  }
}

// ---------- vocab logits via MFMA + per-chunk logsumexp partials ----------
__global__ __launch_bounds__(256) void k_pred_mfma(
    const float* __restrict__ dhall,
    const short* __restrict__ predWb,
    const float* __restrict__ predb,
    float* __restrict__ pm, float* __restrict__ ps)
{
  const int m0 = blockIdx.x * 64;   // 24 row tiles
  const int ch = blockIdx.y;        // 120 col chunks of 256
  const int c0 = ch * 256;
  const int t = threadIdx.x;
  const int w = t >> 6, l = t & 63;
  __shared__ __align__(16) char smem[64*264*4];
  short* Abuf = (short*)smem;       // [64][264] bf16 (first half)
  float* L    = (float*)smem;       // [64][264] f32 logits (aliased, used after)
  __shared__ float red[256];
  __shared__ float rowmax[64];

  // stage A (fp32 -> bf16)
  {
    const int ar = t >> 2, ak0 = (t & 3) * 64;
    const float* src = dhall + (size_t)(m0 + ar)*256 + ak0;
    #pragma unroll
    for (int j = 0; j < 16; ++j) {
      float4 v = *(const float4*)(src + 4*j);
      short4 s4; s4.x = f2bf(v.x); s4.y = f2bf(v.y); s4.z = f2bf(v.z); s4.w = f2bf(v.w);
      *(short4*)(&Abuf[ar*264 + ak0 + 4*j]) = s4;
    }
  }
  LBAR();
  f32x4 acc[4][4];
  #pragma unroll
  for (int i = 0; i < 4; ++i)
    #pragma unroll
    for (int j = 0; j < 4; ++j) acc[i][j] = (f32x4){0.f,0.f,0.f,0.f};
  #pragma unroll
  for (int kst = 0; kst < 8; ++kst) {
    bf16x8 af[4];
    #pragma unroll
    for (int mr = 0; mr < 4; ++mr)
      af[mr] = *(const bf16x8*)(&Abuf[(mr*16 + (l & 15))*264 + kst*32 + (l >> 4)*8]);
    #pragma unroll
    for (int ct = 0; ct < 4; ++ct) {
      int col = c0 + w*64 + ct*16 + (l & 15);
      bf16x8 bfr = *(const bf16x8*)(predWb + (size_t)col*256 + kst*32 + (l >> 4)*8);
      #pragma unroll
      for (int mr = 0; mr < 4; ++mr)
        acc[mr][ct] = __builtin_amdgcn_mfma_f32_16x16x32_bf16(af[mr], bfr, acc[mr][ct], 0, 0, 0);
    }
  }
  LBAR();   // a-frag reads done; safe to overwrite smem with logits
  #pragma unroll
  for (int ct = 0; ct < 4; ++ct) {
    int col = c0 + w*64 + ct*16 + (l & 15);
    float bias = (col < VV) ? predb[col] : 0.0f;
    bool valid = (col < VV);
    #pragma unroll
    for (int mr = 0; mr < 4; ++mr) {
      #pragma unroll
      for (int r = 0; r < 4; ++r) {
        int rl = mr*16 + (l >> 4)*4 + r;
        L[rl*264 + w*64 + ct*16 + (l & 15)] = valid ? (acc[mr][ct][r] + bias) : -1e30f;
      }
    }
  }
  LBAR();
  // per-row max/sumexp over 256 cols (4 threads per row)
  {
    const int row = t & 63, qd = t >> 6;
    float m = -1e30f;
    const float* Lr = L + row*264 + qd*64;
    for (int i = 0; i < 64; ++i) m = fmaxf(m, Lr[i]);
    red[qd*64 + row] = m;
  }
  LBAR();
  if (t < 64) {
    float m = fmaxf(fmaxf(red[t], red[64+t]), fmaxf(red[128+t], red[192+t]));
    rowmax[t] = m;
  }
  LBAR();
  {
    const int row = t & 63, qd = t >> 6;
    float m = rowmax[row];
    float ssum = 0.f;
    const float* Lr = L + row*264 + qd*64;
    for (int i = 0; i < 64; ++i) ssum += __expf(Lr[i] - m);
    red[qd*64 + row] = ssum;
  }
  LBAR();
  if (t < 64) {
    float ssum = red[t] + red[64+t] + red[128+t] + red[192+t];
    pm[(m0 + t)*NCHUNK + ch] = rowmax[t];
    ps[(m0 + t)*NCHUNK + ch] = ssum;
  }
}

// ---------- loss partials: 6 WGs x 256 threads, one row per thread ----------
__global__ __launch_bounds__(256) void k_loss_part(
    const float* __restrict__ pm, const float* __restrict__ ps,
    const float* __restrict__ dhall,
    const float* __restrict__ predW, const float* __restrict__ predb,
    const int* __restrict__ abstr, float* __restrict__ lpart)
{
  const int tid = threadIdx.x;
  const int row = blockIdx.x*256 + tid;   // < 1536
  __shared__ float rs[256], rc[256];
  float lsum = 0.0f, lcnt = 0.0f;
  {
    int t = row >> 4, b = row & 15;
    int tok = abstr[b*TT + t];
    float m = -1e30f;
    for (int c = 0; c < NCHUNK; ++c) m = fmaxf(m, pm[row*NCHUNK + c]);
    float ss = 0.0f;
    for (int c = 0; c < NCHUNK; ++c) ss += ps[row*NCHUNK + c] * __expf(pm[row*NCHUNK + c] - m);
    float lse = m + __logf(ss);
    float tl = predb[tok];
    const float* hrow = dhall + row*256;
    const float* wrow = predW + tok*256;
    #pragma unroll 4
    for (int k = 0; k < 256; ++k) tl += hrow[k] * wrow[k];
    if (tok != 0) { lsum = lse - tl; lcnt = 1.0f; }
  }
  rs[tid] = lsum; rc[tid] = lcnt;
  __syncthreads();
  for (int st = 128; st; st >>= 1) {
    if (tid < st) { rs[tid] += rs[tid + st]; rc[tid] += rc[tid + st]; }
    __syncthreads();
  }
  if (tid == 0) { lpart[blockIdx.x*2] = rs[0]; lpart[blockIdx.x*2 + 1] = rc[0]; }
}

// ---------- final: deterministic sum of 6 partials ----------
__global__ void k_loss_final(const float* __restrict__ lpart, float* __restrict__ out) {
  if (threadIdx.x == 0) {
    float s = 0.f, c = 0.f;
    for (int i = 0; i < 6; ++i) { s += lpart[i*2]; c += lpart[i*2 + 1]; }
    out[0] = s / fmaxf(c, 1.0f);
  }
}

// ---------- launch ----------
extern "C" void kernel_launch(void* const* d_in, const int* in_sizes, int n_in,
                              void* d_out, int out_size, void* d_ws, size_t ws_size,
                              hipStream_t stream) {
  const float* emb   = (const float*)d_in[0];
  const int* article = (const int*)d_in[1];
  const int* alen    = (const int*)d_in[2];
  const int* abstr   = (const int*)d_in[3];
  const float* eWihF = (const float*)d_in[4];
  const float* eWhhF = (const float*)d_in[5];
  const float* ebF   = (const float*)d_in[6];
  const float* eWihB = (const float*)d_in[7];
  const float* eWhhB = (const float*)d_in[8];
  const float* ebB   = (const float*)d_in[9];
  const float* dWih  = (const float*)d_in[10];
  const float* dWhh  = (const float*)d_in[11];
  const float* db    = (const float*)d_in[12];
  const float* pW    = (const float*)d_in[13];
  const float* pb    = (const float*)d_in[14];
  const float* asW   = (const float*)d_in[15];
  const float* asb   = (const float*)d_in[16];
  const float* ahW   = (const float*)d_in[17];
  const float* ahb   = (const float*)d_in[18];
  const float* afW   = (const float*)d_in[19];
  const float* afb   = (const float*)d_in[20];
  float* out = (float*)d_out;

  float* w = (float*)d_ws;
  size_t o = 0;
  float* xcomb  = w + o; o += (size_t)SS*NB*1024;
  float* encout = w + o; o += (size_t)NB*SS*HH;
  float* encwsR = w + o; o += (size_t)NB*SS*AA;
  float* decpre = w + o; o += (size_t)TT*NB*1024;
  float* dhall  = w + o; o += (size_t)TT*NB*HH;
  float* hpub   = w + o; o += NB*HH;
  float* cpub   = w + o; o += NB*8*272;
  float* c0buf  = w + o; o += NB*HH;
  float* pm     = w + o; o += (size_t)TT*NB*NCHUNK;
  float* ps     = w + o; o += (size_t)TT*NB*NCHUNK;
  float* lpart  = w + o; o += 16;
  int* flags = (int*)(w + o); o += 16*8*16;
  short* predWb = (short*)(w + o); o += (size_t)VVP*256/2;
  short* wfB    = (short*)(w + o); o += 512*1024/2;
  short* wbB    = (short*)(w + o); o += 512*1024/2;
  short* dwB    = (short*)(w + o); o += 1024*1024/2;

  k_init<<<1, 256, 0, stream>>>(flags);
  k_casts<<<2048, 256, 0, stream>>>(pW, eWihF, eWihB, dWih, predWb, wfB, wbB, dwB);
  k_embproj_enc_mfma<<<dim3(100, 4), 256, 0, stream>>>(emb, article, wfB, wbB, ebF, ebB, xcomb);
  k_embproj_dec_mfma<<<dim3(24, 4), 256, 0, stream>>>(emb, abstr, dwB, db, decpre);
  k_encoder<<<32, 1024, 0, stream>>>(xcomb, eWhhF, eWhhB, encout, hpub, c0buf);
  k_encws<<<200, 256, 0, stream>>>(encout, asW, asb, encwsR);
  k_decoder<<<128, 1024, 0, stream>>>(decpre, dWhh, dWih, ahW, ahb, afW, afb,
                                      encwsR, encout, alen, c0buf, hpub, cpub, dhall, flags);
  k_pred_mfma<<<dim3(24, 120), 256, 0, stream>>>(dhall, predWb, pb, pm, ps);
  k_loss_part<<<6, 256, 0, stream>>>(pm, ps, dhall, pW, pb, abstr, lpart);
  k_loss_final<<<1, 64, 0, stream>>>(lpart, out);
}

// Round 7
// 1985.184 us; speedup vs baseline: 6.1790x; 1.0110x over previous
//
#include <hip/hip_runtime.h>
#include <cmath>

#define NB 16      // batch
#define SS 400     // source len
#define TT 96      // target len
#define HL 128     // LSTM per dir
#define HH 256     // decoder hidden (2*HL)
#define AA 64      // attn dim
#define VV 30611   // vocab
#define VVP 30720  // vocab padded to 256
#define START_TOK 101
#define NCHUNK 120 // vocab chunks of 256

typedef __attribute__((ext_vector_type(8))) short bf16x8;
typedef __attribute__((ext_vector_type(4))) float f32x4;

// keep a loaded float4 live in VGPRs (forbid rematerialization / load sinking)
#define PIN4(v) asm volatile("" : "+v"((v).x), "+v"((v).y), "+v"((v).z), "+v"((v).w))
// LDS-only barrier: no vmcnt drain (global stores stay in flight)
#define LBAR() asm volatile("s_waitcnt lgkmcnt(0)\n\ts_barrier" ::: "memory")

// ---------- helpers ----------
__device__ __forceinline__ float gload(const float* p) {
  return __hip_atomic_load(p, __ATOMIC_RELAXED, __HIP_MEMORY_SCOPE_AGENT);
}
__device__ __forceinline__ void gstore(float* p, float v) {
  __hip_atomic_store(p, v, __ATOMIC_RELAXED, __HIP_MEMORY_SCOPE_AGENT);
}
__device__ __forceinline__ float sigmf(float x) { return 1.0f / (1.0f + __expf(-x)); }
__device__ __forceinline__ float tanhf_(float x) {
  float xc = fminf(fmaxf(x, -15.0f), 15.0f);
  return 1.0f - 2.0f / (__expf(2.0f * xc) + 1.0f);
}
__device__ __forceinline__ short f2bf(float f) {
  unsigned u = __float_as_uint(f);
  unsigned r = (u + 0x7FFFu + ((u >> 16) & 1u)) >> 16;
  return (short)r;
}
// flag barrier: flags for the 8 WGs of a batch live in ONE 32B cacheline.
// open sync = __syncthreads (drains each wave's vmem), release store by t==0,
// acquire poll by lanes 0..7 (single coalesced request), close = LBAR.
__device__ __forceinline__ void flagbar(int* flags, int b, int g, int target) {
  __syncthreads();
  if (threadIdx.x == 0)
    __hip_atomic_store(&flags[b*8 + g], target, __ATOMIC_RELEASE, __HIP_MEMORY_SCOPE_AGENT);
  if (threadIdx.x < 8) {
    while (__hip_atomic_load(&flags[b*8 + threadIdx.x], __ATOMIC_ACQUIRE, __HIP_MEMORY_SCOPE_AGENT) < target)
      __builtin_amdgcn_s_sleep(1);
  }
  LBAR();
}

// ---------- init: zero flags ----------
__global__ __launch_bounds__(256) void k_init(int* flags) {
  if (threadIdx.x < 128) flags[threadIdx.x] = 0;
}

// ---------- cast weights to bf16 ----------
__global__ __launch_bounds__(256) void k_casts(
    const float* __restrict__ predW, const float* __restrict__ wf,
    const float* __restrict__ wb, const float* __restrict__ dwih,
    short* __restrict__ predWb, short* __restrict__ wfB,
    short* __restrict__ wbB, short* __restrict__ dwB)
{
  const int stride = gridDim.x * 256;
  const int t0 = blockIdx.x * 256 + threadIdx.x;
  for (int i = t0; i < VVP*256; i += stride)
    predWb[i] = (i < VV*256) ? f2bf(predW[i]) : (short)0;
  for (int i = t0; i < 512*1024; i += stride) wfB[i] = f2bf(wf[i]);
  for (int i = t0; i < 512*1024; i += stride) wbB[i] = f2bf(wb[i]);
  for (int i = t0; i < 1024*1024; i += stride) {
    int r = i >> 10, k = i & 1023;
    dwB[i] = f2bf(dwih[r*1280 + k]);
  }
}

// ---------- encoder input projection via MFMA ----------
__global__ __launch_bounds__(256) void k_embproj_enc_mfma(
    const float* __restrict__ emb, const int* __restrict__ article,
    const short* __restrict__ wfB, const short* __restrict__ wbB,
    const float* __restrict__ bf, const float* __restrict__ bb,
    float* __restrict__ xcomb)
{
  const int m0 = blockIdx.x * 64;
  const int n0 = blockIdx.y * 256;
  const int t = threadIdx.x;
  const int w = t >> 6, l = t & 63;
  __shared__ short Abuf[64*136];
  __shared__ int tok[64];
  if (t < 64) {
    int R = m0 + t, s = R >> 4, b = R & 15;
    tok[t] = article[b*SS + s];
  }
  const short* __restrict__ Wb = (n0 < 512) ? wfB : wbB;
  const int nb0 = (n0 < 512) ? n0 : (n0 - 512);
  f32x4 acc[4][4];
  #pragma unroll
  for (int i = 0; i < 4; ++i)
    #pragma unroll
    for (int j = 0; j < 4; ++j) acc[i][j] = (f32x4){0.f,0.f,0.f,0.f};
  __syncthreads();
  const int ar = t >> 2, ak0 = (t & 3) * 32;
  for (int kc = 0; kc < 8; ++kc) {
    const float* src = emb + (size_t)tok[ar]*1024 + kc*128 + ak0;
    #pragma unroll
    for (int j = 0; j < 8; ++j) {
      float4 v = *(const float4*)(src + 4*j);
      short4 s4; s4.x = f2bf(v.x); s4.y = f2bf(v.y); s4.z = f2bf(v.z); s4.w = f2bf(v.w);
      *(short4*)(&Abuf[ar*136 + ak0 + 4*j]) = s4;
    }
    LBAR();
    #pragma unroll
    for (int ks = 0; ks < 4; ++ks) {
      bf16x8 af[4];
      #pragma unroll
      for (int mr = 0; mr < 4; ++mr)
        af[mr] = *(const bf16x8*)(&Abuf[(mr*16 + (l & 15))*136 + ks*32 + (l >> 4)*8]);
      #pragma unroll
      for (int ct = 0; ct < 4; ++ct) {
        int n = nb0 + w*64 + ct*16 + (l & 15);
        bf16x8 bfr = *(const bf16x8*)(Wb + (size_t)n*1024 + kc*128 + ks*32 + (l >> 4)*8);
        #pragma unroll
        for (int mr = 0; mr < 4; ++mr)
          acc[mr][ct] = __builtin_amdgcn_mfma_f32_16x16x32_bf16(af[mr], bfr, acc[mr][ct], 0, 0, 0);
      }
    }
    LBAR();
  }
  #pragma unroll
  for (int ct = 0; ct < 4; ++ct) {
    int n = n0 + w*64 + ct*16 + (l & 15);
    float bias = (n < 512) ? bf[n] : bb[n - 512];
    #pragma unroll
    for (int mr = 0; mr < 4; ++mr) {
      #pragma unroll
      for (int r = 0; r < 4; ++r) {
        int R = m0 + mr*16 + (l >> 4)*4 + r;
        xcomb[(size_t)R*1024 + n] = acc[mr][ct][r] + bias;
      }
    }
  }
}

// ---------- decoder embedding projection via MFMA (dec_b folded) ----------
__global__ __launch_bounds__(256) void k_embproj_dec_mfma(
    const float* __restrict__ emb, const int* __restrict__ abstr,
    const short* __restrict__ dwB, const float* __restrict__ db,
    float* __restrict__ decpre)
{
  const int m0 = blockIdx.x * 64;
  const int n0 = blockIdx.y * 256;
  const int t = threadIdx.x;
  const int w = t >> 6, l = t & 63;
  __shared__ short Abuf[64*136];
  __shared__ int tok[64];
  if (t < 64) {
    int R = m0 + t, tt = R >> 4, b = R & 15;
    tok[t] = (tt == 0) ? START_TOK : abstr[b*TT + tt - 1];
  }
  f32x4 acc[4][4];
  #pragma unroll
  for (int i = 0; i < 4; ++i)
    #pragma unroll
    for (int j = 0; j < 4; ++j) acc[i][j] = (f32x4){0.f,0.f,0.f,0.f};
  __syncthreads();
  const int ar = t >> 2, ak0 = (t & 3) * 32;
  for (int kc = 0; kc < 8; ++kc) {
    const float* src = emb + (size_t)tok[ar]*1024 + kc*128 + ak0;
    #pragma unroll
    for (int j = 0; j < 8; ++j) {
      float4 v = *(const float4*)(src + 4*j);
      short4 s4; s4.x = f2bf(v.x); s4.y = f2bf(v.y); s4.z = f2bf(v.z); s4.w = f2bf(v.w);
      *(short4*)(&Abuf[ar*136 + ak0 + 4*j]) = s4;
    }
    LBAR();
    #pragma unroll
    for (int ks = 0; ks < 4; ++ks) {
      bf16x8 af[4];
      #pragma unroll
      for (int mr = 0; mr < 4; ++mr)
        af[mr] = *(const bf16x8*)(&Abuf[(mr*16 + (l & 15))*136 + ks*32 + (l >> 4)*8]);
      #pragma unroll
      for (int ct = 0; ct < 4; ++ct) {
        int n = n0 + w*64 + ct*16 + (l & 15);
        bf16x8 bfr = *(const bf16x8*)(dwB + (size_t)n*1024 + kc*128 + ks*32 + (l >> 4)*8);
        #pragma unroll
        for (int mr = 0; mr < 4; ++mr)
          acc[mr][ct] = __builtin_amdgcn_mfma_f32_16x16x32_bf16(af[mr], bfr, acc[mr][ct], 0, 0, 0);
      }
    }
    LBAR();
  }
  #pragma unroll
  for (int ct = 0; ct < 4; ++ct) {
    int n = n0 + w*64 + ct*16 + (l & 15);
    float bias = db[n];
    #pragma unroll
    for (int mr = 0; mr < 4; ++mr) {
      #pragma unroll
      for (int r = 0; r < 4; ++r) {
        int R = m0 + mr*16 + (l >> 4)*4 + r;
        decpre[(size_t)R*1024 + n] = acc[mr][ct][r] + bias;
      }
    }
  }
}

// ---------- encoder: 1 WG per (batch, dir), xcomb prefetched 1 step ahead ----------
__global__ __launch_bounds__(1024, 4) void k_encoder(
    const float* __restrict__ xcomb,
    const float* __restrict__ whhf, const float* __restrict__ whhb,
    float* __restrict__ encout,
    float* __restrict__ hpub,      // [16][256]: decoder h0
    float* __restrict__ c0buf)     // [16][256]
{
  const int b = blockIdx.x & 15, dir = blockIdx.x >> 4;
  const int t = threadIdx.x;       // 1024
  const int row = t & 511;
  const int ks = t >> 9;           // K-slice: 2 x 64
  const float* __restrict__ Whh = dir ? whhb : whhf;
  float4 wr[16];
  #pragma unroll
  for (int j = 0; j < 16; ++j) {
    wr[j] = *(const float4*)(Whh + row*128 + ks*64 + j*4);
    PIN4(wr[j]);
  }
  __shared__ float hl[128];
  __shared__ float part[2][512];
  float c_reg = 0.0f;
  if (t < 128) hl[t] = 0.0f;
  // prefetch x for s=0
  float xv0 = 0.f, xv1 = 0.f, xv2 = 0.f, xv3 = 0.f;
  if (t < 128) {
    const float* xr = xcomb + ((dir ? (SS-1) : 0)*NB + b)*1024 + dir*512 + t;
    xv0 = xr[0]; xv1 = xr[128]; xv2 = xr[256]; xv3 = xr[384];
  }
  __syncthreads();
  for (int s = 0; s < SS; ++s) {
    const int sf = dir ? (SS-1-s) : s;
    const float* hs = hl + ks*64;
    float a0 = 0.f, a1 = 0.f, a2 = 0.f, a3 = 0.f;
    #pragma unroll
    for (int j = 0; j < 16; j += 4) {
      float4 h0 = *(const float4*)(hs + j*4);
      float4 h1 = *(const float4*)(hs + j*4 + 4);
      float4 h2 = *(const float4*)(hs + j*4 + 8);
      float4 h3 = *(const float4*)(hs + j*4 + 12);
      a0 += wr[j].x*h0.x + wr[j].y*h0.y + wr[j].z*h0.z + wr[j].w*h0.w;
      a1 += wr[j+1].x*h1.x + wr[j+1].y*h1.y + wr[j+1].z*h1.z + wr[j+1].w*h1.w;
      a2 += wr[j+2].x*h2.x + wr[j+2].y*h2.y + wr[j+2].z*h2.z + wr[j+2].w*h2.w;
      a3 += wr[j+3].x*h3.x + wr[j+3].y*h3.y + wr[j+3].z*h3.z + wr[j+3].w*h3.w;
    }
    part[ks][row] = (a0 + a1) + (a2 + a3);
    // prefetch x for s+1
    float nx0 = 0.f, nx1 = 0.f, nx2 = 0.f, nx3 = 0.f;
    if (t < 128 && s + 1 < SS) {
      const int sfn = dir ? (SS-2-s) : (s+1);
      const float* xr = xcomb + (sfn*NB + b)*1024 + dir*512 + t;
      nx0 = xr[0]; nx1 = xr[128]; nx2 = xr[256]; nx3 = xr[384];
    }
    LBAR();
    if (t < 128) {
      float gi = part[0][t]       + part[1][t]       + xv0;
      float gf = part[0][128 + t] + part[1][128 + t] + xv1;
      float gg = part[0][256 + t] + part[1][256 + t] + xv2;
      float go = part[0][384 + t] + part[1][384 + t] + xv3;
      float iv = sigmf(gi), fv = sigmf(gf), gv = tanhf_(gg), ov = sigmf(go);
      c_reg = fv*c_reg + iv*gv;
      float hv = ov*tanhf_(c_reg);
      hl[t] = hv;
      encout[(b*SS + sf)*HH + dir*HL + t] = hv;
    }
    LBAR();
    xv0 = nx0; xv1 = nx1; xv2 = nx2; xv3 = nx3;
  }
  if (t < 128) {
    hpub[b*HH + dir*HL + t] = hl[t];
    c0buf[b*HH + dir*HL + t] = c_reg;
  }
}

// ---------- enc_ws = enc_out @ attn_s_W.T + b, row-major [b][s][a] ----------
__global__ __launch_bounds__(256) void k_encws(
    const float* __restrict__ encout,
    const float* __restrict__ asW, const float* __restrict__ asb,
    float* __restrict__ encwsR)
{
  const int rt = blockIdx.x;
  const int tid = threadIdx.x;
  __shared__ float Al[32*260];
  #pragma unroll
  for (int i = 0; i < 32; ++i) {
    int l = tid + i*256;
    int r = l >> 8, k = l & 255;
    Al[r*260 + k] = encout[(rt*32 + r)*256 + k];
  }
  __syncthreads();
  const int a = tid & 63, rg = tid >> 6;
  float acc[8];
  #pragma unroll
  for (int q = 0; q < 8; ++q) acc[q] = 0.0f;
  const float4* w4 = (const float4*)(asW + a*256);
  for (int k4 = 0; k4 < 64; ++k4) {
    float4 w = w4[k4];
    #pragma unroll
    for (int q = 0; q < 8; ++q) {
      const float4* a4 = (const float4*)(Al + (rg*8 + q)*260);
      float4 av = a4[k4];
      acc[q] += av.x*w.x + av.y*w.y + av.z*w.z + av.w*w.w;
    }
  }
  float bias = asb[a];
  #pragma unroll
  for (int q = 0; q < 8; ++q) {
    int row = rt*32 + rg*8 + q;
    encwsR[row*64 + a] = acc[q] + bias;
  }
}

// ---------- decoder: 8 WGs x 16 batches; 5 LBARs + 2 flagbars per step ----------
__global__ __launch_bounds__(1024, 4) void k_decoder(
    const float* __restrict__ decpre,
    const float* __restrict__ dwhh,   // [1024][256]
    const float* __restrict__ dwih,   // [1024][1280]
    const float* __restrict__ ahW, const float* __restrict__ ahb,
    const float* __restrict__ afW, const float* __restrict__ afb,
    const float* __restrict__ encwsR, // [b*400+s][64]
    const float* __restrict__ encout, // [b*400+s][256]
    const int* __restrict__ alen,
    const float* __restrict__ c0buf,  // [16][256]
    float* hpub,                      // [16][256], pre-filled with h0
    float* cpub,                      // [16][8][272]: ctxu[256] | m | s
    float* wpub,                      // [16][8][72]: whpart[64]
    float* __restrict__ dhall,        // [96*16][256]
    int* flags)
{
  const int wg = blockIdx.x;
  const int g = wg >> 4, b = wg & 15;   // unit-group / s-slice, batch
  const int t = threadIdx.x;            // 1024
  const int r = t & 127, ks = t >> 7;   // GEMM mapping: row (128), K-slice (8 x 64)
  const int lane = t & 63;
  const int u = t & 31;                 // cell unit (t<256, 8x replicated)
  const int s0 = g*50;

  // weight slice in registers (row grow, K = ks*64..+64)
  const int grow = (r >> 5)*256 + g*32 + (r & 31);
  float4 wr[16];
  #pragma unroll
  for (int j = 0; j < 16; ++j) {
    int k = ks*64 + j*4;
    wr[j] = (k < 256) ? *(const float4*)(dwhh + grow*256 + k)
                      : *(const float4*)(dwih + grow*1280 + 1024 + (k - 256));
    PIN4(wr[j]);
  }

  __shared__ float encl[50*256];   // 51200 B
  __shared__ float wsl[50*68];     // 13600 B
  __shared__ float ahWt[256*68];   // 69632 B
  __shared__ float hc[512];        // [h(256) | ctx(256)]
  __shared__ float part[8][132];
  __shared__ float wh[64];
  __shared__ float fwl[64];
  __shared__ float scl[64];
  __shared__ float sh_m, sh_s;

  // one-time stage-in
  for (int i = t; i < 50*256; i += 1024) {
    int si = i >> 8, d = i & 255;
    encl[i] = encout[(b*SS + s0 + si)*HH + d];
  }
  for (int i = t; i < 50*64; i += 1024) {
    int si = i >> 6, a = i & 63;
    wsl[si*68 + a] = encwsR[(b*SS + s0 + si)*64 + a];
  }
  for (int i = t; i < 64*256; i += 1024) {
    int a = i >> 8, k = i & 255;
    ahWt[k*68 + a] = ahW[i];
  }
  if (t < 64) fwl[t] = afW[t];
  const float fb0 = afb[0];
  int len = alen[b]; len = min(max(len, 1), SS);
  float c_reg = 0.f;
  float pre0 = 0.f, pre1 = 0.f, pre2 = 0.f, pre3 = 0.f;
  if (t < 256) {
    c_reg = c0buf[b*HH + g*32 + u];
    hc[t] = gload(hpub + b*HH + t);
    hc[256 + t] = 0.0f;
    const float* pr = decpre + (size_t)(0*NB + b)*1024 + g*32 + u;
    pre0 = pr[0]; pre1 = pr[256]; pre2 = pr[512]; pre3 = pr[768];
  }
  __syncthreads();

  for (int tt = 0; tt < TT; ++tt) {
    // ---- phase G: gates GEMM (all 1024 threads) ----
    {
      const float* hs = hc + ks*64;
      float a0 = 0.f, a1 = 0.f, a2 = 0.f, a3 = 0.f;
      #pragma unroll
      for (int j = 0; j < 16; j += 4) {
        float4 h0 = *(const float4*)(hs + j*4);
        float4 h1 = *(const float4*)(hs + j*4 + 4);
        float4 h2 = *(const float4*)(hs + j*4 + 8);
        float4 h3 = *(const float4*)(hs + j*4 + 12);
        a0 += wr[j].x*h0.x + wr[j].y*h0.y + wr[j].z*h0.z + wr[j].w*h0.w;
        a1 += wr[j+1].x*h1.x + wr[j+1].y*h1.y + wr[j+1].z*h1.z + wr[j+1].w*h1.w;
        a2 += wr[j+2].x*h2.x + wr[j+2].y*h2.y + wr[j+2].z*h2.z + wr[j+2].w*h2.w;
        a3 += wr[j+3].x*h3.x + wr[j+3].y*h3.y + wr[j+3].z*h3.z + wr[j+3].w*h3.w;
      }
      part[ks][r] = (a0 + a1) + (a2 + a3);
    }
    LBAR();
    // ---- phase C: reduce + cell (t<256, 8x replicated) + whpart via shuffles ----
    if (t < 256) {
      float g0 = pre0, g1 = pre1, g2 = pre2, g3 = pre3;
      #pragma unroll
      for (int j = 0; j < 8; ++j) {
        g0 += part[j][u];
        g1 += part[j][32 + u];
        g2 += part[j][64 + u];
        g3 += part[j][96 + u];
      }
      float iv = sigmf(g0), fv = sigmf(g1), gv = tanhf_(g2), ov = sigmf(g3);
      c_reg = fv*c_reg + iv*gv;
      float hv = ov*tanhf_(c_reg);
      if (t < 32) {
        gstore(hpub + b*HH + g*32 + t, hv);
        dhall[(tt*NB + b)*HH + g*32 + t] = hv;
      }
      // whpart_g[a] = sum_u ahW[a][g*32+u] * h_u  (in-wave shuffles, no LDS deps)
      int wv = t >> 6;                 // 0..3
      int a = wv*16 + (lane >> 2);
      int j4 = lane & 3;
      float wacc = 0.f;
      #pragma unroll
      for (int i = 0; i < 8; ++i) {
        int u2 = j4*8 + i;
        float hx = __shfl(hv, u2, 64);
        wacc += ahWt[(g*32 + u2)*68 + a] * hx;
      }
      wacc += __shfl_xor(wacc, 1);
      wacc += __shfl_xor(wacc, 2);
      if (j4 == 0) gstore(wpub + (b*8 + g)*72 + a, wacc);
    }
    flagbar(flags, b, g, 2*tt + 1);
    // ---- phase SW: stage h (t<256) + prefetch decpre, wh combine (wave 4) ----
    if (t < 256) {
      hc[t] = gload(hpub + b*HH + t);
      if (tt + 1 < TT) {
        const float* pr = decpre + (size_t)((tt+1)*NB + b)*1024 + g*32 + u;
        pre0 = pr[0]; pre1 = pr[256]; pre2 = pr[512]; pre3 = pr[768];
      }
    } else if (t < 320) {
      int a = t - 256;
      float s = ahb[a];
      #pragma unroll
      for (int j = 0; j < 8; ++j) s += gload(wpub + (b*8 + j)*72 + a);
      wh[a] = s;
    }
    LBAR();
    // ---- phase F: scores (t<800, 16-lane shuffle reduce) ----
    if (t < 800) {
      int s = t >> 4, j = t & 15;
      const float* wrow = wsl + s*68 + j*4;
      float p = fwl[j*4]   * tanhf_(wrow[0] + wh[j*4])
              + fwl[j*4+1] * tanhf_(wrow[1] + wh[j*4+1])
              + fwl[j*4+2] * tanhf_(wrow[2] + wh[j*4+2])
              + fwl[j*4+3] * tanhf_(wrow[3] + wh[j*4+3]);
      p += __shfl_xor(p, 1);
      p += __shfl_xor(p, 2);
      p += __shfl_xor(p, 4);
      p += __shfl_xor(p, 8);
      if (j == 0) scl[s] = p;
    }
    LBAR();
    // ---- phase M: slice softmax (wave 0) ----
    if (t < 64) {
      float sc = -1e30f;
      if (t < 50) {
        sc = fb0 + scl[t];
        sc = fminf(sc, (s0 + t < len) ? 9999.0f : -9999.0f);
      }
      float m = sc;
      #pragma unroll
      for (int o = 32; o; o >>= 1) m = fmaxf(m, __shfl_xor(m, o));
      float p = (t < 50) ? __expf(sc - m) : 0.0f;
      scl[t] = p;
      float ssum = p;
      #pragma unroll
      for (int o = 32; o; o >>= 1) ssum += __shfl_xor(ssum, o);
      if (t == 0) { sh_m = m; sh_s = ssum; }
    }
    LBAR();
    // ---- phase X: unnormalized ctx partial (t<256, 50 MACs) + publish ----
    if (t < 256) {
      float acc = 0.0f;
      const float* eb = encl + t;
      #pragma unroll 10
      for (int i = 0; i < 50; ++i) acc += scl[i] * eb[i*256];
      gstore(cpub + (b*8 + g)*272 + t, acc);
      if (t == 0) gstore(cpub + (b*8 + g)*272 + 256, sh_m);
      if (t == 1) gstore(cpub + (b*8 + g)*272 + 257, sh_s);
    }
    flagbar(flags, b, g, 2*tt + 2);
    // ---- phase K: combine 8 online-softmax partials (self-service, t<256) ----
    if (t < 256) {
      float mj[8], sj[8];
      #pragma unroll
      for (int j = 0; j < 8; ++j) {
        mj[j] = gload(cpub + (b*8 + j)*272 + 256);
        sj[j] = gload(cpub + (b*8 + j)*272 + 257);
      }
      float M = mj[0];
      #pragma unroll
      for (int j = 1; j < 8; ++j) M = fmaxf(M, mj[j]);
      float denom = 0.f, ctx = 0.f;
      #pragma unroll
      for (int j = 0; j < 8; ++j) {
        float e = __expf(mj[j] - M);
        denom += sj[j] * e;
        ctx += gload(cpub + (b*8 + j)*272 + t) * e;
      }
      hc[256 + t] = ctx / denom;
    }
    LBAR();
  }
}

// ---------- vocab logits via MFMA + per-chunk logsumexp partials ----------
__global__ __launch_bounds__(256) void k_pred_mfma(
    const float* __restrict__ dhall,
    const short* __restrict__ predWb,
    const float* __restrict__ predb,
    float* __restrict__ pm, float* __restrict__ ps)
{
  const int m0 = blockIdx.x * 64;
  const int ch = blockIdx.y;
  const int c0 = ch * 256;
  const int t = threadIdx.x;
  const int w = t >> 6, l = t & 63;
  __shared__ __align__(16) char smem[64*264*4];
  short* Abuf = (short*)smem;
  float* L    = (float*)smem;
  __shared__ float red[256];
  __shared__ float rowmax[64];

  {
    const int ar = t >> 2, ak0 = (t & 3) * 64;
    const float* src = dhall + (size_t)(m0 + ar)*256 + ak0;
    #pragma unroll
    for (int j = 0; j < 16; ++j) {
      float4 v = *(const float4*)(src + 4*j);
      short4 s4; s4.x = f2bf(v.x); s4.y = f2bf(v.y); s4.z = f2bf(v.z); s4.w = f2bf(v.w);
      *(short4*)(&Abuf[ar*264 + ak0 + 4*j]) = s4;
    }
  }
  LBAR();
  f32x4 acc[4][4];
  #pragma unroll
  for (int i = 0; i < 4; ++i)
    #pragma unroll
    for (int j = 0; j < 4; ++j) acc[i][j] = (f32x4){0.f,0.f,0.f,0.f};
  #pragma unroll
  for (int kst = 0; kst < 8; ++kst) {
    bf16x8 af[4];
    #pragma unroll
    for (int mr = 0; mr < 4; ++mr)
      af[mr] = *(const bf16x8*)(&Abuf[(mr*16 + (l & 15))*264 + kst*32 + (l >> 4)*8]);
    #pragma unroll
    for (int ct = 0; ct < 4; ++ct) {
      int col = c0 + w*64 + ct*16 + (l & 15);
      bf16x8 bfr = *(const bf16x8*)(predWb + (size_t)col*256 + kst*32 + (l >> 4)*8);
      #pragma unroll
      for (int mr = 0; mr < 4; ++mr)
        acc[mr][ct] = __builtin_amdgcn_mfma_f32_16x16x32_bf16(af[mr], bfr, acc[mr][ct], 0, 0, 0);
    }
  }
  LBAR();
  #pragma unroll
  for (int ct = 0; ct < 4; ++ct) {
    int col = c0 + w*64 + ct*16 + (l & 15);
    float bias = (col < VV) ? predb[col] : 0.0f;
    bool valid = (col < VV);
    #pragma unroll
    for (int mr = 0; mr < 4; ++mr) {
      #pragma unroll
      for (int r = 0; r < 4; ++r) {
        int rl = mr*16 + (l >> 4)*4 + r;
        L[rl*264 + w*64 + ct*16 + (l & 15)] = valid ? (acc[mr][ct][r] + bias) : -1e30f;
      }
    }
  }
  LBAR();
  {
    const int row = t & 63, qd = t >> 6;
    float m = -1e30f;
    const float* Lr = L + row*264 + qd*64;
    for (int i = 0; i < 64; ++i) m = fmaxf(m, Lr[i]);
    red[qd*64 + row] = m;
  }
  LBAR();
  if (t < 64) {
    float m = fmaxf(fmaxf(red[t], red[64+t]), fmaxf(red[128+t], red[192+t]));
    rowmax[t] = m;
  }
  LBAR();
  {
    const int row = t & 63, qd = t >> 6;
    float m = rowmax[row];
    float ssum = 0.f;
    const float* Lr = L + row*264 + qd*64;
    for (int i = 0; i < 64; ++i) ssum += __expf(Lr[i] - m);
    red[qd*64 + row] = ssum;
  }
  LBAR();
  if (t < 64) {
    float ssum = red[t] + red[64+t] + red[128+t] + red[192+t];
    pm[(m0 + t)*NCHUNK + ch] = rowmax[t];
    ps[(m0 + t)*NCHUNK + ch] = ssum;
  }
}

// ---------- loss partials: 6 WGs x 256 threads, one row per thread ----------
__global__ __launch_bounds__(256) void k_loss_part(
    const float* __restrict__ pm, const float* __restrict__ ps,
    const float* __restrict__ dhall,
    const float* __restrict__ predW, const float* __restrict__ predb,
    const int* __restrict__ abstr, float* __restrict__ lpart)
{
  const int tid = threadIdx.x;
  const int row = blockIdx.x*256 + tid;
  __shared__ float rs[256], rc[256];
  float lsum = 0.0f, lcnt = 0.0f;
  {
    int t = row >> 4, b = row & 15;
    int tok = abstr[b*TT + t];
    float m = -1e30f;
    for (int c = 0; c < NCHUNK; ++c) m = fmaxf(m, pm[row*NCHUNK + c]);
    float ss = 0.0f;
    for (int c = 0; c < NCHUNK; ++c) ss += ps[row*NCHUNK + c] * __expf(pm[row*NCHUNK + c] - m);
    float lse = m + __logf(ss);
    float tl = predb[tok];
    const float* hrow = dhall + row*256;
    const float* wrow = predW + tok*256;
    #pragma unroll 4
    for (int k = 0; k < 256; ++k) tl += hrow[k] * wrow[k];
    if (tok != 0) { lsum = lse - tl; lcnt = 1.0f; }
  }
  rs[tid] = lsum; rc[tid] = lcnt;
  __syncthreads();
  for (int st = 128; st; st >>= 1) {
    if (tid < st) { rs[tid] += rs[tid + st]; rc[tid] += rc[tid + st]; }
    __syncthreads();
  }
  if (tid == 0) { lpart[blockIdx.x*2] = rs[0]; lpart[blockIdx.x*2 + 1] = rc[0]; }
}

// ---------- final: deterministic sum of 6 partials ----------
__global__ void k_loss_final(const float* __restrict__ lpart, float* __restrict__ out) {
  if (threadIdx.x == 0) {
    float s = 0.f, c = 0.f;
    for (int i = 0; i < 6; ++i) { s += lpart[i*2]; c += lpart[i*2 + 1]; }
    out[0] = s / fmaxf(c, 1.0f);
  }
}

// ---------- launch ----------
extern "C" void kernel_launch(void* const* d_in, const int* in_sizes, int n_in,
                              void* d_out, int out_size, void* d_ws, size_t ws_size,
                              hipStream_t stream) {
  const float* emb   = (const float*)d_in[0];
  const int* article = (const int*)d_in[1];
  const int* alen    = (const int*)d_in[2];
  const int* abstr   = (const int*)d_in[3];
  const float* eWihF = (const float*)d_in[4];
  const float* eWhhF = (const float*)d_in[5];
  const float* ebF   = (const float*)d_in[6];
  const float* eWihB = (const float*)d_in[7];
  const float* eWhhB = (const float*)d_in[8];
  const float* ebB   = (const float*)d_in[9];
  const float* dWih  = (const float*)d_in[10];
  const float* dWhh  = (const float*)d_in[11];
  const float* db    = (const float*)d_in[12];
  const float* pW    = (const float*)d_in[13];
  const float* pb    = (const float*)d_in[14];
  const float* asW   = (const float*)d_in[15];
  const float* asb   = (const float*)d_in[16];
  const float* ahW   = (const float*)d_in[17];
  const float* ahb   = (const float*)d_in[18];
  const float* afW   = (const float*)d_in[19];
  const float* afb   = (const float*)d_in[20];
  float* out = (float*)d_out;

  float* w = (float*)d_ws;
  size_t o = 0;
  float* xcomb  = w + o; o += (size_t)SS*NB*1024;
  float* encout = w + o; o += (size_t)NB*SS*HH;
  float* encwsR = w + o; o += (size_t)NB*SS*AA;
  float* decpre = w + o; o += (size_t)TT*NB*1024;
  float* dhall  = w + o; o += (size_t)TT*NB*HH;
  float* hpub   = w + o; o += NB*HH;
  float* cpub   = w + o; o += NB*8*272;
  float* wpub   = w + o; o += NB*8*72;
  float* c0buf  = w + o; o += NB*HH;
  float* pm     = w + o; o += (size_t)TT*NB*NCHUNK;
  float* ps     = w + o; o += (size_t)TT*NB*NCHUNK;
  float* lpart  = w + o; o += 16;
  int* flags = (int*)(w + o); o += 128;
  short* predWb = (short*)(w + o); o += (size_t)VVP*256/2;
  short* wfB    = (short*)(w + o); o += 512*1024/2;
  short* wbB    = (short*)(w + o); o += 512*1024/2;
  short* dwB    = (short*)(w + o); o += 1024*1024/2;

  k_init<<<1, 256, 0, stream>>>(flags);
  k_casts<<<2048, 256, 0, stream>>>(pW, eWihF, eWihB, dWih, predWb, wfB, wbB, dwB);
  k_embproj_enc_mfma<<<dim3(100, 4), 256, 0, stream>>>(emb, article, wfB, wbB, ebF, ebB, xcomb);
  k_embproj_dec_mfma<<<dim3(24, 4), 256, 0, stream>>>(emb, abstr, dwB, db, decpre);
  k_encoder<<<32, 1024, 0, stream>>>(xcomb, eWhhF, eWhhB, encout, hpub, c0buf);
  k_encws<<<200, 256, 0, stream>>>(encout, asW, asb, encwsR);
  k_decoder<<<128, 1024, 0, stream>>>(decpre, dWhh, dWih, ahW, ahb, afW, afb,
                                      encwsR, encout, alen, c0buf, hpub, cpub, wpub, dhall, flags);
  k_pred_mfma<<<dim3(24, 120), 256, 0, stream>>>(dhall, predWb, pb, pm, ps);
  k_loss_part<<<6, 256, 0, stream>>>(pm, ps, dhall, pW, pb, abstr, lpart);
  k_loss_final<<<1, 64, 0, stream>>>(lpart, out);
}

// Round 8
// 1715.233 us; speedup vs baseline: 7.1515x; 1.1574x over previous
//
#include <hip/hip_runtime.h>
#include <cmath>

#define NB 16      // batch
#define SS 400     // source len
#define TT 96      // target len
#define HL 128     // LSTM per dir
#define HH 256     // decoder hidden (2*HL)
#define AA 64      // attn dim
#define VV 30611   // vocab
#define VVP 30720  // vocab padded to 256
#define START_TOK 101
#define NCHUNK 120 // vocab chunks of 256

typedef __attribute__((ext_vector_type(8))) short bf16x8;
typedef __attribute__((ext_vector_type(4))) float f32x4;

// keep a loaded float4 live in VGPRs (forbid rematerialization / load sinking)
#define PIN4(v) asm volatile("" : "+v"((v).x), "+v"((v).y), "+v"((v).z), "+v"((v).w))
// LDS-only barrier: no vmcnt drain (global stores stay in flight)
#define LBAR() asm volatile("s_waitcnt lgkmcnt(0)\n\ts_barrier" ::: "memory")

// ---------- helpers ----------
__device__ __forceinline__ float gload(const float* p) {
  return __hip_atomic_load(p, __ATOMIC_RELAXED, __HIP_MEMORY_SCOPE_AGENT);
}
__device__ __forceinline__ void gstore(float* p, float v) {
  __hip_atomic_store(p, v, __ATOMIC_RELAXED, __HIP_MEMORY_SCOPE_AGENT);
}
__device__ __forceinline__ float sigmf(float x) { return 1.0f / (1.0f + __expf(-x)); }
__device__ __forceinline__ float tanhf_(float x) {
  float xc = fminf(fmaxf(x, -15.0f), 15.0f);
  return 1.0f - 2.0f / (__expf(2.0f * xc) + 1.0f);
}
__device__ __forceinline__ short f2bf(float f) {
  unsigned u = __float_as_uint(f);
  unsigned r = (u + 0x7FFFu + ((u >> 16) & 1u)) >> 16;
  return (short)r;
}
// flag barrier, RELAXED-only protocol. All cross-WG data moves via relaxed
// agent-scope atomics (coherent at LLC, bypass L2), so no acquire/release
// cache maintenance (buffer_invl2 / wbl2) is needed — ordering comes from:
//   __syncthreads(): each wave drains its own vmcnt -> all data stores at LLC
//   relaxed flag store (reaches LLC after data already acked)
//   relaxed poll (reads LLC directly)
//   LBAR: broadcast "ready" to all waves of this WG
__device__ __forceinline__ void flagbar(int* flags, int b, int g, int target) {
  __syncthreads();
  if (threadIdx.x == 0)
    __hip_atomic_store(&flags[b*8 + g], target, __ATOMIC_RELAXED, __HIP_MEMORY_SCOPE_AGENT);
  if (threadIdx.x < 8) {
    while (__hip_atomic_load(&flags[b*8 + threadIdx.x], __ATOMIC_RELAXED, __HIP_MEMORY_SCOPE_AGENT) < target)
      __builtin_amdgcn_s_sleep(1);
  }
  LBAR();
}

// ---------- init: zero flags ----------
__global__ __launch_bounds__(256) void k_init(int* flags) {
  if (threadIdx.x < 128) flags[threadIdx.x] = 0;
}

// ---------- cast weights to bf16 ----------
__global__ __launch_bounds__(256) void k_casts(
    const float* __restrict__ predW, const float* __restrict__ wf,
    const float* __restrict__ wb, const float* __restrict__ dwih,
    short* __restrict__ predWb, short* __restrict__ wfB,
    short* __restrict__ wbB, short* __restrict__ dwB)
{
  const int stride = gridDim.x * 256;
  const int t0 = blockIdx.x * 256 + threadIdx.x;
  for (int i = t0; i < VVP*256; i += stride)
    predWb[i] = (i < VV*256) ? f2bf(predW[i]) : (short)0;
  for (int i = t0; i < 512*1024; i += stride) wfB[i] = f2bf(wf[i]);
  for (int i = t0; i < 512*1024; i += stride) wbB[i] = f2bf(wb[i]);
  for (int i = t0; i < 1024*1024; i += stride) {
    int r = i >> 10, k = i & 1023;
    dwB[i] = f2bf(dwih[r*1280 + k]);
  }
}

// ---------- encoder input projection via MFMA ----------
__global__ __launch_bounds__(256) void k_embproj_enc_mfma(
    const float* __restrict__ emb, const int* __restrict__ article,
    const short* __restrict__ wfB, const short* __restrict__ wbB,
    const float* __restrict__ bf, const float* __restrict__ bb,
    float* __restrict__ xcomb)
{
  const int m0 = blockIdx.x * 64;
  const int n0 = blockIdx.y * 256;
  const int t = threadIdx.x;
  const int w = t >> 6, l = t & 63;
  __shared__ short Abuf[64*136];
  __shared__ int tok[64];
  if (t < 64) {
    int R = m0 + t, s = R >> 4, b = R & 15;
    tok[t] = article[b*SS + s];
  }
  const short* __restrict__ Wb = (n0 < 512) ? wfB : wbB;
  const int nb0 = (n0 < 512) ? n0 : (n0 - 512);
  f32x4 acc[4][4];
  #pragma unroll
  for (int i = 0; i < 4; ++i)
    #pragma unroll
    for (int j = 0; j < 4; ++j) acc[i][j] = (f32x4){0.f,0.f,0.f,0.f};
  __syncthreads();
  const int ar = t >> 2, ak0 = (t & 3) * 32;
  for (int kc = 0; kc < 8; ++kc) {
    const float* src = emb + (size_t)tok[ar]*1024 + kc*128 + ak0;
    #pragma unroll
    for (int j = 0; j < 8; ++j) {
      float4 v = *(const float4*)(src + 4*j);
      short4 s4; s4.x = f2bf(v.x); s4.y = f2bf(v.y); s4.z = f2bf(v.z); s4.w = f2bf(v.w);
      *(short4*)(&Abuf[ar*136 + ak0 + 4*j]) = s4;
    }
    LBAR();
    #pragma unroll
    for (int ks = 0; ks < 4; ++ks) {
      bf16x8 af[4];
      #pragma unroll
      for (int mr = 0; mr < 4; ++mr)
        af[mr] = *(const bf16x8*)(&Abuf[(mr*16 + (l & 15))*136 + ks*32 + (l >> 4)*8]);
      #pragma unroll
      for (int ct = 0; ct < 4; ++ct) {
        int n = nb0 + w*64 + ct*16 + (l & 15);
        bf16x8 bfr = *(const bf16x8*)(Wb + (size_t)n*1024 + kc*128 + ks*32 + (l >> 4)*8);
        #pragma unroll
        for (int mr = 0; mr < 4; ++mr)
          acc[mr][ct] = __builtin_amdgcn_mfma_f32_16x16x32_bf16(af[mr], bfr, acc[mr][ct], 0, 0, 0);
      }
    }
    LBAR();
  }
  #pragma unroll
  for (int ct = 0; ct < 4; ++ct) {
    int n = n0 + w*64 + ct*16 + (l & 15);
    float bias = (n < 512) ? bf[n] : bb[n - 512];
    #pragma unroll
    for (int mr = 0; mr < 4; ++mr) {
      #pragma unroll
      for (int r = 0; r < 4; ++r) {
        int R = m0 + mr*16 + (l >> 4)*4 + r;
        xcomb[(size_t)R*1024 + n] = acc[mr][ct][r] + bias;
      }
    }
  }
}

// ---------- decoder embedding projection via MFMA (dec_b folded) ----------
__global__ __launch_bounds__(256) void k_embproj_dec_mfma(
    const float* __restrict__ emb, const int* __restrict__ abstr,
    const short* __restrict__ dwB, const float* __restrict__ db,
    float* __restrict__ decpre)
{
  const int m0 = blockIdx.x * 64;
  const int n0 = blockIdx.y * 256;
  const int t = threadIdx.x;
  const int w = t >> 6, l = t & 63;
  __shared__ short Abuf[64*136];
  __shared__ int tok[64];
  if (t < 64) {
    int R = m0 + t, tt = R >> 4, b = R & 15;
    tok[t] = (tt == 0) ? START_TOK : abstr[b*TT + tt - 1];
  }
  f32x4 acc[4][4];
  #pragma unroll
  for (int i = 0; i < 4; ++i)
    #pragma unroll
    for (int j = 0; j < 4; ++j) acc[i][j] = (f32x4){0.f,0.f,0.f,0.f};
  __syncthreads();
  const int ar = t >> 2, ak0 = (t & 3) * 32;
  for (int kc = 0; kc < 8; ++kc) {
    const float* src = emb + (size_t)tok[ar]*1024 + kc*128 + ak0;
    #pragma unroll
    for (int j = 0; j < 8; ++j) {
      float4 v = *(const float4*)(src + 4*j);
      short4 s4; s4.x = f2bf(v.x); s4.y = f2bf(v.y); s4.z = f2bf(v.z); s4.w = f2bf(v.w);
      *(short4*)(&Abuf[ar*136 + ak0 + 4*j]) = s4;
    }
    LBAR();
    #pragma unroll
    for (int ks = 0; ks < 4; ++ks) {
      bf16x8 af[4];
      #pragma unroll
      for (int mr = 0; mr < 4; ++mr)
        af[mr] = *(const bf16x8*)(&Abuf[(mr*16 + (l & 15))*136 + ks*32 + (l >> 4)*8]);
      #pragma unroll
      for (int ct = 0; ct < 4; ++ct) {
        int n = n0 + w*64 + ct*16 + (l & 15);
        bf16x8 bfr = *(const bf16x8*)(dwB + (size_t)n*1024 + kc*128 + ks*32 + (l >> 4)*8);
        #pragma unroll
        for (int mr = 0; mr < 4; ++mr)
          acc[mr][ct] = __builtin_amdgcn_mfma_f32_16x16x32_bf16(af[mr], bfr, acc[mr][ct], 0, 0, 0);
      }
    }
    LBAR();
  }
  #pragma unroll
  for (int ct = 0; ct < 4; ++ct) {
    int n = n0 + w*64 + ct*16 + (l & 15);
    float bias = db[n];
    #pragma unroll
    for (int mr = 0; mr < 4; ++mr) {
      #pragma unroll
      for (int r = 0; r < 4; ++r) {
        int R = m0 + mr*16 + (l >> 4)*4 + r;
        decpre[(size_t)R*1024 + n] = acc[mr][ct][r] + bias;
      }
    }
  }
}

// ---------- encoder: 1 WG per (batch, dir), xcomb prefetched 1 step ahead ----------
__global__ __launch_bounds__(1024, 4) void k_encoder(
    const float* __restrict__ xcomb,
    const float* __restrict__ whhf, const float* __restrict__ whhb,
    float* __restrict__ encout,
    float* __restrict__ hpub,      // [16][256]: decoder h0
    float* __restrict__ c0buf)     // [16][256]
{
  const int b = blockIdx.x & 15, dir = blockIdx.x >> 4;
  const int t = threadIdx.x;       // 1024
  const int row = t & 511;
  const int ks = t >> 9;           // K-slice: 2 x 64
  const float* __restrict__ Whh = dir ? whhb : whhf;
  float4 wr[16];
  #pragma unroll
  for (int j = 0; j < 16; ++j) {
    wr[j] = *(const float4*)(Whh + row*128 + ks*64 + j*4);
    PIN4(wr[j]);
  }
  __shared__ float hl[128];
  __shared__ float part[2][512];
  float c_reg = 0.0f;
  if (t < 128) hl[t] = 0.0f;
  // prefetch x for s=0
  float xv0 = 0.f, xv1 = 0.f, xv2 = 0.f, xv3 = 0.f;
  if (t < 128) {
    const float* xr = xcomb + ((dir ? (SS-1) : 0)*NB + b)*1024 + dir*512 + t;
    xv0 = xr[0]; xv1 = xr[128]; xv2 = xr[256]; xv3 = xr[384];
  }
  __syncthreads();
  for (int s = 0; s < SS; ++s) {
    const int sf = dir ? (SS-1-s) : s;
    const float* hs = hl + ks*64;
    float a0 = 0.f, a1 = 0.f, a2 = 0.f, a3 = 0.f;
    #pragma unroll
    for (int j = 0; j < 16; j += 4) {
      float4 h0 = *(const float4*)(hs + j*4);
      float4 h1 = *(const float4*)(hs + j*4 + 4);
      float4 h2 = *(const float4*)(hs + j*4 + 8);
      float4 h3 = *(const float4*)(hs + j*4 + 12);
      a0 += wr[j].x*h0.x + wr[j].y*h0.y + wr[j].z*h0.z + wr[j].w*h0.w;
      a1 += wr[j+1].x*h1.x + wr[j+1].y*h1.y + wr[j+1].z*h1.z + wr[j+1].w*h1.w;
      a2 += wr[j+2].x*h2.x + wr[j+2].y*h2.y + wr[j+2].z*h2.z + wr[j+2].w*h2.w;
      a3 += wr[j+3].x*h3.x + wr[j+3].y*h3.y + wr[j+3].z*h3.z + wr[j+3].w*h3.w;
    }
    part[ks][row] = (a0 + a1) + (a2 + a3);
    // prefetch x for s+1
    float nx0 = 0.f, nx1 = 0.f, nx2 = 0.f, nx3 = 0.f;
    if (t < 128 && s + 1 < SS) {
      const int sfn = dir ? (SS-2-s) : (s+1);
      const float* xr = xcomb + (sfn*NB + b)*1024 + dir*512 + t;
      nx0 = xr[0]; nx1 = xr[128]; nx2 = xr[256]; nx3 = xr[384];
    }
    LBAR();
    if (t < 128) {
      float gi = part[0][t]       + part[1][t]       + xv0;
      float gf = part[0][128 + t] + part[1][128 + t] + xv1;
      float gg = part[0][256 + t] + part[1][256 + t] + xv2;
      float go = part[0][384 + t] + part[1][384 + t] + xv3;
      float iv = sigmf(gi), fv = sigmf(gf), gv = tanhf_(gg), ov = sigmf(go);
      c_reg = fv*c_reg + iv*gv;
      float hv = ov*tanhf_(c_reg);
      hl[t] = hv;
      encout[(b*SS + sf)*HH + dir*HL + t] = hv;
    }
    LBAR();
    xv0 = nx0; xv1 = nx1; xv2 = nx2; xv3 = nx3;
  }
  if (t < 128) {
    hpub[b*HH + dir*HL + t] = hl[t];
    c0buf[b*HH + dir*HL + t] = c_reg;
  }
}

// ---------- enc_ws = enc_out @ attn_s_W.T + b, row-major [b][s][a] ----------
__global__ __launch_bounds__(256) void k_encws(
    const float* __restrict__ encout,
    const float* __restrict__ asW, const float* __restrict__ asb,
    float* __restrict__ encwsR)
{
  const int rt = blockIdx.x;
  const int tid = threadIdx.x;
  __shared__ float Al[32*260];
  #pragma unroll
  for (int i = 0; i < 32; ++i) {
    int l = tid + i*256;
    int r = l >> 8, k = l & 255;
    Al[r*260 + k] = encout[(rt*32 + r)*256 + k];
  }
  __syncthreads();
  const int a = tid & 63, rg = tid >> 6;
  float acc[8];
  #pragma unroll
  for (int q = 0; q < 8; ++q) acc[q] = 0.0f;
  const float4* w4 = (const float4*)(asW + a*256);
  for (int k4 = 0; k4 < 64; ++k4) {
    float4 w = w4[k4];
    #pragma unroll
    for (int q = 0; q < 8; ++q) {
      const float4* a4 = (const float4*)(Al + (rg*8 + q)*260);
      float4 av = a4[k4];
      acc[q] += av.x*w.x + av.y*w.y + av.z*w.z + av.w*w.w;
    }
  }
  float bias = asb[a];
  #pragma unroll
  for (int q = 0; q < 8; ++q) {
    int row = rt*32 + rg*8 + q;
    encwsR[row*64 + a] = acc[q] + bias;
  }
}

// ---------- decoder: 8 WGs x 16 batches; 5 LBARs + 2 relaxed flagbars per step ----------
__global__ __launch_bounds__(1024, 4) void k_decoder(
    const float* __restrict__ decpre,
    const float* __restrict__ dwhh,   // [1024][256]
    const float* __restrict__ dwih,   // [1024][1280]
    const float* __restrict__ ahW, const float* __restrict__ ahb,
    const float* __restrict__ afW, const float* __restrict__ afb,
    const float* __restrict__ encwsR, // [b*400+s][64]
    const float* __restrict__ encout, // [b*400+s][256]
    const int* __restrict__ alen,
    const float* __restrict__ c0buf,  // [16][256]
    float* hpub,                      // [16][256], pre-filled with h0
    float* cpub,                      // [16][8][272]: ctxu[256] | m | s
    float* wpub,                      // [16][8][72]: whpart[64]
    float* __restrict__ dhall,        // [96*16][256]
    int* flags)
{
  const int wg = blockIdx.x;
  const int g = wg >> 4, b = wg & 15;   // unit-group / s-slice, batch
  const int t = threadIdx.x;            // 1024
  const int r = t & 127, ks = t >> 7;   // GEMM mapping: row (128), K-slice (8 x 64)
  const int lane = t & 63;
  const int u = t & 31;                 // cell unit (t<256, 8x replicated)
  const int s0 = g*50;

  // weight slice in registers (row grow, K = ks*64..+64)
  const int grow = (r >> 5)*256 + g*32 + (r & 31);
  float4 wr[16];
  #pragma unroll
  for (int j = 0; j < 16; ++j) {
    int k = ks*64 + j*4;
    wr[j] = (k < 256) ? *(const float4*)(dwhh + grow*256 + k)
                      : *(const float4*)(dwih + grow*1280 + 1024 + (k - 256));
    PIN4(wr[j]);
  }

  __shared__ float encl[50*256];   // 51200 B
  __shared__ float wsl[50*68];     // 13600 B
  __shared__ float ahWt[256*68];   // 69632 B
  __shared__ float hc[512];        // [h(256) | ctx(256)]
  __shared__ float part[8][132];
  __shared__ float wh[64];
  __shared__ float fwl[64];
  __shared__ float scl[64];
  __shared__ float sh_m, sh_s;

  // one-time stage-in
  for (int i = t; i < 50*256; i += 1024) {
    int si = i >> 8, d = i & 255;
    encl[i] = encout[(b*SS + s0 + si)*HH + d];
  }
  for (int i = t; i < 50*64; i += 1024) {
    int si = i >> 6, a = i & 63;
    wsl[si*68 + a] = encwsR[(b*SS + s0 + si)*64 + a];
  }
  for (int i = t; i < 64*256; i += 1024) {
    int a = i >> 8, k = i & 255;
    ahWt[k*68 + a] = ahW[i];
  }
  if (t < 64) fwl[t] = afW[t];
  const float fb0 = afb[0];
  int len = alen[b]; len = min(max(len, 1), SS);
  float c_reg = 0.f;
  float pre0 = 0.f, pre1 = 0.f, pre2 = 0.f, pre3 = 0.f;
  if (t < 256) {
    c_reg = c0buf[b*HH + g*32 + u];
    hc[t] = gload(hpub + b*HH + t);
    hc[256 + t] = 0.0f;
    const float* pr = decpre + (size_t)(0*NB + b)*1024 + g*32 + u;
    pre0 = pr[0]; pre1 = pr[256]; pre2 = pr[512]; pre3 = pr[768];
  }
  __syncthreads();

  for (int tt = 0; tt < TT; ++tt) {
    // ---- phase G: gates GEMM (all 1024 threads) ----
    {
      const float* hs = hc + ks*64;
      float a0 = 0.f, a1 = 0.f, a2 = 0.f, a3 = 0.f;
      #pragma unroll
      for (int j = 0; j < 16; j += 4) {
        float4 h0 = *(const float4*)(hs + j*4);
        float4 h1 = *(const float4*)(hs + j*4 + 4);
        float4 h2 = *(const float4*)(hs + j*4 + 8);
        float4 h3 = *(const float4*)(hs + j*4 + 12);
        a0 += wr[j].x*h0.x + wr[j].y*h0.y + wr[j].z*h0.z + wr[j].w*h0.w;
        a1 += wr[j+1].x*h1.x + wr[j+1].y*h1.y + wr[j+1].z*h1.z + wr[j+1].w*h1.w;
        a2 += wr[j+2].x*h2.x + wr[j+2].y*h2.y + wr[j+2].z*h2.z + wr[j+2].w*h2.w;
        a3 += wr[j+3].x*h3.x + wr[j+3].y*h3.y + wr[j+3].z*h3.z + wr[j+3].w*h3.w;
      }
      part[ks][r] = (a0 + a1) + (a2 + a3);
    }
    LBAR();
    // ---- phase C: reduce + cell (t<256, 8x replicated) + whpart via shuffles ----
    if (t < 256) {
      float g0 = pre0, g1 = pre1, g2 = pre2, g3 = pre3;
      #pragma unroll
      for (int j = 0; j < 8; ++j) {
        g0 += part[j][u];
        g1 += part[j][32 + u];
        g2 += part[j][64 + u];
        g3 += part[j][96 + u];
      }
      float iv = sigmf(g0), fv = sigmf(g1), gv = tanhf_(g2), ov = sigmf(g3);
      c_reg = fv*c_reg + iv*gv;
      float hv = ov*tanhf_(c_reg);
      if (t < 32) {
        gstore(hpub + b*HH + g*32 + t, hv);
        dhall[(tt*NB + b)*HH + g*32 + t] = hv;
      }
      // whpart_g[a] = sum_u ahW[a][g*32+u] * h_u  (in-wave shuffles, no LDS deps)
      int wv = t >> 6;                 // 0..3
      int a = wv*16 + (lane >> 2);
      int j4 = lane & 3;
      float wacc = 0.f;
      #pragma unroll
      for (int i = 0; i < 8; ++i) {
        int u2 = j4*8 + i;
        float hx = __shfl(hv, u2, 64);
        wacc += ahWt[(g*32 + u2)*68 + a] * hx;
      }
      wacc += __shfl_xor(wacc, 1);
      wacc += __shfl_xor(wacc, 2);
      if (j4 == 0) gstore(wpub + (b*8 + g)*72 + a, wacc);
    }
    flagbar(flags, b, g, 2*tt + 1);
    // ---- phase SW: stage h (t<256) + prefetch decpre, wh combine (wave 4) ----
    if (t < 256) {
      hc[t] = gload(hpub + b*HH + t);
      if (tt + 1 < TT) {
        const float* pr = decpre + (size_t)((tt+1)*NB + b)*1024 + g*32 + u;
        pre0 = pr[0]; pre1 = pr[256]; pre2 = pr[512]; pre3 = pr[768];
      }
    } else if (t < 320) {
      int a = t - 256;
      float s = ahb[a];
      #pragma unroll
      for (int j = 0; j < 8; ++j) s += gload(wpub + (b*8 + j)*72 + a);
      wh[a] = s;
    }
    LBAR();
    // ---- phase F: scores (t<800, 16-lane shuffle reduce) ----
    if (t < 800) {
      int s = t >> 4, j = t & 15;
      const float* wrow = wsl + s*68 + j*4;
      float p = fwl[j*4]   * tanhf_(wrow[0] + wh[j*4])
              + fwl[j*4+1] * tanhf_(wrow[1] + wh[j*4+1])
              + fwl[j*4+2] * tanhf_(wrow[2] + wh[j*4+2])
              + fwl[j*4+3] * tanhf_(wrow[3] + wh[j*4+3]);
      p += __shfl_xor(p, 1);
      p += __shfl_xor(p, 2);
      p += __shfl_xor(p, 4);
      p += __shfl_xor(p, 8);
      if (j == 0) scl[s] = p;
    }
    LBAR();
    // ---- phase M: slice softmax (wave 0) ----
    if (t < 64) {
      float sc = -1e30f;
      if (t < 50) {
        sc = fb0 + scl[t];
        sc = fminf(sc, (s0 + t < len) ? 9999.0f : -9999.0f);
      }
      float m = sc;
      #pragma unroll
      for (int o = 32; o; o >>= 1) m = fmaxf(m, __shfl_xor(m, o));
      float p = (t < 50) ? __expf(sc - m) : 0.0f;
      scl[t] = p;
      float ssum = p;
      #pragma unroll
      for (int o = 32; o; o >>= 1) ssum += __shfl_xor(ssum, o);
      if (t == 0) { sh_m = m; sh_s = ssum; }
    }
    LBAR();
    // ---- phase X: unnormalized ctx partial (t<256, 50 MACs) + publish ----
    if (t < 256) {
      float acc = 0.0f;
      const float* eb = encl + t;
      #pragma unroll 10
      for (int i = 0; i < 50; ++i) acc += scl[i] * eb[i*256];
      gstore(cpub + (b*8 + g)*272 + t, acc);
      if (t == 0) gstore(cpub + (b*8 + g)*272 + 256, sh_m);
      if (t == 1) gstore(cpub + (b*8 + g)*272 + 257, sh_s);
    }
    flagbar(flags, b, g, 2*tt + 2);
    // ---- phase K: combine 8 online-softmax partials (self-service, t<256) ----
    if (t < 256) {
      float mj[8], sj[8];
      #pragma unroll
      for (int j = 0; j < 8; ++j) {
        mj[j] = gload(cpub + (b*8 + j)*272 + 256);
        sj[j] = gload(cpub + (b*8 + j)*272 + 257);
      }
      float M = mj[0];
      #pragma unroll
      for (int j = 1; j < 8; ++j) M = fmaxf(M, mj[j]);
      float denom = 0.f, ctx = 0.f;
      #pragma unroll
      for (int j = 0; j < 8; ++j) {
        float e = __expf(mj[j] - M);
        denom += sj[j] * e;
        ctx += gload(cpub + (b*8 + j)*272 + t) * e;
      }
      hc[256 + t] = ctx / denom;
    }
    LBAR();
  }
}

// ---------- vocab logits via MFMA + per-chunk logsumexp partials ----------
__global__ __launch_bounds__(256) void k_pred_mfma(
    const float* __restrict__ dhall,
    const short* __restrict__ predWb,
    const float* __restrict__ predb,
    float* __restrict__ pm, float* __restrict__ ps)
{
  const int m0 = blockIdx.x * 64;
  const int ch = blockIdx.y;
  const int c0 = ch * 256;
  const int t = threadIdx.x;
  const int w = t >> 6, l = t & 63;
  __shared__ __align__(16) char smem[64*264*4];
  short* Abuf = (short*)smem;
  float* L    = (float*)smem;
  __shared__ float red[256];
  __shared__ float rowmax[64];

  {
    const int ar = t >> 2, ak0 = (t & 3) * 64;
    const float* src = dhall + (size_t)(m0 + ar)*256 + ak0;
    #pragma unroll
    for (int j = 0; j < 16; ++j) {
      float4 v = *(const float4*)(src + 4*j);
      short4 s4; s4.x = f2bf(v.x); s4.y = f2bf(v.y); s4.z = f2bf(v.z); s4.w = f2bf(v.w);
      *(short4*)(&Abuf[ar*264 + ak0 + 4*j]) = s4;
    }
  }
  LBAR();
  f32x4 acc[4][4];
  #pragma unroll
  for (int i = 0; i < 4; ++i)
    #pragma unroll
    for (int j = 0; j < 4; ++j) acc[i][j] = (f32x4){0.f,0.f,0.f,0.f};
  #pragma unroll
  for (int kst = 0; kst < 8; ++kst) {
    bf16x8 af[4];
    #pragma unroll
    for (int mr = 0; mr < 4; ++mr)
      af[mr] = *(const bf16x8*)(&Abuf[(mr*16 + (l & 15))*264 + kst*32 + (l >> 4)*8]);
    #pragma unroll
    for (int ct = 0; ct < 4; ++ct) {
      int col = c0 + w*64 + ct*16 + (l & 15);
      bf16x8 bfr = *(const bf16x8*)(predWb + (size_t)col*256 + kst*32 + (l >> 4)*8);
      #pragma unroll
      for (int mr = 0; mr < 4; ++mr)
        acc[mr][ct] = __builtin_amdgcn_mfma_f32_16x16x32_bf16(af[mr], bfr, acc[mr][ct], 0, 0, 0);
    }
  }
  LBAR();
  #pragma unroll
  for (int ct = 0; ct < 4; ++ct) {
    int col = c0 + w*64 + ct*16 + (l & 15);
    float bias = (col < VV) ? predb[col] : 0.0f;
    bool valid = (col < VV);
    #pragma unroll
    for (int mr = 0; mr < 4; ++mr) {
      #pragma unroll
      for (int r = 0; r < 4; ++r) {
        int rl = mr*16 + (l >> 4)*4 + r;
        L[rl*264 + w*64 + ct*16 + (l & 15)] = valid ? (acc[mr][ct][r] + bias) : -1e30f;
      }
    }
  }
  LBAR();
  {
    const int row = t & 63, qd = t >> 6;
    float m = -1e30f;
    const float* Lr = L + row*264 + qd*64;
    for (int i = 0; i < 64; ++i) m = fmaxf(m, Lr[i]);
    red[qd*64 + row] = m;
  }
  LBAR();
  if (t < 64) {
    float m = fmaxf(fmaxf(red[t], red[64+t]), fmaxf(red[128+t], red[192+t]));
    rowmax[t] = m;
  }
  LBAR();
  {
    const int row = t & 63, qd = t >> 6;
    float m = rowmax[row];
    float ssum = 0.f;
    const float* Lr = L + row*264 + qd*64;
    for (int i = 0; i < 64; ++i) ssum += __expf(Lr[i] - m);
    red[qd*64 + row] = ssum;
  }
  LBAR();
  if (t < 64) {
    float ssum = red[t] + red[64+t] + red[128+t] + red[192+t];
    pm[(m0 + t)*NCHUNK + ch] = rowmax[t];
    ps[(m0 + t)*NCHUNK + ch] = ssum;
  }
}

// ---------- loss partials: 6 WGs x 256 threads, one row per thread ----------
__global__ __launch_bounds__(256) void k_loss_part(
    const float* __restrict__ pm, const float* __restrict__ ps,
    const float* __restrict__ dhall,
    const float* __restrict__ predW, const float* __restrict__ predb,
    const int* __restrict__ abstr, float* __restrict__ lpart)
{
  const int tid = threadIdx.x;
  const int row = blockIdx.x*256 + tid;
  __shared__ float rs[256], rc[256];
  float lsum = 0.0f, lcnt = 0.0f;
  {
    int t = row >> 4, b = row & 15;
    int tok = abstr[b*TT + t];
    float m = -1e30f;
    for (int c = 0; c < NCHUNK; ++c) m = fmaxf(m, pm[row*NCHUNK + c]);
    float ss = 0.0f;
    for (int c = 0; c < NCHUNK; ++c) ss += ps[row*NCHUNK + c] * __expf(pm[row*NCHUNK + c] - m);
    float lse = m + __logf(ss);
    float tl = predb[tok];
    const float* hrow = dhall + row*256;
    const float* wrow = predW + tok*256;
    #pragma unroll 4
    for (int k = 0; k < 256; ++k) tl += hrow[k] * wrow[k];
    if (tok != 0) { lsum = lse - tl; lcnt = 1.0f; }
  }
  rs[tid] = lsum; rc[tid] = lcnt;
  __syncthreads();
  for (int st = 128; st; st >>= 1) {
    if (tid < st) { rs[tid] += rs[tid + st]; rc[tid] += rc[tid + st]; }
    __syncthreads();
  }
  if (tid == 0) { lpart[blockIdx.x*2] = rs[0]; lpart[blockIdx.x*2 + 1] = rc[0]; }
}

// ---------- final: deterministic sum of 6 partials ----------
__global__ void k_loss_final(const float* __restrict__ lpart, float* __restrict__ out) {
  if (threadIdx.x == 0) {
    float s = 0.f, c = 0.f;
    for (int i = 0; i < 6; ++i) { s += lpart[i*2]; c += lpart[i*2 + 1]; }
    out[0] = s / fmaxf(c, 1.0f);
  }
}

// ---------- launch ----------
extern "C" void kernel_launch(void* const* d_in, const int* in_sizes, int n_in,
                              void* d_out, int out_size, void* d_ws, size_t ws_size,
                              hipStream_t stream) {
  const float* emb   = (const float*)d_in[0];
  const int* article = (const int*)d_in[1];
  const int* alen    = (const int*)d_in[2];
  const int* abstr   = (const int*)d_in[3];
  const float* eWihF = (const float*)d_in[4];
  const float* eWhhF = (const float*)d_in[5];
  const float* ebF   = (const float*)d_in[6];
  const float* eWihB = (const float*)d_in[7];
  const float* eWhhB = (const float*)d_in[8];
  const float* ebB   = (const float*)d_in[9];
  const float* dWih  = (const float*)d_in[10];
  const float* dWhh  = (const float*)d_in[11];
  const float* db    = (const float*)d_in[12];
  const float* pW    = (const float*)d_in[13];
  const float* pb    = (const float*)d_in[14];
  const float* asW   = (const float*)d_in[15];
  const float* asb   = (const float*)d_in[16];
  const float* ahW   = (const float*)d_in[17];
  const float* ahb   = (const float*)d_in[18];
  const float* afW   = (const float*)d_in[19];
  const float* afb   = (const float*)d_in[20];
  float* out = (float*)d_out;

  float* w = (float*)d_ws;
  size_t o = 0;
  float* xcomb  = w + o; o += (size_t)SS*NB*1024;
  float* encout = w + o; o += (size_t)NB*SS*HH;
  float* encwsR = w + o; o += (size_t)NB*SS*AA;
  float* decpre = w + o; o += (size_t)TT*NB*1024;
  float* dhall  = w + o; o += (size_t)TT*NB*HH;
  float* hpub   = w + o; o += NB*HH;
  float* cpub   = w + o; o += NB*8*272;
  float* wpub   = w + o; o += NB*8*72;
  float* c0buf  = w + o; o += NB*HH;
  float* pm     = w + o; o += (size_t)TT*NB*NCHUNK;
  float* ps     = w + o; o += (size_t)TT*NB*NCHUNK;
  float* lpart  = w + o; o += 16;
  int* flags = (int*)(w + o); o += 128;
  short* predWb = (short*)(w + o); o += (size_t)VVP*256/2;
  short* wfB    = (short*)(w + o); o += 512*1024/2;
  short* wbB    = (short*)(w + o); o += 512*1024/2;
  short* dwB    = (short*)(w + o); o += 1024*1024/2;

  k_init<<<1, 256, 0, stream>>>(flags);
  k_casts<<<2048, 256, 0, stream>>>(pW, eWihF, eWihB, dWih, predWb, wfB, wbB, dwB);
  k_embproj_enc_mfma<<<dim3(100, 4), 256, 0, stream>>>(emb, article, wfB, wbB, ebF, ebB, xcomb);
  k_embproj_dec_mfma<<<dim3(24, 4), 256, 0, stream>>>(emb, abstr, dwB, db, decpre);
  k_encoder<<<32, 1024, 0, stream>>>(xcomb, eWhhF, eWhhB, encout, hpub, c0buf);
  k_encws<<<200, 256, 0, stream>>>(encout, asW, asb, encwsR);
  k_decoder<<<128, 1024, 0, stream>>>(decpre, dWhh, dWih, ahW, ahb, afW, afb,
                                      encwsR, encout, alen, c0buf, hpub, cpub, wpub, dhall, flags);
  k_pred_mfma<<<dim3(24, 120), 256, 0, stream>>>(dhall, predWb, pb, pm, ps);
  k_loss_part<<<6, 256, 0, stream>>>(pm, ps, dhall, pW, pb, abstr, lpart);
  k_loss_final<<<1, 64, 0, stream>>>(lpart, out);
}